// Round 9
// baseline (431.162 us; speedup 1.0000x reference)
//
#include <hip/hip_runtime.h>
#include <hip/hip_bf16.h>

#define NEX 4096
#define M   256
#define NM  (NEX*M)

typedef __attribute__((ext_vector_type(8))) short short8;
typedef __attribute__((ext_vector_type(16))) float floatx16;

__device__ inline unsigned short f2bfu(float x) {
    __hip_bfloat16 h = __float2bfloat16(x);
    union { __hip_bfloat16 b; unsigned short u; } cv; cv.b = h;
    return cv.u;
}
__device__ inline float bfu2f(unsigned short u) {
    union { unsigned short u; __hip_bfloat16 b; } cv; cv.u = u;
    return __bfloat162float(cv.b);
}

// ---------------- fused prep kernel ----------------
// b in [0,256): Wd0T ; [256,512): Wd1T ; [512,576): W0T
// b == 576: ksq + trace ; [577,593): symA ; [593,657): FB ; [657,665): FA
//
// FB layout for 32x32x16 MFMA B-operand (ushort), layer l stride 131072:
//   chunk (atile in [0,8), kstep in [0,16), h in {hi,lo}) of 512 ushorts:
//   FB[l*131072 + ((atile*16+kstep)*2 + h)*512 + lane*8 + e]
//     = split_h( Wd[l][atile*32 + (lane&31)][kstep*16 + (lane>>5)*8 + e] )
// FA layout (f32): A-fragment-ordered W0T with row d=63 zeroed:
//   FA[((dtile*16+kstep)*64 + tl)*8 + e] = W0T[dtile*32+(tl&31)][kstep*16+(tl>>5)*8+e]
__global__ void k_prep(const float* __restrict__ Wd, const float* __restrict__ W0,
                       const float* __restrict__ A,
                       unsigned short* __restrict__ FB, float* __restrict__ FA,
                       float* __restrict__ Wd0T, float* __restrict__ Wd1T,
                       float* __restrict__ W0T, float* __restrict__ symA,
                       float* __restrict__ ksq, float* __restrict__ trace) {
    int b = blockIdx.x, t = threadIdx.x;
    if (b < 256) {
        int idx = b*256 + t;                // dst index c*256+r
        int c = idx >> 8, r = idx & 255;
        Wd0T[idx] = Wd[r*256 + c];
    } else if (b < 512) {
        int idx = (b-256)*256 + t;
        int c = idx >> 8, r = idx & 255;
        Wd1T[idx] = Wd[65536 + r*256 + c];
    } else if (b < 576) {
        int idx = (b-512)*256 + t;          // 16384 entries: c*256+r, c<64
        int c = idx >> 8, r = idx & 255;
        W0T[idx] = W0[r*64 + c];
    } else if (b == 576) {
        float s = 0.f;
        for (int dd = 0; dd < 63; dd++) { float v = W0[t*64+dd]; s += v*v; }
        ksq[t] = s;
        float p = 0.f;
        for (int idx = t; idx < 630; idx += 256) {
            int r = idx / 63, i = idx % 63;
            float v = A[r*64+i]; p += v*v;
        }
        for (int off = 32; off; off >>= 1) p += __shfl_down(p, off, 64);
        __shared__ float red[4];
        if ((t & 63) == 0) red[t >> 6] = p;
        __syncthreads();
        if (t == 0) trace[0] = red[0]+red[1]+red[2]+red[3];
    } else if (b < 593) {
        int idx = (b-577)*256 + t;          // 4096 entries
        int i = idx >> 6, j = idx & 63;
        float s = 0.f;
        #pragma unroll
        for (int r = 0; r < 10; r++) s += A[r*64+i] * A[r*64+j];
        symA[idx] = s;
    } else if (b < 657) {
        // FB build: 256 (l,atile,kstep) combos, 4 per block
        int combo = (b-593)*4 + (t >> 6);
        int l = combo >> 7, rest = combo & 127;   // rest = atile*16 + kstep
        int atile = rest >> 4, kstep = rest & 15;
        int lane = t & 63, l31 = lane & 31, lhi = lane >> 5;
        const float* src = Wd + l*65536 + (atile*32 + l31)*256 + kstep*16 + lhi*8;
        unsigned short* dst = FB + l*131072 + ((atile*16 + kstep)*2)*512 + lane*8;
        #pragma unroll
        for (int e = 0; e < 8; ++e) {
            float x = src[e];
            unsigned short h = f2bfu(x);
            dst[e]       = h;
            dst[512 + e] = f2bfu(x - bfu2f(h));
        }
    } else {
        // FA build: 2048 lane-slots, 256 per block
        int q = (b-657)*256 + t;            // [0,2048)
        int tl = q & 63, frag = q >> 6;     // frag = dtile*16+kstep in [0,32)
        int d  = (frag >> 4)*32 + (tl & 31);
        int m0 = (frag & 15)*16 + (tl >> 5)*8;
        float* dst = FA + q*8;
        #pragma unroll
        for (int e = 0; e < 8; ++e)
            dst[e] = (d == 63) ? 0.f : W0[(m0 + e)*64 + d];
    }
}

// ---------------- fused forward chain: opening + pre0 + pre1 ----------------
__global__ void k_fwd(const float* __restrict__ x, const float* __restrict__ W0T,
                      const float* __restrict__ b0, const float* __restrict__ Wd0T,
                      const float* __restrict__ Wd1T, const float* __restrict__ bd,
                      float* __restrict__ tanhopen, float* __restrict__ tp0,
                      float* __restrict__ tp1) {
    __shared__ float xs[8*64];
    __shared__ float u0s[8*256];
    __shared__ float u1s[8*256];
    int n0 = blockIdx.x * 8, t = threadIdx.x;
    #pragma unroll
    for (int i = 0; i < 2; i++) { int f = t + i*256; xs[f] = x[n0*64 + f]; }
    __syncthreads();
    float acc[8];
    float b = b0[t];
    #pragma unroll
    for (int j = 0; j < 8; j++) acc[j] = b;
    for (int c = 0; c < 64; c++) {
        float w = W0T[c*256 + t];
        #pragma unroll
        for (int j = 0; j < 8; j++) acc[j] += w * xs[j*64 + c];
    }
    #pragma unroll
    for (int j = 0; j < 8; j++) {
        float p = acc[j];
        tanhopen[(n0+j)*256 + t] = tanhf(p);
        float a = fabsf(p);
        u0s[j*256 + t] = a + log1pf(expf(-2.f*a));
    }
    __syncthreads();
    b = bd[t];
    #pragma unroll
    for (int j = 0; j < 8; j++) acc[j] = b;
    for (int k = 0; k < 256; k++) {
        float w = Wd0T[k*256 + t];
        #pragma unroll
        for (int j = 0; j < 8; j++) acc[j] += w * u0s[j*256 + k];
    }
    #pragma unroll
    for (int j = 0; j < 8; j++) {
        float p = acc[j];
        tp0[(n0+j)*256 + t] = tanhf(p);
        float a = fabsf(p);
        u1s[j*256 + t] = u0s[j*256 + t] + 0.5f*(a + log1pf(expf(-2.f*a)));
    }
    __syncthreads();
    b = bd[256 + t];
    #pragma unroll
    for (int j = 0; j < 8; j++) acc[j] = b;
    for (int k = 0; k < 256; k++) {
        float w = Wd1T[k*256 + t];
        #pragma unroll
        for (int j = 0; j < 8; j++) acc[j] += w * u1s[j*256 + k];
    }
    #pragma unroll
    for (int j = 0; j < 8; j++) tp1[(n0+j)*256 + t] = tanhf(acc[j]);
}

// ---------------- fused backward chain: z2 + z1 + grad ----------------
__global__ void k_bwd(const float* __restrict__ tanhopen, const float* __restrict__ tp0,
                      const float* __restrict__ tp1, const float* __restrict__ wv,
                      const float* __restrict__ Wd, const float* __restrict__ W0,
                      const float* __restrict__ symA, const float* __restrict__ x,
                      const float* __restrict__ cw,
                      float* __restrict__ z2T, float* __restrict__ z1T,
                      float* __restrict__ out) {
    __shared__ float coefs[8*256];
    __shared__ float z2s[8*256];
    __shared__ float sa[64*64];
    __shared__ float xs[8*64];
    __shared__ float cws[64];
    const float* Wd0 = Wd;
    const float* Wd1 = Wd + 65536;
    int n0 = blockIdx.x * 8, t = threadIdx.x;
    float wvt = wv[t];
    #pragma unroll
    for (int j = 0; j < 8; j++) coefs[j*256 + t] = tp1[(n0+j)*256 + t] * wvt;
    #pragma unroll
    for (int i = 0; i < 16; i++) { int f = t + i*256; sa[f] = symA[f]; }
    #pragma unroll
    for (int i = 0; i < 2; i++) { int f = t + i*256; xs[f] = x[n0*64 + f]; }
    if (t < 64) cws[t] = cw[t];
    __syncthreads();
    float acc[8];
    #pragma unroll
    for (int j = 0; j < 8; j++) acc[j] = 0.f;
    for (int m = 0; m < 256; m++) {
        float w = Wd1[m*256 + t];
        #pragma unroll
        for (int j = 0; j < 8; j++) acc[j] += w * coefs[j*256 + m];
    }
    #pragma unroll
    for (int j = 0; j < 8; j++) {
        float v = wvt + 0.5f*acc[j];
        z2s[j*256 + t] = v;
        z2T[(n0+j)*256 + t] = v;
    }
    __syncthreads();
    #pragma unroll
    for (int j = 0; j < 8; j++) coefs[j*256 + t] = tp0[(n0+j)*256 + t] * z2s[j*256 + t];
    __syncthreads();
    #pragma unroll
    for (int j = 0; j < 8; j++) acc[j] = 0.f;
    for (int m = 0; m < 256; m++) {
        float w = Wd0[m*256 + t];
        #pragma unroll
        for (int j = 0; j < 8; j++) acc[j] += w * coefs[j*256 + m];
    }
    #pragma unroll
    for (int j = 0; j < 8; j++) {
        float v = z2s[j*256 + t] + 0.5f*acc[j];
        z2s[j*256 + t] = v;
        z1T[(n0+j)*256 + t] = v;
    }
    __syncthreads();
    #pragma unroll
    for (int j = 0; j < 8; j++) coefs[j*256 + t] = tanhopen[(n0+j)*256 + t] * z2s[j*256 + t];
    __syncthreads();
    int c = t & 63, jj = t >> 6;
    float g[2] = {0.f, 0.f};
    for (int m = 0; m < 256; m++) {
        float w0v = W0[m*64 + c];
        #pragma unroll
        for (int jb = 0; jb < 2; jb++) g[jb] += coefs[(jj + jb*4)*256 + m] * w0v;
    }
    #pragma unroll
    for (int jb = 0; jb < 2; jb++) {
        int j = jj + jb*4;
        float g2 = 0.f;
        for (int jd = 0; jd < 64; jd++) g2 += sa[jd*64 + c] * xs[j*64 + jd];
        out[(n0+j)*64 + c] = g[jb] + g2 + cws[c];
    }
}

// ---------------- heavy Jacobian kernel: 2 examples/block, B shared in-wave ----------------
// 256 threads (4 waves), 2 examples/block, 2048 blocks, 2 blocks/CU (LDS ~74 KB).
// Wave w: d-tile cw = w&1, a-tile group jg = w>>1 (a-tiles 4jg..4jg+3).
// acc[4 j][2 ex] x floatx16 = 128 VGPR; launch_bounds(256,2) -> 256-reg cap (~190 used).
// Each B fragment (1 KB coalesced, L2/L1) feeds 4 MFMAs (2 hi/lo x 2 examples).
// A-frag LDS reads only for own d-tile (halved vs round 8).
// C/D: col(a)=lane&31, row(d)=(reg&3)+8*(reg>>2)+4*(lane>>5)  [m74/m101-verified]
__global__ __launch_bounds__(256, 2) void k_heavy_mfma(
        const float* __restrict__ tanhopen, const float* __restrict__ tp0,
        const float* __restrict__ tp1, const float* __restrict__ z2T,
        const float* __restrict__ z1T, const float* __restrict__ wv,
        const float* __restrict__ FA, const unsigned short* __restrict__ FB,
        const float* __restrict__ ksq, const float* __restrict__ trace,
        float* __restrict__ outTrH) {
    __shared__ __align__(16) unsigned short Af[2][16384];   // 64 KB, fragment order
    __shared__ float ss[2][256], tp0s[2][256], w1s[2][256], w2s[2][256];
    __shared__ float red[4][2];
    int n0 = blockIdx.x * 2, t = threadIdx.x;      // t in [0,256)
    int lane = t & 63, w = t >> 6, l31 = lane & 31, lhi = lane >> 5;
    int cw = w & 1, jg = w >> 1;

    float tot0, tot1;
    {
        float sv0 = tanhopen[n0*256 + t];
        float sv1 = tanhopen[(n0+1)*256 + t];
        float a00 = tp0[n0*256 + t], a01 = tp0[(n0+1)*256 + t];
        float a10 = tp1[n0*256 + t], a11 = tp1[(n0+1)*256 + t];
        ss[0][t] = sv0;  ss[1][t] = sv1;
        tp0s[0][t] = a00; tp0s[1][t] = a01;
        w1s[0][t] = (1.f - a00*a00) * z2T[n0*256 + t];
        w1s[1][t] = (1.f - a01*a01) * z2T[(n0+1)*256 + t];
        float wvt = wv[t];
        w2s[0][t] = (1.f - a10*a10) * wvt;
        w2s[1][t] = (1.f - a11*a11) * wvt;
        tot0 = (1.f - sv0*sv0) * z1T[n0*256 + t] * ksq[t];
        tot1 = (1.f - sv1*sv1) * z1T[(n0+1)*256 + t] * ksq[t];
    }
    __syncthreads();

    // build Af[ex] = bf16(FA * s_ex): coalesced FA loads, linear b128 LDS writes
    #pragma unroll
    for (int i = 0; i < 16; ++i) {
        int q = t + i*256;                  // [0,4096)
        int ex = q >> 11, qq = q & 2047;
        int tl = qq & 63, frag = qq >> 6;
        int m0 = (frag & 15)*16 + (tl >> 5)*8;
        const float* fp = FA + qq*8;
        short8 v8;
        #pragma unroll
        for (int e = 0; e < 8; ++e)
            v8[e] = (short)f2bfu(fp[e] * ss[ex][m0 + e]);
        *reinterpret_cast<short8*>(&Af[ex][qq*8]) = v8;
    }
    __syncthreads();

    floatx16 acc[4][2];   // [a-tile j][example ex]
    int aj[4];
    #pragma unroll
    for (int j = 0; j < 4; ++j) aj[j] = (jg*4 + j)*32 + l31;

    // ---------------- layer 0: KJ1^T ----------------
    #pragma unroll
    for (int j = 0; j < 4; ++j)
        #pragma unroll
        for (int e = 0; e < 2; ++e)
            #pragma unroll
            for (int r = 0; r < 16; ++r) acc[j][e][r] = 0.f;

    for (int ks = 0; ks < 16; ++ks) {
        short8 A0 = *reinterpret_cast<const short8*>(&Af[0][((cw*16 + ks)*64 + lane)*8]);
        short8 A1 = *reinterpret_cast<const short8*>(&Af[1][((cw*16 + ks)*64 + lane)*8]);
        #pragma unroll
        for (int j = 0; j < 4; ++j) {
            const unsigned short* bp = FB + (((jg*4 + j)*16 + ks)*2)*512 + lane*8;
            short8 Bh = *reinterpret_cast<const short8*>(bp);
            short8 Bl = *reinterpret_cast<const short8*>(bp + 512);
            acc[j][0] = __builtin_amdgcn_mfma_f32_32x32x16_bf16(A0, Bh, acc[j][0], 0, 0, 0);
            acc[j][0] = __builtin_amdgcn_mfma_f32_32x32x16_bf16(A0, Bl, acc[j][0], 0, 0, 0);
            acc[j][1] = __builtin_amdgcn_mfma_f32_32x32x16_bf16(A1, Bh, acc[j][1], 0, 0, 0);
            acc[j][1] = __builtin_amdgcn_mfma_f32_32x32x16_bf16(A1, Bl, acc[j][1], 0, 0, 0);
        }
    }
    __syncthreads();   // all layer-0 reads of Af done before update writes

    // trH layer-1 term + Jac update (LDS RMW in fragment slot):
    //   JacT[d][a] += 0.5*tp0[a]*KJ1T[d][a]
    {
        float w1a[2][4], tp0a[2][4];
        #pragma unroll
        for (int j = 0; j < 4; ++j) {
            int a = aj[j];
            w1a[0][j] = w1s[0][a];  w1a[1][j] = w1s[1][a];
            tp0a[0][j] = 0.5f * tp0s[0][a];  tp0a[1][j] = 0.5f * tp0s[1][a];
        }
        #pragma unroll
        for (int r = 0; r < 16; ++r) {
            int d = cw*32 + (r & 3) + 8*(r >> 2) + 4*lhi;
            #pragma unroll
            for (int j = 0; j < 4; ++j) {
                int a = aj[j];
                int idx = ((cw*16 + (a >> 4))*64 + ((a >> 3) & 1)*32 + (d & 31))*8 + (a & 7);
                float v0 = acc[j][0][r], v1 = acc[j][1][r];
                tot0 += 0.5f * w1a[0][j] * v0 * v0;
                tot1 += 0.5f * w1a[1][j] * v1 * v1;
                Af[0][idx] = f2bfu(bfu2f(Af[0][idx]) + tp0a[0][j] * v0);
                Af[1][idx] = f2bfu(bfu2f(Af[1][idx]) + tp0a[1][j] * v1);
            }
        }
    }
    __syncthreads();   // updates visible before layer-1 reads

    // ---------------- layer 1: KJ2^T ----------------
    #pragma unroll
    for (int j = 0; j < 4; ++j)
        #pragma unroll
        for (int e = 0; e < 2; ++e)
            #pragma unroll
            for (int r = 0; r < 16; ++r) acc[j][e][r] = 0.f;

    const unsigned short* FB1 = FB + 131072;
    for (int ks = 0; ks < 16; ++ks) {
        short8 A0 = *reinterpret_cast<const short8*>(&Af[0][((cw*16 + ks)*64 + lane)*8]);
        short8 A1 = *reinterpret_cast<const short8*>(&Af[1][((cw*16 + ks)*64 + lane)*8]);
        #pragma unroll
        for (int j = 0; j < 4; ++j) {
            const unsigned short* bp = FB1 + (((jg*4 + j)*16 + ks)*2)*512 + lane*8;
            short8 Bh = *reinterpret_cast<const short8*>(bp);
            short8 Bl = *reinterpret_cast<const short8*>(bp + 512);
            acc[j][0] = __builtin_amdgcn_mfma_f32_32x32x16_bf16(A0, Bh, acc[j][0], 0, 0, 0);
            acc[j][0] = __builtin_amdgcn_mfma_f32_32x32x16_bf16(A0, Bl, acc[j][0], 0, 0, 0);
            acc[j][1] = __builtin_amdgcn_mfma_f32_32x32x16_bf16(A1, Bh, acc[j][1], 0, 0, 0);
            acc[j][1] = __builtin_amdgcn_mfma_f32_32x32x16_bf16(A1, Bl, acc[j][1], 0, 0, 0);
        }
    }

    // trH layer-2 term
    {
        #pragma unroll
        for (int j = 0; j < 4; ++j) {
            int a = aj[j];
            float w20 = w2s[0][a], w21 = w2s[1][a];
            #pragma unroll
            for (int r = 0; r < 16; ++r) {
                float v0 = acc[j][0][r], v1 = acc[j][1][r];
                tot0 += 0.5f * w20 * v0 * v0;
                tot1 += 0.5f * w21 * v1 * v1;
            }
        }
    }

    // reduce 256 -> 2
    #pragma unroll
    for (int off = 32; off; off >>= 1) {
        tot0 += __shfl_down(tot0, off, 64);
        tot1 += __shfl_down(tot1, off, 64);
    }
    if (lane == 0) { red[w][0] = tot0; red[w][1] = tot1; }
    __syncthreads();
    if (t < 2) {
        float s = trace[0];
        #pragma unroll
        for (int i = 0; i < 4; ++i) s += red[i][t];
        outTrH[n0 + t] = s;
    }
}

// ---------------- launcher ----------------

extern "C" void kernel_launch(void* const* d_in, const int* in_sizes, int n_in,
                              void* d_out, int out_size, void* d_ws, size_t ws_size,
                              hipStream_t stream) {
    const float* x   = (const float*)d_in[0];   // 4096*64
    const float* W0  = (const float*)d_in[1];   // 256*64
    const float* b0  = (const float*)d_in[2];   // 256
    const float* Wd  = (const float*)d_in[3];   // 2*256*256
    const float* bd  = (const float*)d_in[4];   // 2*256
    const float* wv  = (const float*)d_in[5];   // 256
    const float* A   = (const float*)d_in[6];   // 10*64
    const float* cw  = (const float*)d_in[7];   // 64
    float* out = (float*)d_out;
    float* ws  = (float*)d_ws;

    float* tanhopen = ws;               // NM
    float* tp0  = tanhopen + NM;        // NM
    float* tp1  = tp0 + NM;             // NM
    float* z2T  = tp1 + NM;             // NM
    float* z1T  = z2T + NM;             // NM
    float* Wd0T = z1T + NM;             // 65536
    float* Wd1T = Wd0T + 65536;         // 65536
    float* W0T  = Wd1T + 65536;         // 16384
    float* symA = W0T + 16384;          // 4096
    float* ksq  = symA + 4096;          // 256
    float* trace= ksq + 256;            // 1
    unsigned short* FB = (unsigned short*)(trace + 1);    // 262144 ushorts (512 KB)
    float* FA = (float*)(FB + 262144);                    // 16384 floats (64 KB)

    k_prep<<<665, 256, 0, stream>>>(Wd, W0, A, FB, FA, Wd0T, Wd1T, W0T,
                                    symA, ksq, trace);
    k_fwd<<<NEX/8, 256, 0, stream>>>(x, W0T, b0, Wd0T, Wd1T, bd,
                                     tanhopen, tp0, tp1);
    k_bwd<<<NEX/8, 256, 0, stream>>>(tanhopen, tp0, tp1, wv, Wd, W0, symA, x, cw,
                                     z2T, z1T, out);
    k_heavy_mfma<<<NEX/2, 256, 0, stream>>>(tanhopen, tp0, tp1, z2T, z1T, wv,
                                            FA, FB, ksq, trace, out + NEX*64);
}

// Round 10
// 231.892 us; speedup vs baseline: 1.8593x; 1.8593x over previous
//
#include <hip/hip_runtime.h>
#include <hip/hip_bf16.h>

#define NEX 4096
#define M   256
#define NM  (NEX*M)

typedef __attribute__((ext_vector_type(8))) short short8;
typedef __attribute__((ext_vector_type(16))) float floatx16;
typedef __attribute__((ext_vector_type(4))) unsigned short ushort4v;

__device__ inline unsigned short f2bfu(float x) {
    __hip_bfloat16 h = __float2bfloat16(x);
    union { __hip_bfloat16 b; unsigned short u; } cv; cv.b = h;
    return cv.u;
}
__device__ inline float bfu2f(unsigned short u) {
    union { unsigned short u; __hip_bfloat16 b; } cv; cv.u = u;
    return __bfloat162float(cv.b);
}

// ---------------- fused prep kernel ----------------
// b in [0,256): Wd0T ; [256,512): Wd1T ; [512,576): W0T
// b == 576: ksq + trace ; [577,593): symA ; [593,657): FB ; [657,665): FA
//
// FB (ushort), layer l stride 131072: chunk (mtile in [0,8), ks in [0,16), h) of 512:
//   FB[l*131072 + ((mtile*16+ks)*2 + h)*512 + lane*8 + e]
//     = split_h( Wd[l][mtile*32 + (lane&31)][ks*16 + (lane>>5)*8 + e] )
// Used as the 32x32x16 MFMA **A-operand** (lane&31 = row m, lane>>5 = k-half).
// FA (f32): W0T in fragment order with row d=63 zeroed:
//   FA[((dh*16+ks)*64 + tl)*8 + e] = W0T[dh*32+(tl&31)][ks*16+(tl>>5)*8+e]
__global__ void k_prep(const float* __restrict__ Wd, const float* __restrict__ W0,
                       const float* __restrict__ A,
                       unsigned short* __restrict__ FB, float* __restrict__ FA,
                       float* __restrict__ Wd0T, float* __restrict__ Wd1T,
                       float* __restrict__ W0T, float* __restrict__ symA,
                       float* __restrict__ ksq, float* __restrict__ trace) {
    int b = blockIdx.x, t = threadIdx.x;
    if (b < 256) {
        int idx = b*256 + t;                // dst index c*256+r
        int c = idx >> 8, r = idx & 255;
        Wd0T[idx] = Wd[r*256 + c];
    } else if (b < 512) {
        int idx = (b-256)*256 + t;
        int c = idx >> 8, r = idx & 255;
        Wd1T[idx] = Wd[65536 + r*256 + c];
    } else if (b < 576) {
        int idx = (b-512)*256 + t;          // 16384 entries: c*256+r, c<64
        int c = idx >> 8, r = idx & 255;
        W0T[idx] = W0[r*64 + c];
    } else if (b == 576) {
        float s = 0.f;
        for (int dd = 0; dd < 63; dd++) { float v = W0[t*64+dd]; s += v*v; }
        ksq[t] = s;
        float p = 0.f;
        for (int idx = t; idx < 630; idx += 256) {
            int r = idx / 63, i = idx % 63;
            float v = A[r*64+i]; p += v*v;
        }
        for (int off = 32; off; off >>= 1) p += __shfl_down(p, off, 64);
        __shared__ float red[4];
        if ((t & 63) == 0) red[t >> 6] = p;
        __syncthreads();
        if (t == 0) trace[0] = red[0]+red[1]+red[2]+red[3];
    } else if (b < 593) {
        int idx = (b-577)*256 + t;          // 4096 entries
        int i = idx >> 6, j = idx & 63;
        float s = 0.f;
        #pragma unroll
        for (int r = 0; r < 10; r++) s += A[r*64+i] * A[r*64+j];
        symA[idx] = s;
    } else if (b < 657) {
        // FB build: 256 (l,mtile,ks) combos, 4 per block
        int combo = (b-593)*4 + (t >> 6);
        int l = combo >> 7, rest = combo & 127;   // rest = mtile*16 + ks
        int mtile = rest >> 4, kstep = rest & 15;
        int lane = t & 63, l31 = lane & 31, lhi = lane >> 5;
        const float* src = Wd + l*65536 + (mtile*32 + l31)*256 + kstep*16 + lhi*8;
        unsigned short* dst = FB + l*131072 + ((mtile*16 + kstep)*2)*512 + lane*8;
        #pragma unroll
        for (int e = 0; e < 8; ++e) {
            float x = src[e];
            unsigned short h = f2bfu(x);
            dst[e]       = h;
            dst[512 + e] = f2bfu(x - bfu2f(h));
        }
    } else {
        // FA build: 2048 lane-slots, 256 per block
        int q = (b-657)*256 + t;            // [0,2048)
        int tl = q & 63, frag = q >> 6;     // frag = dh*16+ks in [0,32)
        int d  = (frag >> 4)*32 + (tl & 31);
        int m0 = (frag & 15)*16 + (tl >> 5)*8;
        float* dst = FA + q*8;
        #pragma unroll
        for (int e = 0; e < 8; ++e)
            dst[e] = (d == 63) ? 0.f : W0[(m0 + e)*64 + d];
    }
}

// ---------------- fused forward chain: opening + pre0 + pre1 ----------------
__global__ void k_fwd(const float* __restrict__ x, const float* __restrict__ W0T,
                      const float* __restrict__ b0, const float* __restrict__ Wd0T,
                      const float* __restrict__ Wd1T, const float* __restrict__ bd,
                      float* __restrict__ tanhopen, float* __restrict__ tp0,
                      float* __restrict__ tp1) {
    __shared__ float xs[8*64];
    __shared__ float u0s[8*256];
    __shared__ float u1s[8*256];
    int n0 = blockIdx.x * 8, t = threadIdx.x;
    #pragma unroll
    for (int i = 0; i < 2; i++) { int f = t + i*256; xs[f] = x[n0*64 + f]; }
    __syncthreads();
    float acc[8];
    float b = b0[t];
    #pragma unroll
    for (int j = 0; j < 8; j++) acc[j] = b;
    for (int c = 0; c < 64; c++) {
        float w = W0T[c*256 + t];
        #pragma unroll
        for (int j = 0; j < 8; j++) acc[j] += w * xs[j*64 + c];
    }
    #pragma unroll
    for (int j = 0; j < 8; j++) {
        float p = acc[j];
        tanhopen[(n0+j)*256 + t] = tanhf(p);
        float a = fabsf(p);
        u0s[j*256 + t] = a + log1pf(expf(-2.f*a));
    }
    __syncthreads();
    b = bd[t];
    #pragma unroll
    for (int j = 0; j < 8; j++) acc[j] = b;
    for (int k = 0; k < 256; k++) {
        float w = Wd0T[k*256 + t];
        #pragma unroll
        for (int j = 0; j < 8; j++) acc[j] += w * u0s[j*256 + k];
    }
    #pragma unroll
    for (int j = 0; j < 8; j++) {
        float p = acc[j];
        tp0[(n0+j)*256 + t] = tanhf(p);
        float a = fabsf(p);
        u1s[j*256 + t] = u0s[j*256 + t] + 0.5f*(a + log1pf(expf(-2.f*a)));
    }
    __syncthreads();
    b = bd[256 + t];
    #pragma unroll
    for (int j = 0; j < 8; j++) acc[j] = b;
    for (int k = 0; k < 256; k++) {
        float w = Wd1T[k*256 + t];
        #pragma unroll
        for (int j = 0; j < 8; j++) acc[j] += w * u1s[j*256 + k];
    }
    #pragma unroll
    for (int j = 0; j < 8; j++) tp1[(n0+j)*256 + t] = tanhf(acc[j]);
}

// ---------------- fused backward chain: z2 + z1 + grad ----------------
__global__ void k_bwd(const float* __restrict__ tanhopen, const float* __restrict__ tp0,
                      const float* __restrict__ tp1, const float* __restrict__ wv,
                      const float* __restrict__ Wd, const float* __restrict__ W0,
                      const float* __restrict__ symA, const float* __restrict__ x,
                      const float* __restrict__ cw,
                      float* __restrict__ z2T, float* __restrict__ z1T,
                      float* __restrict__ out) {
    __shared__ float coefs[8*256];
    __shared__ float z2s[8*256];
    __shared__ float sa[64*64];
    __shared__ float xs[8*64];
    __shared__ float cws[64];
    const float* Wd0 = Wd;
    const float* Wd1 = Wd + 65536;
    int n0 = blockIdx.x * 8, t = threadIdx.x;
    float wvt = wv[t];
    #pragma unroll
    for (int j = 0; j < 8; j++) coefs[j*256 + t] = tp1[(n0+j)*256 + t] * wvt;
    #pragma unroll
    for (int i = 0; i < 16; i++) { int f = t + i*256; sa[f] = symA[f]; }
    #pragma unroll
    for (int i = 0; i < 2; i++) { int f = t + i*256; xs[f] = x[n0*64 + f]; }
    if (t < 64) cws[t] = cw[t];
    __syncthreads();
    float acc[8];
    #pragma unroll
    for (int j = 0; j < 8; j++) acc[j] = 0.f;
    for (int m = 0; m < 256; m++) {
        float w = Wd1[m*256 + t];
        #pragma unroll
        for (int j = 0; j < 8; j++) acc[j] += w * coefs[j*256 + m];
    }
    #pragma unroll
    for (int j = 0; j < 8; j++) {
        float v = wvt + 0.5f*acc[j];
        z2s[j*256 + t] = v;
        z2T[(n0+j)*256 + t] = v;
    }
    __syncthreads();
    #pragma unroll
    for (int j = 0; j < 8; j++) coefs[j*256 + t] = tp0[(n0+j)*256 + t] * z2s[j*256 + t];
    __syncthreads();
    #pragma unroll
    for (int j = 0; j < 8; j++) acc[j] = 0.f;
    for (int m = 0; m < 256; m++) {
        float w = Wd0[m*256 + t];
        #pragma unroll
        for (int j = 0; j < 8; j++) acc[j] += w * coefs[j*256 + m];
    }
    #pragma unroll
    for (int j = 0; j < 8; j++) {
        float v = z2s[j*256 + t] + 0.5f*acc[j];
        z2s[j*256 + t] = v;
        z1T[(n0+j)*256 + t] = v;
    }
    __syncthreads();
    #pragma unroll
    for (int j = 0; j < 8; j++) coefs[j*256 + t] = tanhopen[(n0+j)*256 + t] * z2s[j*256 + t];
    __syncthreads();
    int c = t & 63, jj = t >> 6;
    float g[2] = {0.f, 0.f};
    for (int m = 0; m < 256; m++) {
        float w0v = W0[m*64 + c];
        #pragma unroll
        for (int jb = 0; jb < 2; jb++) g[jb] += coefs[(jj + jb*4)*256 + m] * w0v;
    }
    #pragma unroll
    for (int jb = 0; jb < 2; jb++) {
        int j = jj + jb*4;
        float g2 = 0.f;
        for (int jd = 0; jd < 64; jd++) g2 += sa[jd*64 + c] * xs[j*64 + jd];
        out[(n0+j)*64 + c] = g[jb] + g2 + cws[c];
    }
}

// ---------------- heavy Jacobian kernel: KJ = Wd @ Jac, 2 ex/block ----------------
// 512 threads (8 waves), 2 examples/block, 2048 blocks.
// A = Wd hi/lo from FB (L2-resident, lane&31 = m-row); B = Jac bf16 in LDS
// (lane&31 = d-col, frag = (ex*2+dh)*16+ks). Wave w: mg = w>>1 owns m-tiles
// {2mg,2mg+1}; dg = w&1 owns example dg (both d-halves). acc[2 m][2 dh] x16 = 64 AGPR.
// C/D: col = lane&31 = d&31, row m = mt*32+(r&3)+8*(r>>2)+4*(lane>>5) [m74/m101].
// Inter-layer update: C/D cols align with B-frag cols -> per-thread b64 LDS RMW:
//   element (m,d): frag ks = m>>4, lane' = ((m>>3)&1)*32+(d&31), e = m&7.
__global__ __launch_bounds__(512, 2) void k_heavy_mfma(
        const float* __restrict__ tanhopen, const float* __restrict__ tp0,
        const float* __restrict__ tp1, const float* __restrict__ z2T,
        const float* __restrict__ z1T, const float* __restrict__ wv,
        const float* __restrict__ FA, const unsigned short* __restrict__ FB,
        const float* __restrict__ ksq, const float* __restrict__ trace,
        float* __restrict__ outTrH) {
    __shared__ __align__(16) unsigned short Bf[32768];   // 64 KB: 64 frags x 512
    __shared__ float ss[2][256], tp0s[2][256], w1s[2][256], w2s[2][256];
    __shared__ float red[8][2];
    int n0 = blockIdx.x * 2, t = threadIdx.x;      // t in [0,512)
    int lane = t & 63, w = t >> 6, l31 = lane & 31, lhi = lane >> 5;
    int mg = w >> 1, dg = w & 1;

    float tot0 = 0.f, tot1 = 0.f;
    {
        int e = t >> 8, m = t & 255;
        float sv = tanhopen[(n0+e)*256 + m];
        float a0 = tp0[(n0+e)*256 + m];
        float a1 = tp1[(n0+e)*256 + m];
        ss[e][m] = sv;
        tp0s[e][m] = a0;
        w1s[e][m] = (1.f - a0*a0) * z2T[(n0+e)*256 + m];
        w2s[e][m] = (1.f - a1*a1) * wv[m];
        float part = (1.f - sv*sv) * z1T[(n0+e)*256 + m] * ksq[m];
        if (e == 0) tot0 = part; else tot1 = part;
    }
    __syncthreads();

    // build Bf[frag= (ex*2+dh)*16+ks][tl][e] = bf16( W0T[d][k] * ss[ex][k] )
    #pragma unroll
    for (int i = 0; i < 8; ++i) {
        int q = t + i*512;                  // [0,4096) lane-chunks of short8
        int frag = q >> 6, tl = q & 63;
        int ex = frag >> 5;
        int k0 = (frag & 15)*16 + (tl >> 5)*8;
        const float* fp = FA + ((frag & 31)*64 + tl)*8;
        short8 v8;
        #pragma unroll
        for (int e = 0; e < 8; ++e)
            v8[e] = (short)f2bfu(fp[e] * ss[ex][k0 + e]);
        *reinterpret_cast<short8*>(&Bf[q*8]) = v8;
    }
    __syncthreads();

    floatx16 acc[2][2];   // [m-tile jm][d-half dh]
    int mt0 = mg*2, mt1 = mg*2 + 1;
    float wtot = 0.f;

    // ---------------- layer 0: KJ1 = Wd0 @ Jac ----------------
    #pragma unroll
    for (int jm = 0; jm < 2; ++jm)
        #pragma unroll
        for (int dh = 0; dh < 2; ++dh)
            #pragma unroll
            for (int r = 0; r < 16; ++r) acc[jm][dh][r] = 0.f;

    for (int ks = 0; ks < 16; ++ks) {
        const unsigned short* a0p = FB + ((mt0*16 + ks)*2)*512 + lane*8;
        const unsigned short* a1p = FB + ((mt1*16 + ks)*2)*512 + lane*8;
        short8 A0h = *reinterpret_cast<const short8*>(a0p);
        short8 A0l = *reinterpret_cast<const short8*>(a0p + 512);
        short8 A1h = *reinterpret_cast<const short8*>(a1p);
        short8 A1l = *reinterpret_cast<const short8*>(a1p + 512);
        short8 B0 = *reinterpret_cast<const short8*>(&Bf[(((dg*2+0)*16 + ks)*64 + lane)*8]);
        short8 B1 = *reinterpret_cast<const short8*>(&Bf[(((dg*2+1)*16 + ks)*64 + lane)*8]);
        acc[0][0] = __builtin_amdgcn_mfma_f32_32x32x16_bf16(A0h, B0, acc[0][0], 0, 0, 0);
        acc[0][0] = __builtin_amdgcn_mfma_f32_32x32x16_bf16(A0l, B0, acc[0][0], 0, 0, 0);
        acc[0][1] = __builtin_amdgcn_mfma_f32_32x32x16_bf16(A0h, B1, acc[0][1], 0, 0, 0);
        acc[0][1] = __builtin_amdgcn_mfma_f32_32x32x16_bf16(A0l, B1, acc[0][1], 0, 0, 0);
        acc[1][0] = __builtin_amdgcn_mfma_f32_32x32x16_bf16(A1h, B0, acc[1][0], 0, 0, 0);
        acc[1][0] = __builtin_amdgcn_mfma_f32_32x32x16_bf16(A1l, B0, acc[1][0], 0, 0, 0);
        acc[1][1] = __builtin_amdgcn_mfma_f32_32x32x16_bf16(A1h, B1, acc[1][1], 0, 0, 0);
        acc[1][1] = __builtin_amdgcn_mfma_f32_32x32x16_bf16(A1l, B1, acc[1][1], 0, 0, 0);
    }
    __syncthreads();   // all layer-0 B-reads done before update writes

    // trH layer-1 + Jac update: Jac[m][d] += 0.5*tp0[ex][m]*KJ1[m][d]
    // (b64 RMW; write slot derivation: ks=mt*2+(g>>1), lane'=(g&1)*32+l31, e=q+4*lhi)
    #pragma unroll
    for (int jm = 0; jm < 2; ++jm) {
        int mt = mg*2 + jm;
        #pragma unroll
        for (int g = 0; g < 4; ++g) {
            float w1m[4], tm[4];
            #pragma unroll
            for (int q = 0; q < 4; ++q) {
                int m = mt*32 + 8*g + q + 4*lhi;
                w1m[q] = 0.5f * w1s[dg][m];
                tm[q]  = 0.5f * tp0s[dg][m];
            }
            #pragma unroll
            for (int dh = 0; dh < 2; ++dh) {
                int base = (((dg*2 + dh)*16 + mt*2 + (g >> 1))*64
                            + ((g & 1)*32 + l31))*8 + 4*lhi;
                ushort4v old = *reinterpret_cast<ushort4v*>(&Bf[base]);
                ushort4v nw;
                #pragma unroll
                for (int q = 0; q < 4; ++q) {
                    float v = acc[jm][dh][4*g + q];
                    wtot += w1m[q] * v * v;
                    nw[q] = f2bfu(bfu2f(old[q]) + tm[q] * v);
                }
                *reinterpret_cast<ushort4v*>(&Bf[base]) = nw;
            }
        }
    }
    __syncthreads();   // updates visible before layer-1 reads

    // ---------------- layer 1: KJ2 = Wd1 @ Jac_new ----------------
    #pragma unroll
    for (int jm = 0; jm < 2; ++jm)
        #pragma unroll
        for (int dh = 0; dh < 2; ++dh)
            #pragma unroll
            for (int r = 0; r < 16; ++r) acc[jm][dh][r] = 0.f;

    const unsigned short* FB1 = FB + 131072;
    for (int ks = 0; ks < 16; ++ks) {
        const unsigned short* a0p = FB1 + ((mt0*16 + ks)*2)*512 + lane*8;
        const unsigned short* a1p = FB1 + ((mt1*16 + ks)*2)*512 + lane*8;
        short8 A0h = *reinterpret_cast<const short8*>(a0p);
        short8 A0l = *reinterpret_cast<const short8*>(a0p + 512);
        short8 A1h = *reinterpret_cast<const short8*>(a1p);
        short8 A1l = *reinterpret_cast<const short8*>(a1p + 512);
        short8 B0 = *reinterpret_cast<const short8*>(&Bf[(((dg*2+0)*16 + ks)*64 + lane)*8]);
        short8 B1 = *reinterpret_cast<const short8*>(&Bf[(((dg*2+1)*16 + ks)*64 + lane)*8]);
        acc[0][0] = __builtin_amdgcn_mfma_f32_32x32x16_bf16(A0h, B0, acc[0][0], 0, 0, 0);
        acc[0][0] = __builtin_amdgcn_mfma_f32_32x32x16_bf16(A0l, B0, acc[0][0], 0, 0, 0);
        acc[0][1] = __builtin_amdgcn_mfma_f32_32x32x16_bf16(A0h, B1, acc[0][1], 0, 0, 0);
        acc[0][1] = __builtin_amdgcn_mfma_f32_32x32x16_bf16(A0l, B1, acc[0][1], 0, 0, 0);
        acc[1][0] = __builtin_amdgcn_mfma_f32_32x32x16_bf16(A1h, B0, acc[1][0], 0, 0, 0);
        acc[1][0] = __builtin_amdgcn_mfma_f32_32x32x16_bf16(A1l, B0, acc[1][0], 0, 0, 0);
        acc[1][1] = __builtin_amdgcn_mfma_f32_32x32x16_bf16(A1h, B1, acc[1][1], 0, 0, 0);
        acc[1][1] = __builtin_amdgcn_mfma_f32_32x32x16_bf16(A1l, B1, acc[1][1], 0, 0, 0);
    }

    // trH layer-2 term
    #pragma unroll
    for (int jm = 0; jm < 2; ++jm)
        #pragma unroll
        for (int g = 0; g < 4; ++g)
            #pragma unroll
            for (int q = 0; q < 4; ++q) {
                int m = (mg*2 + jm)*32 + 8*g + q + 4*lhi;
                float w2m = 0.5f * w2s[dg][m];
                float v0 = acc[jm][0][4*g + q], v1 = acc[jm][1][4*g + q];
                wtot += w2m * (v0*v0 + v1*v1);
            }

    if (dg == 0) tot0 += wtot; else tot1 += wtot;

    // reduce 512 -> 2
    #pragma unroll
    for (int off = 32; off; off >>= 1) {
        tot0 += __shfl_down(tot0, off, 64);
        tot1 += __shfl_down(tot1, off, 64);
    }
    if (lane == 0) { red[w][0] = tot0; red[w][1] = tot1; }
    __syncthreads();
    if (t < 2) {
        float s = trace[0];
        #pragma unroll
        for (int i = 0; i < 8; ++i) s += red[i][t];
        outTrH[n0 + t] = s;
    }
}

// ---------------- launcher ----------------

extern "C" void kernel_launch(void* const* d_in, const int* in_sizes, int n_in,
                              void* d_out, int out_size, void* d_ws, size_t ws_size,
                              hipStream_t stream) {
    const float* x   = (const float*)d_in[0];   // 4096*64
    const float* W0  = (const float*)d_in[1];   // 256*64
    const float* b0  = (const float*)d_in[2];   // 256
    const float* Wd  = (const float*)d_in[3];   // 2*256*256
    const float* bd  = (const float*)d_in[4];   // 2*256
    const float* wv  = (const float*)d_in[5];   // 256
    const float* A   = (const float*)d_in[6];   // 10*64
    const float* cw  = (const float*)d_in[7];   // 64
    float* out = (float*)d_out;
    float* ws  = (float*)d_ws;

    float* tanhopen = ws;               // NM
    float* tp0  = tanhopen + NM;        // NM
    float* tp1  = tp0 + NM;             // NM
    float* z2T  = tp1 + NM;             // NM
    float* z1T  = z2T + NM;             // NM
    float* Wd0T = z1T + NM;             // 65536
    float* Wd1T = Wd0T + 65536;         // 65536
    float* W0T  = Wd1T + 65536;         // 16384
    float* symA = W0T + 16384;          // 4096
    float* ksq  = symA + 4096;          // 256
    float* trace= ksq + 256;            // 1
    unsigned short* FB = (unsigned short*)(trace + 1);    // 262144 ushorts (512 KB)
    float* FA = (float*)(FB + 262144);                    // 16384 floats (64 KB)

    k_prep<<<665, 256, 0, stream>>>(Wd, W0, A, FB, FA, Wd0T, Wd1T, W0T,
                                    symA, ksq, trace);
    k_fwd<<<NEX/8, 256, 0, stream>>>(x, W0T, b0, Wd0T, Wd1T, bd,
                                     tanhopen, tp0, tp1);
    k_bwd<<<NEX/8, 256, 0, stream>>>(tanhopen, tp0, tp1, wv, Wd, W0, symA, x, cw,
                                     z2T, z1T, out);
    k_heavy_mfma<<<NEX/2, 512, 0, stream>>>(tanhopen, tp0, tp1, z2T, z1T, wv,
                                            FA, FB, ksq, trace, out + NEX*64);
}

// Round 11
// 192.176 us; speedup vs baseline: 2.2436x; 1.2067x over previous
//
#include <hip/hip_runtime.h>
#include <hip/hip_bf16.h>

#define NEX 4096
#define M   256
#define NM  (NEX*M)

typedef __attribute__((ext_vector_type(8))) short short8;
typedef __attribute__((ext_vector_type(16))) float floatx16;
typedef __attribute__((ext_vector_type(4))) unsigned short ushort4v;

__device__ inline unsigned short f2bfu(float x) {
    __hip_bfloat16 h = __float2bfloat16(x);
    union { __hip_bfloat16 b; unsigned short u; } cv; cv.b = h;
    return cv.u;
}
__device__ inline float bfu2f(unsigned short u) {
    union { unsigned short u; __hip_bfloat16 b; } cv; cv.u = u;
    return __bfloat162float(cv.b);
}

// ---------------- fused prep kernel ----------------
// b in [0,256): Wd0T ; [256,512): Wd1T ; [512,576): W0T
// b == 576: ksq + trace ; [577,593): symA ; [593,657): FB ; [657,665): FA
//
// FB (ushort), layer l stride 65536: chunk (mtile in [0,8), ks in [0,16)) of 512:
//   FB[l*65536 + (mtile*16+ks)*512 + lane*8 + e]
//     = bf16( Wd[l][mtile*32 + (lane&31)][ks*16 + (lane>>5)*8 + e] )
// Used as the 32x32x16 MFMA **A-operand** (lane&31 = row m, lane>>5 = k-half).
// FA (f32): W0T in fragment order with row d=63 zeroed:
//   FA[((dh*16+ks)*64 + tl)*8 + e] = W0T[dh*32+(tl&31)][ks*16+(tl>>5)*8+e]
__global__ void k_prep(const float* __restrict__ Wd, const float* __restrict__ W0,
                       const float* __restrict__ A,
                       unsigned short* __restrict__ FB, float* __restrict__ FA,
                       float* __restrict__ Wd0T, float* __restrict__ Wd1T,
                       float* __restrict__ W0T, float* __restrict__ symA,
                       float* __restrict__ ksq, float* __restrict__ trace) {
    int b = blockIdx.x, t = threadIdx.x;
    if (b < 256) {
        int idx = b*256 + t;                // dst index c*256+r
        int c = idx >> 8, r = idx & 255;
        Wd0T[idx] = Wd[r*256 + c];
    } else if (b < 512) {
        int idx = (b-256)*256 + t;
        int c = idx >> 8, r = idx & 255;
        Wd1T[idx] = Wd[65536 + r*256 + c];
    } else if (b < 576) {
        int idx = (b-512)*256 + t;          // 16384 entries: c*256+r, c<64
        int c = idx >> 8, r = idx & 255;
        W0T[idx] = W0[r*64 + c];
    } else if (b == 576) {
        float s = 0.f;
        for (int dd = 0; dd < 63; dd++) { float v = W0[t*64+dd]; s += v*v; }
        ksq[t] = s;
        float p = 0.f;
        for (int idx = t; idx < 630; idx += 256) {
            int r = idx / 63, i = idx % 63;
            float v = A[r*64+i]; p += v*v;
        }
        for (int off = 32; off; off >>= 1) p += __shfl_down(p, off, 64);
        __shared__ float red[4];
        if ((t & 63) == 0) red[t >> 6] = p;
        __syncthreads();
        if (t == 0) trace[0] = red[0]+red[1]+red[2]+red[3];
    } else if (b < 593) {
        int idx = (b-577)*256 + t;          // 4096 entries
        int i = idx >> 6, j = idx & 63;
        float s = 0.f;
        #pragma unroll
        for (int r = 0; r < 10; r++) s += A[r*64+i] * A[r*64+j];
        symA[idx] = s;
    } else if (b < 657) {
        // FB build: 256 (l,mtile,ks) combos, 4 per block
        int combo = (b-593)*4 + (t >> 6);
        int l = combo >> 7, rest = combo & 127;   // rest = mtile*16 + ks
        int mtile = rest >> 4, kstep = rest & 15;
        int lane = t & 63, l31 = lane & 31, lhi = lane >> 5;
        const float* src = Wd + l*65536 + (mtile*32 + l31)*256 + kstep*16 + lhi*8;
        unsigned short* dst = FB + l*65536 + (mtile*16 + kstep)*512 + lane*8;
        #pragma unroll
        for (int e = 0; e < 8; ++e) dst[e] = f2bfu(src[e]);
    } else {
        // FA build: 2048 lane-slots, 256 per block
        int q = (b-657)*256 + t;            // [0,2048)
        int tl = q & 63, frag = q >> 6;     // frag = dh*16+ks in [0,32)
        int d  = (frag >> 4)*32 + (tl & 31);
        int m0 = (frag & 15)*16 + (tl >> 5)*8;
        float* dst = FA + q*8;
        #pragma unroll
        for (int e = 0; e < 8; ++e)
            dst[e] = (d == 63) ? 0.f : W0[(m0 + e)*64 + d];
    }
}

// ---------------- fused forward chain: opening + pre0 + pre1 ----------------
__global__ void k_fwd(const float* __restrict__ x, const float* __restrict__ W0T,
                      const float* __restrict__ b0, const float* __restrict__ Wd0T,
                      const float* __restrict__ Wd1T, const float* __restrict__ bd,
                      float* __restrict__ tanhopen, float* __restrict__ tp0,
                      float* __restrict__ tp1) {
    __shared__ float xs[8*64];
    __shared__ float u0s[8*256];
    __shared__ float u1s[8*256];
    int n0 = blockIdx.x * 8, t = threadIdx.x;
    #pragma unroll
    for (int i = 0; i < 2; i++) { int f = t + i*256; xs[f] = x[n0*64 + f]; }
    __syncthreads();
    float acc[8];
    float b = b0[t];
    #pragma unroll
    for (int j = 0; j < 8; j++) acc[j] = b;
    for (int c = 0; c < 64; c++) {
        float w = W0T[c*256 + t];
        #pragma unroll
        for (int j = 0; j < 8; j++) acc[j] += w * xs[j*64 + c];
    }
    #pragma unroll
    for (int j = 0; j < 8; j++) {
        float p = acc[j];
        tanhopen[(n0+j)*256 + t] = tanhf(p);
        float a = fabsf(p);
        u0s[j*256 + t] = a + log1pf(expf(-2.f*a));
    }
    __syncthreads();
    b = bd[t];
    #pragma unroll
    for (int j = 0; j < 8; j++) acc[j] = b;
    for (int k = 0; k < 256; k++) {
        float w = Wd0T[k*256 + t];
        #pragma unroll
        for (int j = 0; j < 8; j++) acc[j] += w * u0s[j*256 + k];
    }
    #pragma unroll
    for (int j = 0; j < 8; j++) {
        float p = acc[j];
        tp0[(n0+j)*256 + t] = tanhf(p);
        float a = fabsf(p);
        u1s[j*256 + t] = u0s[j*256 + t] + 0.5f*(a + log1pf(expf(-2.f*a)));
    }
    __syncthreads();
    b = bd[256 + t];
    #pragma unroll
    for (int j = 0; j < 8; j++) acc[j] = b;
    for (int k = 0; k < 256; k++) {
        float w = Wd1T[k*256 + t];
        #pragma unroll
        for (int j = 0; j < 8; j++) acc[j] += w * u1s[j*256 + k];
    }
    #pragma unroll
    for (int j = 0; j < 8; j++) tp1[(n0+j)*256 + t] = tanhf(acc[j]);
}

// ---------------- fused backward chain: z2 + z1 + grad ----------------
__global__ void k_bwd(const float* __restrict__ tanhopen, const float* __restrict__ tp0,
                      const float* __restrict__ tp1, const float* __restrict__ wv,
                      const float* __restrict__ Wd, const float* __restrict__ W0,
                      const float* __restrict__ symA, const float* __restrict__ x,
                      const float* __restrict__ cw,
                      float* __restrict__ z2T, float* __restrict__ z1T,
                      float* __restrict__ out) {
    __shared__ float coefs[8*256];
    __shared__ float z2s[8*256];
    __shared__ float sa[64*64];
    __shared__ float xs[8*64];
    __shared__ float cws[64];
    const float* Wd0 = Wd;
    const float* Wd1 = Wd + 65536;
    int n0 = blockIdx.x * 8, t = threadIdx.x;
    float wvt = wv[t];
    #pragma unroll
    for (int j = 0; j < 8; j++) coefs[j*256 + t] = tp1[(n0+j)*256 + t] * wvt;
    #pragma unroll
    for (int i = 0; i < 16; i++) { int f = t + i*256; sa[f] = symA[f]; }
    #pragma unroll
    for (int i = 0; i < 2; i++) { int f = t + i*256; xs[f] = x[n0*64 + f]; }
    if (t < 64) cws[t] = cw[t];
    __syncthreads();
    float acc[8];
    #pragma unroll
    for (int j = 0; j < 8; j++) acc[j] = 0.f;
    for (int m = 0; m < 256; m++) {
        float w = Wd1[m*256 + t];
        #pragma unroll
        for (int j = 0; j < 8; j++) acc[j] += w * coefs[j*256 + m];
    }
    #pragma unroll
    for (int j = 0; j < 8; j++) {
        float v = wvt + 0.5f*acc[j];
        z2s[j*256 + t] = v;
        z2T[(n0+j)*256 + t] = v;
    }
    __syncthreads();
    #pragma unroll
    for (int j = 0; j < 8; j++) coefs[j*256 + t] = tp0[(n0+j)*256 + t] * z2s[j*256 + t];
    __syncthreads();
    #pragma unroll
    for (int j = 0; j < 8; j++) acc[j] = 0.f;
    for (int m = 0; m < 256; m++) {
        float w = Wd0[m*256 + t];
        #pragma unroll
        for (int j = 0; j < 8; j++) acc[j] += w * coefs[j*256 + m];
    }
    #pragma unroll
    for (int j = 0; j < 8; j++) {
        float v = z2s[j*256 + t] + 0.5f*acc[j];
        z2s[j*256 + t] = v;
        z1T[(n0+j)*256 + t] = v;
    }
    __syncthreads();
    #pragma unroll
    for (int j = 0; j < 8; j++) coefs[j*256 + t] = tanhopen[(n0+j)*256 + t] * z2s[j*256 + t];
    __syncthreads();
    int c = t & 63, jj = t >> 6;
    float g[2] = {0.f, 0.f};
    for (int m = 0; m < 256; m++) {
        float w0v = W0[m*64 + c];
        #pragma unroll
        for (int jb = 0; jb < 2; jb++) g[jb] += coefs[(jj + jb*4)*256 + m] * w0v;
    }
    #pragma unroll
    for (int jb = 0; jb < 2; jb++) {
        int j = jj + jb*4;
        float g2 = 0.f;
        for (int jd = 0; jd < 64; jd++) g2 += sa[jd*64 + c] * xs[j*64 + jd];
        out[(n0+j)*64 + c] = g[jb] + g2 + cws[c];
    }
}

// ---------------- heavy Jacobian kernel: KJ = Wd @ Jac, 2 ex/block, bf16 Wd ----------------
// 512 threads (8 waves), 2 examples/block, 2048 blocks.
// A = Wd bf16 from FB (L2-resident, lane&31 = m-row); B = Jac bf16 in LDS
// (lane&31 = d-col, frag = (ex*2+dh)*16+ks). Wave w: mg = w>>1 owns m-tiles
// {2mg,2mg+1}; dg = w&1 owns example dg (both d-halves). acc[2 m][2 dh] x16 = 64 AGPR.
// C/D: col = lane&31 = d&31, row m = mt*32+(r&3)+8*(r>>2)+4*(lane>>5) [m74/m101].
// Inter-layer update: C/D cols align with B-frag cols -> per-thread b64 LDS RMW:
//   element (m,d): frag ks = m>>4, lane' = ((m>>3)&1)*32+(d&31), e = m&7.
__global__ __launch_bounds__(512, 2) void k_heavy_mfma(
        const float* __restrict__ tanhopen, const float* __restrict__ tp0,
        const float* __restrict__ tp1, const float* __restrict__ z2T,
        const float* __restrict__ z1T, const float* __restrict__ wv,
        const float* __restrict__ FA, const unsigned short* __restrict__ FB,
        const float* __restrict__ ksq, const float* __restrict__ trace,
        float* __restrict__ outTrH) {
    __shared__ __align__(16) unsigned short Bf[32768];   // 64 KB: 64 frags x 512
    __shared__ float ss[2][256], tp0s[2][256], w1s[2][256], w2s[2][256];
    __shared__ float red[8][2];
    int n0 = blockIdx.x * 2, t = threadIdx.x;      // t in [0,512)
    int lane = t & 63, w = t >> 6, l31 = lane & 31, lhi = lane >> 5;
    int mg = w >> 1, dg = w & 1;

    float tot0 = 0.f, tot1 = 0.f;
    {
        int e = t >> 8, m = t & 255;
        float sv = tanhopen[(n0+e)*256 + m];
        float a0 = tp0[(n0+e)*256 + m];
        float a1 = tp1[(n0+e)*256 + m];
        ss[e][m] = sv;
        tp0s[e][m] = a0;
        w1s[e][m] = (1.f - a0*a0) * z2T[(n0+e)*256 + m];
        w2s[e][m] = (1.f - a1*a1) * wv[m];
        float part = (1.f - sv*sv) * z1T[(n0+e)*256 + m] * ksq[m];
        if (e == 0) tot0 = part; else tot1 = part;
    }
    __syncthreads();

    // build Bf[frag= (ex*2+dh)*16+ks][tl][e] = bf16( W0T[d][k] * ss[ex][k] )
    #pragma unroll
    for (int i = 0; i < 8; ++i) {
        int q = t + i*512;                  // [0,4096) lane-chunks of short8
        int frag = q >> 6, tl = q & 63;
        int ex = frag >> 5;
        int k0 = (frag & 15)*16 + (tl >> 5)*8;
        const float* fp = FA + ((frag & 31)*64 + tl)*8;
        short8 v8;
        #pragma unroll
        for (int e = 0; e < 8; ++e)
            v8[e] = (short)f2bfu(fp[e] * ss[ex][k0 + e]);
        *reinterpret_cast<short8*>(&Bf[q*8]) = v8;
    }
    __syncthreads();

    floatx16 acc[2][2];   // [m-tile jm][d-half dh]
    int mt0 = mg*2, mt1 = mg*2 + 1;
    float wtot = 0.f;

    // ---------------- layer 0: KJ1 = Wd0 @ Jac ----------------
    #pragma unroll
    for (int jm = 0; jm < 2; ++jm)
        #pragma unroll
        for (int dh = 0; dh < 2; ++dh)
            #pragma unroll
            for (int r = 0; r < 16; ++r) acc[jm][dh][r] = 0.f;

    for (int ks = 0; ks < 16; ++ks) {
        short8 A0 = *reinterpret_cast<const short8*>(FB + (mt0*16 + ks)*512 + lane*8);
        short8 A1 = *reinterpret_cast<const short8*>(FB + (mt1*16 + ks)*512 + lane*8);
        short8 B0 = *reinterpret_cast<const short8*>(&Bf[(((dg*2+0)*16 + ks)*64 + lane)*8]);
        short8 B1 = *reinterpret_cast<const short8*>(&Bf[(((dg*2+1)*16 + ks)*64 + lane)*8]);
        acc[0][0] = __builtin_amdgcn_mfma_f32_32x32x16_bf16(A0, B0, acc[0][0], 0, 0, 0);
        acc[0][1] = __builtin_amdgcn_mfma_f32_32x32x16_bf16(A0, B1, acc[0][1], 0, 0, 0);
        acc[1][0] = __builtin_amdgcn_mfma_f32_32x32x16_bf16(A1, B0, acc[1][0], 0, 0, 0);
        acc[1][1] = __builtin_amdgcn_mfma_f32_32x32x16_bf16(A1, B1, acc[1][1], 0, 0, 0);
    }
    __syncthreads();   // all layer-0 B-reads done before update writes

    // trH layer-1 + Jac update: Jac[m][d] += 0.5*tp0[ex][m]*KJ1[m][d]
    // (b64 RMW; write slot: ks=mt*2+(g>>1), lane'=(g&1)*32+l31, e=q+4*lhi)
    #pragma unroll
    for (int jm = 0; jm < 2; ++jm) {
        int mt = mg*2 + jm;
        #pragma unroll
        for (int g = 0; g < 4; ++g) {
            float w1m[4], tm[4];
            #pragma unroll
            for (int q = 0; q < 4; ++q) {
                int m = mt*32 + 8*g + q + 4*lhi;
                w1m[q] = 0.5f * w1s[dg][m];
                tm[q]  = 0.5f * tp0s[dg][m];
            }
            #pragma unroll
            for (int dh = 0; dh < 2; ++dh) {
                int base = (((dg*2 + dh)*16 + mt*2 + (g >> 1))*64
                            + ((g & 1)*32 + l31))*8 + 4*lhi;
                ushort4v old = *reinterpret_cast<ushort4v*>(&Bf[base]);
                ushort4v nw;
                #pragma unroll
                for (int q = 0; q < 4; ++q) {
                    float v = acc[jm][dh][4*g + q];
                    wtot += w1m[q] * v * v;
                    nw[q] = f2bfu(bfu2f(old[q]) + tm[q] * v);
                }
                *reinterpret_cast<ushort4v*>(&Bf[base]) = nw;
            }
        }
    }
    __syncthreads();   // updates visible before layer-1 reads

    // ---------------- layer 1: KJ2 = Wd1 @ Jac_new ----------------
    #pragma unroll
    for (int jm = 0; jm < 2; ++jm)
        #pragma unroll
        for (int dh = 0; dh < 2; ++dh)
            #pragma unroll
            for (int r = 0; r < 16; ++r) acc[jm][dh][r] = 0.f;

    const unsigned short* FB1 = FB + 65536;
    for (int ks = 0; ks < 16; ++ks) {
        short8 A0 = *reinterpret_cast<const short8*>(FB1 + (mt0*16 + ks)*512 + lane*8);
        short8 A1 = *reinterpret_cast<const short8*>(FB1 + (mt1*16 + ks)*512 + lane*8);
        short8 B0 = *reinterpret_cast<const short8*>(&Bf[(((dg*2+0)*16 + ks)*64 + lane)*8]);
        short8 B1 = *reinterpret_cast<const short8*>(&Bf[(((dg*2+1)*16 + ks)*64 + lane)*8]);
        acc[0][0] = __builtin_amdgcn_mfma_f32_32x32x16_bf16(A0, B0, acc[0][0], 0, 0, 0);
        acc[0][1] = __builtin_amdgcn_mfma_f32_32x32x16_bf16(A0, B1, acc[0][1], 0, 0, 0);
        acc[1][0] = __builtin_amdgcn_mfma_f32_32x32x16_bf16(A1, B0, acc[1][0], 0, 0, 0);
        acc[1][1] = __builtin_amdgcn_mfma_f32_32x32x16_bf16(A1, B1, acc[1][1], 0, 0, 0);
    }

    // trH layer-2 term
    #pragma unroll
    for (int jm = 0; jm < 2; ++jm)
        #pragma unroll
        for (int g = 0; g < 4; ++g)
            #pragma unroll
            for (int q = 0; q < 4; ++q) {
                int m = (mg*2 + jm)*32 + 8*g + q + 4*lhi;
                float w2m = 0.5f * w2s[dg][m];
                float v0 = acc[jm][0][4*g + q], v1 = acc[jm][1][4*g + q];
                wtot += w2m * (v0*v0 + v1*v1);
            }

    if (dg == 0) tot0 += wtot; else tot1 += wtot;

    // reduce 512 -> 2
    #pragma unroll
    for (int off = 32; off; off >>= 1) {
        tot0 += __shfl_down(tot0, off, 64);
        tot1 += __shfl_down(tot1, off, 64);
    }
    if (lane == 0) { red[w][0] = tot0; red[w][1] = tot1; }
    __syncthreads();
    if (t < 2) {
        float s = trace[0];
        #pragma unroll
        for (int i = 0; i < 8; ++i) s += red[i][t];
        outTrH[n0 + t] = s;
    }
}

// ---------------- launcher ----------------

extern "C" void kernel_launch(void* const* d_in, const int* in_sizes, int n_in,
                              void* d_out, int out_size, void* d_ws, size_t ws_size,
                              hipStream_t stream) {
    const float* x   = (const float*)d_in[0];   // 4096*64
    const float* W0  = (const float*)d_in[1];   // 256*64
    const float* b0  = (const float*)d_in[2];   // 256
    const float* Wd  = (const float*)d_in[3];   // 2*256*256
    const float* bd  = (const float*)d_in[4];   // 2*256
    const float* wv  = (const float*)d_in[5];   // 256
    const float* A   = (const float*)d_in[6];   // 10*64
    const float* cw  = (const float*)d_in[7];   // 64
    float* out = (float*)d_out;
    float* ws  = (float*)d_ws;

    float* tanhopen = ws;               // NM
    float* tp0  = tanhopen + NM;        // NM
    float* tp1  = tp0 + NM;             // NM
    float* z2T  = tp1 + NM;             // NM
    float* z1T  = z2T + NM;             // NM
    float* Wd0T = z1T + NM;             // 65536
    float* Wd1T = Wd0T + 65536;         // 65536
    float* W0T  = Wd1T + 65536;         // 16384
    float* symA = W0T + 16384;          // 4096
    float* ksq  = symA + 4096;          // 256
    float* trace= ksq + 256;            // 1
    unsigned short* FB = (unsigned short*)(trace + 1);    // 131072 ushorts (256 KB)
    float* FA = (float*)(FB + 131072);                    // 16384 floats (64 KB)

    k_prep<<<665, 256, 0, stream>>>(Wd, W0, A, FB, FA, Wd0T, Wd1T, W0T,
                                    symA, ksq, trace);
    k_fwd<<<NEX/8, 256, 0, stream>>>(x, W0T, b0, Wd0T, Wd1T, bd,
                                     tanhopen, tp0, tp1);
    k_bwd<<<NEX/8, 256, 0, stream>>>(tanhopen, tp0, tp1, wv, Wd, W0, symA, x, cw,
                                     z2T, z1T, out);
    k_heavy_mfma<<<NEX/2, 512, 0, stream>>>(tanhopen, tp0, tp1, z2T, z1T, wv,
                                            FA, FB, ksq, trace, out + NEX*64);
}

// Round 12
// 161.397 us; speedup vs baseline: 2.6714x; 1.1907x over previous
//
#include <hip/hip_runtime.h>
#include <hip/hip_bf16.h>

#define NEX 4096
#define M   256
#define NM  (NEX*M)

typedef __attribute__((ext_vector_type(8))) short short8;
typedef __attribute__((ext_vector_type(16))) float floatx16;
typedef __attribute__((ext_vector_type(4))) unsigned short ushort4v;

__device__ inline unsigned short f2bfu(float x) {
    __hip_bfloat16 h = __float2bfloat16(x);
    union { __hip_bfloat16 b; unsigned short u; } cv; cv.b = h;
    return cv.u;
}
__device__ inline float bfu2f(unsigned short u) {
    union { unsigned short u; __hip_bfloat16 b; } cv; cv.u = u;
    return __bfloat162float(cv.b);
}

// ---------------- fused prep kernel ----------------
// Fragment convention (32x32x16 MFMA, verified rounds 8-11):
//   A-frag slot: lane&31 = C-row, k = ks*16 + (lane>>5)*8 + e
//   B-frag slot: lane&31 = C-col, k = ks*16 + (lane>>5)*8 + e
//   C/D: col = lane&31, row = (r&3) + 8*(r>>2) + 4*(lane>>5)
// Buffers (hi/lo split; "h" = bf16(v), "l" = bf16(v - h)):
//   FBh/FBl  [l][mt*16+ks]: Wd[l][mt*32+l31][ks*16+lhi*8+e]      (k_heavy uses FBh)
//   FBTh/FBTl[l][kt*16+ms]: Wd[l][ms*16+lhi*8+e][kt*32+l31]      (transposed)
//   FW0h/l   [mt*4+ks]:     W0[mt*32+l31][ks*16+lhi*8+e]
//   FWTh/l   [ct*16+ms]:    W0[ms*16+lhi*8+e][ct*32+l31]
//   FSAh/l   [ct*4+ks]:     symA[ct*32+l31][ks*16+lhi*8+e]
//   FA (f32) [frag*64+tl]:  W0T fragment-ordered, row d=63 zeroed (k_heavy Bf build)
__global__ void k_prep(const float* __restrict__ Wd, const float* __restrict__ W0,
                       const float* __restrict__ A,
                       unsigned short* __restrict__ FBh, unsigned short* __restrict__ FBl,
                       unsigned short* __restrict__ FBTh, unsigned short* __restrict__ FBTl,
                       unsigned short* __restrict__ FW0h, unsigned short* __restrict__ FW0l,
                       unsigned short* __restrict__ FWTh, unsigned short* __restrict__ FWTl,
                       unsigned short* __restrict__ FSAh, unsigned short* __restrict__ FSAl,
                       float* __restrict__ FA,
                       float* __restrict__ ksq, float* __restrict__ trace) {
    int b = blockIdx.x, t = threadIdx.x;
    int lane = t & 63, l31 = lane & 31, lhi = lane >> 5;
    if (b < 64) {
        // FB: 256 combos (l, mtile, kstep)
        int combo = b*4 + (t >> 6);
        int l = combo >> 7, rest = combo & 127;
        int mtile = rest >> 4, kstep = rest & 15;
        const float* src = Wd + l*65536 + (mtile*32 + l31)*256 + kstep*16 + lhi*8;
        int off = l*65536 + (mtile*16 + kstep)*512 + lane*8;
        #pragma unroll
        for (int e = 0; e < 8; ++e) {
            float v = src[e];
            unsigned short h = f2bfu(v);
            FBh[off+e] = h;
            FBl[off+e] = f2bfu(v - bfu2f(h));
        }
    } else if (b < 128) {
        // FBT: 256 combos (l, ktile, ms)
        int combo = (b-64)*4 + (t >> 6);
        int l = combo >> 7, rest = combo & 127;
        int kt = rest >> 4, ms = rest & 15;
        const float* src = Wd + l*65536 + (ms*16 + lhi*8)*256 + kt*32 + l31;
        int off = l*65536 + (kt*16 + ms)*512 + lane*8;
        #pragma unroll
        for (int e = 0; e < 8; ++e) {
            float v = src[e*256];
            unsigned short h = f2bfu(v);
            FBTh[off+e] = h;
            FBTl[off+e] = f2bfu(v - bfu2f(h));
        }
    } else if (b < 136) {
        // FW0: 32 combos (mt, ks)
        int combo = (b-128)*4 + (t >> 6);
        int mt = combo >> 2, ks = combo & 3;
        const float* src = W0 + (mt*32 + l31)*64 + ks*16 + lhi*8;
        int off = combo*512 + lane*8;
        #pragma unroll
        for (int e = 0; e < 8; ++e) {
            float v = src[e];
            unsigned short h = f2bfu(v);
            FW0h[off+e] = h;
            FW0l[off+e] = f2bfu(v - bfu2f(h));
        }
    } else if (b < 144) {
        // FWT: 32 combos (ct, ms)
        int combo = (b-136)*4 + (t >> 6);
        int ct = combo >> 4, ms = combo & 15;
        const float* src = W0 + (ms*16 + lhi*8)*64 + ct*32 + l31;
        int off = combo*512 + lane*8;
        #pragma unroll
        for (int e = 0; e < 8; ++e) {
            float v = src[e*64];
            unsigned short h = f2bfu(v);
            FWTh[off+e] = h;
            FWTl[off+e] = f2bfu(v - bfu2f(h));
        }
    } else if (b < 146) {
        // FSA: 8 combos (ct, ks); symA computed inline from A
        int combo = (b-144)*4 + (t >> 6);
        int ct = combo >> 2, ks = combo & 3;
        int c = ct*32 + l31;
        int off = combo*512 + lane*8;
        #pragma unroll
        for (int e = 0; e < 8; ++e) {
            int j = ks*16 + lhi*8 + e;
            float s = 0.f;
            #pragma unroll
            for (int r = 0; r < 10; ++r) s += A[r*64+c] * A[r*64+j];
            unsigned short h = f2bfu(s);
            FSAh[off+e] = h;
            FSAl[off+e] = f2bfu(s - bfu2f(h));
        }
    } else if (b == 146) {
        float s = 0.f;
        for (int dd = 0; dd < 63; dd++) { float v = W0[t*64+dd]; s += v*v; }
        ksq[t] = s;
        float p = 0.f;
        for (int idx = t; idx < 630; idx += 256) {
            int r = idx / 63, i = idx % 63;
            float v = A[r*64+i]; p += v*v;
        }
        for (int off = 32; off; off >>= 1) p += __shfl_down(p, off, 64);
        __shared__ float red[4];
        if ((t & 63) == 0) red[t >> 6] = p;
        __syncthreads();
        if (t == 0) trace[0] = red[0]+red[1]+red[2]+red[3];
    } else {
        // FA build: 2048 lane-slots, 256 per block
        int q = (b-147)*256 + t;            // [0,2048)
        int tl = q & 63, frag = q >> 6;     // frag = dh*16+ks in [0,32)
        int d  = (frag >> 4)*32 + (tl & 31);
        int m0 = (frag & 15)*16 + (tl >> 5)*8;
        float* dst = FA + q*8;
        #pragma unroll
        for (int e = 0; e < 8; ++e)
            dst[e] = (d == 63) ? 0.f : W0[(m0 + e)*64 + d];
    }
}

// ---------------- fused fwd+bwd MFMA kernel: 32 examples/block ----------------
// 512 threads (8 waves), 128 blocks. Wave w owns unit-tile mt = w (rows w*32..w*32+31)
// for all M=256 GEMMs; C cols = 32 examples. hi/lo on both operands (3-MFMA scheme).
// Chain: opening -> pre0 -> pre1 -> z2 (FBT1) -> z1 (FBT0) -> grad (FWT + FSA).
// Inter-GEMM B-frag rebuild uses the k_heavy RMW slot math; stores via LDS bounce.
__global__ __launch_bounds__(512, 2) void k_fb(
        const float* __restrict__ x, const float* __restrict__ b0,
        const float* __restrict__ bd, const float* __restrict__ wv,
        const float* __restrict__ cw,
        const unsigned short* __restrict__ FW0h, const unsigned short* __restrict__ FW0l,
        const unsigned short* __restrict__ FBh, const unsigned short* __restrict__ FBl,
        const unsigned short* __restrict__ FBTh, const unsigned short* __restrict__ FBTl,
        const unsigned short* __restrict__ FWTh, const unsigned short* __restrict__ FWTl,
        const unsigned short* __restrict__ FSAh, const unsigned short* __restrict__ FSAl,
        float* __restrict__ tanhopen, float* __restrict__ tp0g,
        float* __restrict__ tp1g, float* __restrict__ z2T, float* __restrict__ z1T,
        float* __restrict__ out) {
    __shared__ __align__(16) unsigned short Buh[8192], Bul[8192];   // 16ks x 512, 32 KB
    __shared__ __align__(16) unsigned short Bxh[2048], Bxl[2048];   // 4ks x 512, 8 KB
    __shared__ __align__(16) float bounce[8224];                    // 32*257 / gpart 8*32*32
    __shared__ float b0s[256], bd0s[256], bd1s[256], wvs[256], cws[64];
    int n0 = blockIdx.x * 32, t = threadIdx.x;
    int lane = t & 63, w = t >> 6, l31 = lane & 31, lhi = lane >> 5;

    if (t < 256) { b0s[t]=b0[t]; bd0s[t]=bd[t]; bd1s[t]=bd[256+t]; wvs[t]=wv[t]; }
    if (t < 64) cws[t] = cw[t];
    if (t < 256) {
        // Bx build: t = ks*64 + tl
        int tl = t & 63;
        int ex = tl & 31, k0 = (t >> 6)*16 + (tl >> 5)*8;
        const float* xp = x + (n0+ex)*64 + k0;
        short8 h8, l8;
        #pragma unroll
        for (int e = 0; e < 8; ++e) {
            float v = xp[e];
            unsigned short h = f2bfu(v);
            h8[e] = (short)h; l8[e] = (short)f2bfu(v - bfu2f(h));
        }
        *reinterpret_cast<short8*>(&Bxh[t*8]) = h8;
        *reinterpret_cast<short8*>(&Bxl[t*8]) = l8;
    }
    __syncthreads();

#define MROW(r) (w*32 + ((r)&3) + 8*((r)>>2) + 4*lhi)

#define MFMA3(AH, AL, BH, BL) do { \
    acc = __builtin_amdgcn_mfma_f32_32x32x16_bf16(AH, BH, acc, 0, 0, 0); \
    acc = __builtin_amdgcn_mfma_f32_32x32x16_bf16(AH, BL, acc, 0, 0, 0); \
    acc = __builtin_amdgcn_mfma_f32_32x32x16_bf16(AL, BH, acc, 0, 0, 0); \
} while (0)

#define GEMM256(PH, PL) do { \
    for (int ks = 0; ks < 16; ++ks) { \
        short8 Ah = *reinterpret_cast<const short8*>(PH + (w*16+ks)*512 + lane*8); \
        short8 Al = *reinterpret_cast<const short8*>(PL + (w*16+ks)*512 + lane*8); \
        short8 Bh = *reinterpret_cast<const short8*>(&Buh[(ks*64+lane)*8]); \
        short8 Bl = *reinterpret_cast<const short8*>(&Bul[(ks*64+lane)*8]); \
        MFMA3(Ah, Al, Bh, Bl); \
    } \
} while (0)

// write val[16] -> bounce -> coalesced global store to DST ([ex][m] layout)
#define STORE_PASS(VAL, DST) do { \
    _Pragma("unroll") \
    for (int r = 0; r < 16; ++r) bounce[l31*257 + MROW(r)] = VAL[r]; \
    __syncthreads(); \
    _Pragma("unroll") \
    for (int i = 0; i < 16; ++i) { \
        int f = t + i*512; int ex_ = f >> 8, m_ = f & 255; \
        DST[(n0+ex_)*256 + m_] = bounce[ex_*257 + m_]; \
    } \
    __syncthreads(); \
} while (0)

// rebuild Bu frags (hi/lo) from val[16] (C-layout -> B-frag slots, k_heavy RMW math)
#define BUILD_BU(VAL) do { \
    _Pragma("unroll") \
    for (int g = 0; g < 4; ++g) { \
        int ks_ = w*2 + (g>>1); \
        int lp_ = (g&1)*32 + l31; \
        int base_ = (ks_*64 + lp_)*8 + 4*lhi; \
        ushort4v h4, l4; \
        _Pragma("unroll") \
        for (int q = 0; q < 4; ++q) { \
            float v_ = VAL[g*4+q]; \
            unsigned short h_ = f2bfu(v_); \
            h4[q] = h_; l4[q] = f2bfu(v_ - bfu2f(h_)); \
        } \
        *reinterpret_cast<ushort4v*>(&Buh[base_]) = h4; \
        *reinterpret_cast<ushort4v*>(&Bul[base_]) = l4; \
    } \
    __syncthreads(); \
} while (0)

    floatx16 acc;
    float sv[16], u0v[16], tp0v[16], z2v[16], cf[16];

    // ---- opening (K=64, A=FW0, B=Bx) ----
    #pragma unroll
    for (int r = 0; r < 16; ++r) acc[r] = 0.f;
    #pragma unroll
    for (int ks = 0; ks < 4; ++ks) {
        short8 Ah = *reinterpret_cast<const short8*>(FW0h + (w*4+ks)*512 + lane*8);
        short8 Al = *reinterpret_cast<const short8*>(FW0l + (w*4+ks)*512 + lane*8);
        short8 Bh = *reinterpret_cast<const short8*>(&Bxh[(ks*64+lane)*8]);
        short8 Bl = *reinterpret_cast<const short8*>(&Bxl[(ks*64+lane)*8]);
        MFMA3(Ah, Al, Bh, Bl);
    }
    #pragma unroll
    for (int r = 0; r < 16; ++r) {
        float p = acc[r] + b0s[MROW(r)];
        sv[r] = tanhf(p);
        float a = fabsf(p);
        u0v[r] = a + log1pf(expf(-2.f*a));
    }
    STORE_PASS(sv, tanhopen);
    BUILD_BU(u0v);

    // ---- pre0 (A=FB layer0, B=u0) ----
    #pragma unroll
    for (int r = 0; r < 16; ++r) acc[r] = 0.f;
    GEMM256(FBh, FBl);
    #pragma unroll
    for (int r = 0; r < 16; ++r) {
        float p = acc[r] + bd0s[MROW(r)];
        tp0v[r] = tanhf(p);
        float a = fabsf(p);
        u0v[r] += 0.5f*(a + log1pf(expf(-2.f*a)));   // now u1
    }
    STORE_PASS(tp0v, tp0g);
    BUILD_BU(u0v);

    // ---- pre1 (A=FB layer1, B=u1) ----
    #pragma unroll
    for (int r = 0; r < 16; ++r) acc[r] = 0.f;
    GEMM256(FBh + 65536, FBl + 65536);
    #pragma unroll
    for (int r = 0; r < 16; ++r) cf[r] = tanhf(acc[r] + bd1s[MROW(r)]);
    STORE_PASS(cf, tp1g);
    #pragma unroll
    for (int r = 0; r < 16; ++r) cf[r] *= wvs[MROW(r)];   // coef2 = tp1*wv
    BUILD_BU(cf);

    // ---- z2 (A=FBT layer1, B=coef2) ----
    #pragma unroll
    for (int r = 0; r < 16; ++r) acc[r] = 0.f;
    GEMM256(FBTh + 65536, FBTl + 65536);
    #pragma unroll
    for (int r = 0; r < 16; ++r) z2v[r] = wvs[MROW(r)] + 0.5f*acc[r];
    STORE_PASS(z2v, z2T);
    #pragma unroll
    for (int r = 0; r < 16; ++r) cf[r] = tp0v[r] * z2v[r];   // coef1
    BUILD_BU(cf);

    // ---- z1 (A=FBT layer0, B=coef1) ----
    #pragma unroll
    for (int r = 0; r < 16; ++r) acc[r] = 0.f;
    GEMM256(FBTh, FBTl);
    #pragma unroll
    for (int r = 0; r < 16; ++r) z2v[r] += 0.5f*acc[r];      // now z1
    STORE_PASS(z2v, z1T);
    #pragma unroll
    for (int r = 0; r < 16; ++r) cf[r] = sv[r] * z2v[r];     // coef0
    BUILD_BU(cf);

    // ---- grad (A=FWT over coef0, + FSA over x), K-split across waves ----
    {
        int ct = w >> 2, seg = w & 3;
        #pragma unroll
        for (int r = 0; r < 16; ++r) acc[r] = 0.f;
        #pragma unroll
        for (int k2 = 0; k2 < 4; ++k2) {
            int ms = seg*4 + k2;
            short8 Ah = *reinterpret_cast<const short8*>(FWTh + (ct*16+ms)*512 + lane*8);
            short8 Al = *reinterpret_cast<const short8*>(FWTl + (ct*16+ms)*512 + lane*8);
            short8 Bh = *reinterpret_cast<const short8*>(&Buh[(ms*64+lane)*8]);
            short8 Bl = *reinterpret_cast<const short8*>(&Bul[(ms*64+lane)*8]);
            MFMA3(Ah, Al, Bh, Bl);
        }
        if (seg == 0) {
            #pragma unroll
            for (int ks = 0; ks < 4; ++ks) {
                short8 Ah = *reinterpret_cast<const short8*>(FSAh + (ct*4+ks)*512 + lane*8);
                short8 Al = *reinterpret_cast<const short8*>(FSAl + (ct*4+ks)*512 + lane*8);
                short8 Bh = *reinterpret_cast<const short8*>(&Bxh[(ks*64+lane)*8]);
                short8 Bl = *reinterpret_cast<const short8*>(&Bxl[(ks*64+lane)*8]);
                MFMA3(Ah, Al, Bh, Bl);
            }
        }
        float* gpart = bounce;   // [8][32][32]
        #pragma unroll
        for (int r = 0; r < 16; ++r) gpart[w*1024 + (2*r+lhi)*32 + l31] = acc[r];
        __syncthreads();
        // combine 4 K-segments + cw, coalesced b128 store
        int o0 = t*4, ex = o0 >> 6, c0 = o0 & 63;
        float4 gv;
        #pragma unroll
        for (int jj = 0; jj < 4; ++jj) {
            int c = c0 + jj;
            int ctx = c >> 5, cr = c & 31;
            int lh = (cr >> 2) & 1;
            int rr = (cr & 3) | ((cr >> 3) << 2);
            float s = cws[c];
            #pragma unroll
            for (int sg = 0; sg < 4; ++sg)
                s += gpart[(ctx*4+sg)*1024 + (2*rr+lh)*32 + ex];
            gv[jj] = s;
        }
        *reinterpret_cast<float4*>(&out[(n0+ex)*64 + c0]) = gv;
    }
#undef MROW
#undef MFMA3
#undef GEMM256
#undef STORE_PASS
#undef BUILD_BU
}

// ---------------- heavy Jacobian kernel (unchanged from round 11) ----------------
__global__ __launch_bounds__(512, 2) void k_heavy_mfma(
        const float* __restrict__ tanhopen, const float* __restrict__ tp0,
        const float* __restrict__ tp1, const float* __restrict__ z2T,
        const float* __restrict__ z1T, const float* __restrict__ wv,
        const float* __restrict__ FA, const unsigned short* __restrict__ FB,
        const float* __restrict__ ksq, const float* __restrict__ trace,
        float* __restrict__ outTrH) {
    __shared__ __align__(16) unsigned short Bf[32768];   // 64 KB: 64 frags x 512
    __shared__ float ss[2][256], tp0s[2][256], w1s[2][256], w2s[2][256];
    __shared__ float red[8][2];
    int n0 = blockIdx.x * 2, t = threadIdx.x;      // t in [0,512)
    int lane = t & 63, w = t >> 6, l31 = lane & 31, lhi = lane >> 5;
    int mg = w >> 1, dg = w & 1;

    float tot0 = 0.f, tot1 = 0.f;
    {
        int e = t >> 8, m = t & 255;
        float sv = tanhopen[(n0+e)*256 + m];
        float a0 = tp0[(n0+e)*256 + m];
        float a1 = tp1[(n0+e)*256 + m];
        ss[e][m] = sv;
        tp0s[e][m] = a0;
        w1s[e][m] = (1.f - a0*a0) * z2T[(n0+e)*256 + m];
        w2s[e][m] = (1.f - a1*a1) * wv[m];
        float part = (1.f - sv*sv) * z1T[(n0+e)*256 + m] * ksq[m];
        if (e == 0) tot0 = part; else tot1 = part;
    }
    __syncthreads();

    // build Bf[frag= (ex*2+dh)*16+ks][tl][e] = bf16( W0T[d][k] * ss[ex][k] )
    #pragma unroll
    for (int i = 0; i < 8; ++i) {
        int q = t + i*512;                  // [0,4096) lane-chunks of short8
        int frag = q >> 6, tl = q & 63;
        int ex = frag >> 5;
        int k0 = (frag & 15)*16 + (tl >> 5)*8;
        const float* fp = FA + ((frag & 31)*64 + tl)*8;
        short8 v8;
        #pragma unroll
        for (int e = 0; e < 8; ++e)
            v8[e] = (short)f2bfu(fp[e] * ss[ex][k0 + e]);
        *reinterpret_cast<short8*>(&Bf[q*8]) = v8;
    }
    __syncthreads();

    floatx16 acc[2][2];   // [m-tile jm][d-half dh]
    int mt0 = mg*2, mt1 = mg*2 + 1;
    float wtot = 0.f;

    // ---------------- layer 0: KJ1 = Wd0 @ Jac ----------------
    #pragma unroll
    for (int jm = 0; jm < 2; ++jm)
        #pragma unroll
        for (int dh = 0; dh < 2; ++dh)
            #pragma unroll
            for (int r = 0; r < 16; ++r) acc[jm][dh][r] = 0.f;

    for (int ks = 0; ks < 16; ++ks) {
        short8 A0 = *reinterpret_cast<const short8*>(FB + (mt0*16 + ks)*512 + lane*8);
        short8 A1 = *reinterpret_cast<const short8*>(FB + (mt1*16 + ks)*512 + lane*8);
        short8 B0 = *reinterpret_cast<const short8*>(&Bf[(((dg*2+0)*16 + ks)*64 + lane)*8]);
        short8 B1 = *reinterpret_cast<const short8*>(&Bf[(((dg*2+1)*16 + ks)*64 + lane)*8]);
        acc[0][0] = __builtin_amdgcn_mfma_f32_32x32x16_bf16(A0, B0, acc[0][0], 0, 0, 0);
        acc[0][1] = __builtin_amdgcn_mfma_f32_32x32x16_bf16(A0, B1, acc[0][1], 0, 0, 0);
        acc[1][0] = __builtin_amdgcn_mfma_f32_32x32x16_bf16(A1, B0, acc[1][0], 0, 0, 0);
        acc[1][1] = __builtin_amdgcn_mfma_f32_32x32x16_bf16(A1, B1, acc[1][1], 0, 0, 0);
    }
    __syncthreads();   // all layer-0 B-reads done before update writes

    // trH layer-1 + Jac update: Jac[m][d] += 0.5*tp0[ex][m]*KJ1[m][d]
    #pragma unroll
    for (int jm = 0; jm < 2; ++jm) {
        int mt = mg*2 + jm;
        #pragma unroll
        for (int g = 0; g < 4; ++g) {
            float w1m[4], tm[4];
            #pragma unroll
            for (int q = 0; q < 4; ++q) {
                int m = mt*32 + 8*g + q + 4*lhi;
                w1m[q] = 0.5f * w1s[dg][m];
                tm[q]  = 0.5f * tp0s[dg][m];
            }
            #pragma unroll
            for (int dh = 0; dh < 2; ++dh) {
                int base = (((dg*2 + dh)*16 + mt*2 + (g >> 1))*64
                            + ((g & 1)*32 + l31))*8 + 4*lhi;
                ushort4v old = *reinterpret_cast<ushort4v*>(&Bf[base]);
                ushort4v nw;
                #pragma unroll
                for (int q = 0; q < 4; ++q) {
                    float v = acc[jm][dh][4*g + q];
                    wtot += w1m[q] * v * v;
                    nw[q] = f2bfu(bfu2f(old[q]) + tm[q] * v);
                }
                *reinterpret_cast<ushort4v*>(&Bf[base]) = nw;
            }
        }
    }
    __syncthreads();   // updates visible before layer-1 reads

    // ---------------- layer 1: KJ2 = Wd1 @ Jac_new ----------------
    #pragma unroll
    for (int jm = 0; jm < 2; ++jm)
        #pragma unroll
        for (int dh = 0; dh < 2; ++dh)
            #pragma unroll
            for (int r = 0; r < 16; ++r) acc[jm][dh][r] = 0.f;

    const unsigned short* FB1 = FB + 65536;
    for (int ks = 0; ks < 16; ++ks) {
        short8 A0 = *reinterpret_cast<const short8*>(FB1 + (mt0*16 + ks)*512 + lane*8);
        short8 A1 = *reinterpret_cast<const short8*>(FB1 + (mt1*16 + ks)*512 + lane*8);
        short8 B0 = *reinterpret_cast<const short8*>(&Bf[(((dg*2+0)*16 + ks)*64 + lane)*8]);
        short8 B1 = *reinterpret_cast<const short8*>(&Bf[(((dg*2+1)*16 + ks)*64 + lane)*8]);
        acc[0][0] = __builtin_amdgcn_mfma_f32_32x32x16_bf16(A0, B0, acc[0][0], 0, 0, 0);
        acc[0][1] = __builtin_amdgcn_mfma_f32_32x32x16_bf16(A0, B1, acc[0][1], 0, 0, 0);
        acc[1][0] = __builtin_amdgcn_mfma_f32_32x32x16_bf16(A1, B0, acc[1][0], 0, 0, 0);
        acc[1][1] = __builtin_amdgcn_mfma_f32_32x32x16_bf16(A1, B1, acc[1][1], 0, 0, 0);
    }

    // trH layer-2 term
    #pragma unroll
    for (int jm = 0; jm < 2; ++jm)
        #pragma unroll
        for (int g = 0; g < 4; ++g)
            #pragma unroll
            for (int q = 0; q < 4; ++q) {
                int m = (mg*2 + jm)*32 + 8*g + q + 4*lhi;
                float w2m = 0.5f * w2s[dg][m];
                float v0 = acc[jm][0][4*g + q], v1 = acc[jm][1][4*g + q];
                wtot += w2m * (v0*v0 + v1*v1);
            }

    if (dg == 0) tot0 += wtot; else tot1 += wtot;

    // reduce 512 -> 2
    #pragma unroll
    for (int off = 32; off; off >>= 1) {
        tot0 += __shfl_down(tot0, off, 64);
        tot1 += __shfl_down(tot1, off, 64);
    }
    if (lane == 0) { red[w][0] = tot0; red[w][1] = tot1; }
    __syncthreads();
    if (t < 2) {
        float s = trace[0];
        #pragma unroll
        for (int i = 0; i < 8; ++i) s += red[i][t];
        outTrH[n0 + t] = s;
    }
}

// ---------------- launcher ----------------

extern "C" void kernel_launch(void* const* d_in, const int* in_sizes, int n_in,
                              void* d_out, int out_size, void* d_ws, size_t ws_size,
                              hipStream_t stream) {
    const float* x   = (const float*)d_in[0];   // 4096*64
    const float* W0  = (const float*)d_in[1];   // 256*64
    const float* b0  = (const float*)d_in[2];   // 256
    const float* Wd  = (const float*)d_in[3];   // 2*256*256
    const float* bd  = (const float*)d_in[4];   // 2*256
    const float* wv  = (const float*)d_in[5];   // 256
    const float* A   = (const float*)d_in[6];   // 10*64
    const float* cw  = (const float*)d_in[7];   // 64
    float* out = (float*)d_out;
    float* ws  = (float*)d_ws;

    float* tanhopen = ws;               // NM
    float* tp0  = tanhopen + NM;        // NM
    float* tp1  = tp0 + NM;             // NM
    float* z2T  = tp1 + NM;             // NM
    float* z1T  = z2T + NM;             // NM
    float* FA   = z1T + NM;             // 16384
    float* ksq  = FA + 16384;           // 256
    float* trace= ksq + 256;            // 4 (padded for alignment)
    unsigned short* FBh  = (unsigned short*)(trace + 4);  // 131072
    unsigned short* FBl  = FBh + 131072;
    unsigned short* FBTh = FBl + 131072;
    unsigned short* FBTl = FBTh + 131072;
    unsigned short* FW0h = FBTl + 131072;                 // 16384
    unsigned short* FW0l = FW0h + 16384;
    unsigned short* FWTh = FW0l + 16384;                  // 16384
    unsigned short* FWTl = FWTh + 16384;
    unsigned short* FSAh = FWTl + 16384;                  // 4096
    unsigned short* FSAl = FSAh + 4096;

    k_prep<<<155, 256, 0, stream>>>(Wd, W0, A, FBh, FBl, FBTh, FBTl,
                                    FW0h, FW0l, FWTh, FWTl, FSAh, FSAl,
                                    FA, ksq, trace);
    k_fb<<<NEX/32, 512, 0, stream>>>(x, b0, bd, wv, cw,
                                     FW0h, FW0l, FBh, FBl, FBTh, FBTl,
                                     FWTh, FWTl, FSAh, FSAl,
                                     tanhopen, tp0, tp1, z2T, z1T, out);
    k_heavy_mfma<<<NEX/2, 512, 0, stream>>>(tanhopen, tp0, tp1, z2T, z1T, wv,
                                            FA, FBh, ksq, trace, out + NEX*64);
}

// Round 13
// 147.901 us; speedup vs baseline: 2.9152x; 1.0912x over previous
//
#include <hip/hip_runtime.h>
#include <hip/hip_bf16.h>

#define NEX 4096
#define M   256
#define NM  (NEX*M)

typedef __attribute__((ext_vector_type(8))) short short8;
typedef __attribute__((ext_vector_type(16))) float floatx16;
typedef __attribute__((ext_vector_type(4))) unsigned short ushort4v;

__device__ inline unsigned short f2bfu(float x) {
    __hip_bfloat16 h = __float2bfloat16(x);
    union { __hip_bfloat16 b; unsigned short u; } cv; cv.b = h;
    return cv.u;
}
__device__ inline float bfu2f(unsigned short u) {
    union { unsigned short u; __hip_bfloat16 b; } cv; cv.u = u;
    return __bfloat162float(cv.b);
}

// ---------------- fused prep kernel ----------------
// Fragment convention (32x32x16 MFMA, verified rounds 8-12):
//   A-frag slot: lane&31 = C-row, k = ks*16 + (lane>>5)*8 + e
//   B-frag slot: lane&31 = C-col, k = ks*16 + (lane>>5)*8 + e
//   C/D: col = lane&31, row = (r&3) + 8*(r>>2) + 4*(lane>>5)
__global__ void k_prep(const float* __restrict__ Wd, const float* __restrict__ W0,
                       const float* __restrict__ A,
                       unsigned short* __restrict__ FBh, unsigned short* __restrict__ FBl,
                       unsigned short* __restrict__ FBTh, unsigned short* __restrict__ FBTl,
                       unsigned short* __restrict__ FW0h, unsigned short* __restrict__ FW0l,
                       unsigned short* __restrict__ FWTh, unsigned short* __restrict__ FWTl,
                       unsigned short* __restrict__ FSAh, unsigned short* __restrict__ FSAl,
                       float* __restrict__ FA,
                       float* __restrict__ ksq, float* __restrict__ trace) {
    int b = blockIdx.x, t = threadIdx.x;
    int lane = t & 63, l31 = lane & 31, lhi = lane >> 5;
    if (b < 64) {
        // FB: 256 combos (l, mtile, kstep)
        int combo = b*4 + (t >> 6);
        int l = combo >> 7, rest = combo & 127;
        int mtile = rest >> 4, kstep = rest & 15;
        const float* src = Wd + l*65536 + (mtile*32 + l31)*256 + kstep*16 + lhi*8;
        int off = l*65536 + (mtile*16 + kstep)*512 + lane*8;
        #pragma unroll
        for (int e = 0; e < 8; ++e) {
            float v = src[e];
            unsigned short h = f2bfu(v);
            FBh[off+e] = h;
            FBl[off+e] = f2bfu(v - bfu2f(h));
        }
    } else if (b < 128) {
        // FBT: 256 combos (l, ktile, ms)
        int combo = (b-64)*4 + (t >> 6);
        int l = combo >> 7, rest = combo & 127;
        int kt = rest >> 4, ms = rest & 15;
        const float* src = Wd + l*65536 + (ms*16 + lhi*8)*256 + kt*32 + l31;
        int off = l*65536 + (kt*16 + ms)*512 + lane*8;
        #pragma unroll
        for (int e = 0; e < 8; ++e) {
            float v = src[e*256];
            unsigned short h = f2bfu(v);
            FBTh[off+e] = h;
            FBTl[off+e] = f2bfu(v - bfu2f(h));
        }
    } else if (b < 136) {
        // FW0: 32 combos (mt, ks)
        int combo = (b-128)*4 + (t >> 6);
        int mt = combo >> 2, ks = combo & 3;
        const float* src = W0 + (mt*32 + l31)*64 + ks*16 + lhi*8;
        int off = combo*512 + lane*8;
        #pragma unroll
        for (int e = 0; e < 8; ++e) {
            float v = src[e];
            unsigned short h = f2bfu(v);
            FW0h[off+e] = h;
            FW0l[off+e] = f2bfu(v - bfu2f(h));
        }
    } else if (b < 144) {
        // FWT: 32 combos (ct, ms)
        int combo = (b-136)*4 + (t >> 6);
        int ct = combo >> 4, ms = combo & 15;
        const float* src = W0 + (ms*16 + lhi*8)*64 + ct*32 + l31;
        int off = combo*512 + lane*8;
        #pragma unroll
        for (int e = 0; e < 8; ++e) {
            float v = src[e*64];
            unsigned short h = f2bfu(v);
            FWTh[off+e] = h;
            FWTl[off+e] = f2bfu(v - bfu2f(h));
        }
    } else if (b < 146) {
        // FSA: 8 combos (ct, ks); symA computed inline from A
        int combo = (b-144)*4 + (t >> 6);
        int ct = combo >> 2, ks = combo & 3;
        int c = ct*32 + l31;
        int off = combo*512 + lane*8;
        #pragma unroll
        for (int e = 0; e < 8; ++e) {
            int j = ks*16 + lhi*8 + e;
            float s = 0.f;
            #pragma unroll
            for (int r = 0; r < 10; ++r) s += A[r*64+c] * A[r*64+j];
            unsigned short h = f2bfu(s);
            FSAh[off+e] = h;
            FSAl[off+e] = f2bfu(s - bfu2f(h));
        }
    } else if (b == 146) {
        float s = 0.f;
        for (int dd = 0; dd < 63; dd++) { float v = W0[t*64+dd]; s += v*v; }
        ksq[t] = s;
        float p = 0.f;
        for (int idx = t; idx < 630; idx += 256) {
            int r = idx / 63, i = idx % 63;
            float v = A[r*64+i]; p += v*v;
        }
        for (int off = 32; off; off >>= 1) p += __shfl_down(p, off, 64);
        __shared__ float red[4];
        if ((t & 63) == 0) red[t >> 6] = p;
        __syncthreads();
        if (t == 0) trace[0] = red[0]+red[1]+red[2]+red[3];
    } else {
        // FA build: 2048 lane-slots, 256 per block
        int q = (b-147)*256 + t;            // [0,2048)
        int tl = q & 63, frag = q >> 6;     // frag = dh*16+ks in [0,32)
        int d  = (frag >> 4)*32 + (tl & 31);
        int m0 = (frag & 15)*16 + (tl >> 5)*8;
        float* dst = FA + q*8;
        #pragma unroll
        for (int e = 0; e < 8; ++e)
            dst[e] = (d == 63) ? 0.f : W0[(m0 + e)*64 + d];
    }
}

// ---------------- fused fwd+bwd MFMA kernel: 32 examples/block ----------------
__global__ __launch_bounds__(512, 2) void k_fb(
        const float* __restrict__ x, const float* __restrict__ b0,
        const float* __restrict__ bd, const float* __restrict__ wv,
        const float* __restrict__ cw,
        const unsigned short* __restrict__ FW0h, const unsigned short* __restrict__ FW0l,
        const unsigned short* __restrict__ FBh, const unsigned short* __restrict__ FBl,
        const unsigned short* __restrict__ FBTh, const unsigned short* __restrict__ FBTl,
        const unsigned short* __restrict__ FWTh, const unsigned short* __restrict__ FWTl,
        const unsigned short* __restrict__ FSAh, const unsigned short* __restrict__ FSAl,
        float* __restrict__ tanhopen, float* __restrict__ tp0g,
        float* __restrict__ tp1g, float* __restrict__ z2T, float* __restrict__ z1T,
        float* __restrict__ out) {
    __shared__ __align__(16) unsigned short Buh[8192], Bul[8192];   // 16ks x 512, 32 KB
    __shared__ __align__(16) unsigned short Bxh[2048], Bxl[2048];   // 4ks x 512, 8 KB
    __shared__ __align__(16) float bounce[8224];                    // 32*257 / gpart 8*32*32
    __shared__ float b0s[256], bd0s[256], bd1s[256], wvs[256], cws[64];
    int n0 = blockIdx.x * 32, t = threadIdx.x;
    int lane = t & 63, w = t >> 6, l31 = lane & 31, lhi = lane >> 5;

    if (t < 256) { b0s[t]=b0[t]; bd0s[t]=bd[t]; bd1s[t]=bd[256+t]; wvs[t]=wv[t]; }
    if (t < 64) cws[t] = cw[t];
    if (t < 256) {
        // Bx build: t = ks*64 + tl
        int tl = t & 63;
        int ex = tl & 31, k0 = (t >> 6)*16 + (tl >> 5)*8;
        const float* xp = x + (n0+ex)*64 + k0;
        short8 h8, l8;
        #pragma unroll
        for (int e = 0; e < 8; ++e) {
            float v = xp[e];
            unsigned short h = f2bfu(v);
            h8[e] = (short)h; l8[e] = (short)f2bfu(v - bfu2f(h));
        }
        *reinterpret_cast<short8*>(&Bxh[t*8]) = h8;
        *reinterpret_cast<short8*>(&Bxl[t*8]) = l8;
    }
    __syncthreads();

#define MROW(r) (w*32 + ((r)&3) + 8*((r)>>2) + 4*lhi)

#define MFMA3(AH, AL, BH, BL) do { \
    acc = __builtin_amdgcn_mfma_f32_32x32x16_bf16(AH, BH, acc, 0, 0, 0); \
    acc = __builtin_amdgcn_mfma_f32_32x32x16_bf16(AH, BL, acc, 0, 0, 0); \
    acc = __builtin_amdgcn_mfma_f32_32x32x16_bf16(AL, BH, acc, 0, 0, 0); \
} while (0)

#define GEMM256(PH, PL) do { \
    for (int ks = 0; ks < 16; ++ks) { \
        short8 Ah = *reinterpret_cast<const short8*>(PH + (w*16+ks)*512 + lane*8); \
        short8 Al = *reinterpret_cast<const short8*>(PL + (w*16+ks)*512 + lane*8); \
        short8 Bh = *reinterpret_cast<const short8*>(&Buh[(ks*64+lane)*8]); \
        short8 Bl = *reinterpret_cast<const short8*>(&Bul[(ks*64+lane)*8]); \
        MFMA3(Ah, Al, Bh, Bl); \
    } \
} while (0)

#define STORE_PASS(VAL, DST) do { \
    _Pragma("unroll") \
    for (int r = 0; r < 16; ++r) bounce[l31*257 + MROW(r)] = VAL[r]; \
    __syncthreads(); \
    _Pragma("unroll") \
    for (int i = 0; i < 16; ++i) { \
        int f = t + i*512; int ex_ = f >> 8, m_ = f & 255; \
        DST[(n0+ex_)*256 + m_] = bounce[ex_*257 + m_]; \
    } \
    __syncthreads(); \
} while (0)

#define BUILD_BU(VAL) do { \
    _Pragma("unroll") \
    for (int g = 0; g < 4; ++g) { \
        int ks_ = w*2 + (g>>1); \
        int lp_ = (g&1)*32 + l31; \
        int base_ = (ks_*64 + lp_)*8 + 4*lhi; \
        ushort4v h4, l4; \
        _Pragma("unroll") \
        for (int q = 0; q < 4; ++q) { \
            float v_ = VAL[g*4+q]; \
            unsigned short h_ = f2bfu(v_); \
            h4[q] = h_; l4[q] = f2bfu(v_ - bfu2f(h_)); \
        } \
        *reinterpret_cast<ushort4v*>(&Buh[base_]) = h4; \
        *reinterpret_cast<ushort4v*>(&Bul[base_]) = l4; \
    } \
    __syncthreads(); \
} while (0)

    floatx16 acc;
    float sv[16], u0v[16], tp0v[16], z2v[16], cf[16];

    // ---- opening (K=64, A=FW0, B=Bx) ----
    #pragma unroll
    for (int r = 0; r < 16; ++r) acc[r] = 0.f;
    #pragma unroll
    for (int ks = 0; ks < 4; ++ks) {
        short8 Ah = *reinterpret_cast<const short8*>(FW0h + (w*4+ks)*512 + lane*8);
        short8 Al = *reinterpret_cast<const short8*>(FW0l + (w*4+ks)*512 + lane*8);
        short8 Bh = *reinterpret_cast<const short8*>(&Bxh[(ks*64+lane)*8]);
        short8 Bl = *reinterpret_cast<const short8*>(&Bxl[(ks*64+lane)*8]);
        MFMA3(Ah, Al, Bh, Bl);
    }
    #pragma unroll
    for (int r = 0; r < 16; ++r) {
        float p = acc[r] + b0s[MROW(r)];
        sv[r] = tanhf(p);
        float a = fabsf(p);
        u0v[r] = a + log1pf(expf(-2.f*a));
    }
    STORE_PASS(sv, tanhopen);
    BUILD_BU(u0v);

    // ---- pre0 (A=FB layer0, B=u0) ----
    #pragma unroll
    for (int r = 0; r < 16; ++r) acc[r] = 0.f;
    GEMM256(FBh, FBl);
    #pragma unroll
    for (int r = 0; r < 16; ++r) {
        float p = acc[r] + bd0s[MROW(r)];
        tp0v[r] = tanhf(p);
        float a = fabsf(p);
        u0v[r] += 0.5f*(a + log1pf(expf(-2.f*a)));   // now u1
    }
    STORE_PASS(tp0v, tp0g);
    BUILD_BU(u0v);

    // ---- pre1 (A=FB layer1, B=u1) ----
    #pragma unroll
    for (int r = 0; r < 16; ++r) acc[r] = 0.f;
    GEMM256(FBh + 65536, FBl + 65536);
    #pragma unroll
    for (int r = 0; r < 16; ++r) cf[r] = tanhf(acc[r] + bd1s[MROW(r)]);
    STORE_PASS(cf, tp1g);
    #pragma unroll
    for (int r = 0; r < 16; ++r) cf[r] *= wvs[MROW(r)];   // coef2 = tp1*wv
    BUILD_BU(cf);

    // ---- z2 (A=FBT layer1, B=coef2) ----
    #pragma unroll
    for (int r = 0; r < 16; ++r) acc[r] = 0.f;
    GEMM256(FBTh + 65536, FBTl + 65536);
    #pragma unroll
    for (int r = 0; r < 16; ++r) z2v[r] = wvs[MROW(r)] + 0.5f*acc[r];
    STORE_PASS(z2v, z2T);
    #pragma unroll
    for (int r = 0; r < 16; ++r) cf[r] = tp0v[r] * z2v[r];   // coef1
    BUILD_BU(cf);

    // ---- z1 (A=FBT layer0, B=coef1) ----
    #pragma unroll
    for (int r = 0; r < 16; ++r) acc[r] = 0.f;
    GEMM256(FBTh, FBTl);
    #pragma unroll
    for (int r = 0; r < 16; ++r) z2v[r] += 0.5f*acc[r];      // now z1
    STORE_PASS(z2v, z1T);
    #pragma unroll
    for (int r = 0; r < 16; ++r) cf[r] = sv[r] * z2v[r];     // coef0
    BUILD_BU(cf);

    // ---- grad (A=FWT over coef0, + FSA over x), K-split across waves ----
    {
        int ct = w >> 2, seg = w & 3;
        #pragma unroll
        for (int r = 0; r < 16; ++r) acc[r] = 0.f;
        #pragma unroll
        for (int k2 = 0; k2 < 4; ++k2) {
            int ms = seg*4 + k2;
            short8 Ah = *reinterpret_cast<const short8*>(FWTh + (ct*16+ms)*512 + lane*8);
            short8 Al = *reinterpret_cast<const short8*>(FWTl + (ct*16+ms)*512 + lane*8);
            short8 Bh = *reinterpret_cast<const short8*>(&Buh[(ms*64+lane)*8]);
            short8 Bl = *reinterpret_cast<const short8*>(&Bul[(ms*64+lane)*8]);
            MFMA3(Ah, Al, Bh, Bl);
        }
        if (seg == 0) {
            #pragma unroll
            for (int ks = 0; ks < 4; ++ks) {
                short8 Ah = *reinterpret_cast<const short8*>(FSAh + (ct*4+ks)*512 + lane*8);
                short8 Al = *reinterpret_cast<const short8*>(FSAl + (ct*4+ks)*512 + lane*8);
                short8 Bh = *reinterpret_cast<const short8*>(&Bxh[(ks*64+lane)*8]);
                short8 Bl = *reinterpret_cast<const short8*>(&Bxl[(ks*64+lane)*8]);
                MFMA3(Ah, Al, Bh, Bl);
            }
        }
        float* gpart = bounce;   // [8][32][32]
        #pragma unroll
        for (int r = 0; r < 16; ++r) gpart[w*1024 + (2*r+lhi)*32 + l31] = acc[r];
        __syncthreads();
        int o0 = t*4, ex = o0 >> 6, c0 = o0 & 63;
        float4 gv;
        #pragma unroll
        for (int jj = 0; jj < 4; ++jj) {
            int c = c0 + jj;
            int ctx = c >> 5, cr = c & 31;
            int lh = (cr >> 2) & 1;
            int rr = (cr & 3) | ((cr >> 3) << 2);
            float s = cws[c];
            #pragma unroll
            for (int sg = 0; sg < 4; ++sg)
                s += gpart[(ctx*4+sg)*1024 + (2*rr+lh)*32 + ex];
            gv[jj] = s;
        }
        *reinterpret_cast<float4*>(&out[(n0+ex)*64 + c0]) = gv;
    }
#undef MROW
#undef MFMA3
#undef GEMM256
#undef STORE_PASS
#undef BUILD_BU
}

// ---------------- heavy Jacobian kernel: 256 thr, 1 example/block ----------------
// 4 waves, 4096 blocks, 3 blocks/CU (148 regs/thread: 3 waves/SIMD x 148 = 444 <= 512;
// LDS ~36.3 KB x 3 = 109 KB <= 160 KB) -> 12 waves/CU vs round 12's 8.
// KJ = Wd @ Jac: A = Wd bf16 from FB (L2), B = Jac bf16 in LDS (32 KB, frag dh*16+ks).
// Wave w owns m-tiles {2w,2w+1} x both d-halves -> acc[2][2]x16 = 64 AGPR.
// C/D: col = lane&31 = d&31, row m = mt*32+(r&3)+8*(r>>2)+4*(lane>>5) [m74/m101].
// Inter-layer RMW slot for (m,d): ks=m>>4, lane'=((m>>3)&1)*32+(d&31), e=m&7.
__global__ __launch_bounds__(256, 3) void k_heavy_mfma(
        const float* __restrict__ tanhopen, const float* __restrict__ tp0,
        const float* __restrict__ tp1, const float* __restrict__ z2T,
        const float* __restrict__ z1T, const float* __restrict__ wv,
        const float* __restrict__ FA, const unsigned short* __restrict__ FB,
        const float* __restrict__ ksq, const float* __restrict__ trace,
        float* __restrict__ outTrH) {
    __shared__ __align__(16) unsigned short Bf[16384];   // 32 KB: 32 frags x 512
    __shared__ float ss[256], tp0s[256], w1s[256], w2s[256];
    __shared__ float red[4];
    int n = blockIdx.x, t = threadIdx.x;           // t in [0,256)
    int lane = t & 63, w = t >> 6, l31 = lane & 31, lhi = lane >> 5;

    float sv = tanhopen[n*256 + t];
    float a0 = tp0[n*256 + t];
    float a1 = tp1[n*256 + t];
    ss[t] = sv;
    tp0s[t] = a0;
    w1s[t] = (1.f - a0*a0) * z2T[n*256 + t];
    w2s[t] = (1.f - a1*a1) * wv[t];
    float tot = (1.f - sv*sv) * z1T[n*256 + t] * ksq[t];   // trH layer-0 partial (m=t)
    __syncthreads();

    // build Bf[frag= dh*16+ks][tl][e] = bf16( W0T[d][k] * ss[k] )
    #pragma unroll
    for (int i = 0; i < 8; ++i) {
        int q = t + i*256;                  // [0,2048) lane-chunks of short8
        int frag = q >> 6, tl = q & 63;
        int k0 = (frag & 15)*16 + (tl >> 5)*8;
        const float* fp = FA + q*8;         // FA layout matches frag*64+tl
        short8 v8;
        #pragma unroll
        for (int e = 0; e < 8; ++e)
            v8[e] = (short)f2bfu(fp[e] * ss[k0 + e]);
        *reinterpret_cast<short8*>(&Bf[q*8]) = v8;
    }
    __syncthreads();

    floatx16 acc[2][2];   // [m-tile jm][d-half dh]
    int mt0 = w*2, mt1 = w*2 + 1;
    float wtot = 0.f;

    // ---------------- layer 0: KJ1 = Wd0 @ Jac ----------------
    #pragma unroll
    for (int jm = 0; jm < 2; ++jm)
        #pragma unroll
        for (int dh = 0; dh < 2; ++dh)
            #pragma unroll
            for (int r = 0; r < 16; ++r) acc[jm][dh][r] = 0.f;

    for (int ks = 0; ks < 16; ++ks) {
        short8 A0 = *reinterpret_cast<const short8*>(FB + (mt0*16 + ks)*512 + lane*8);
        short8 A1 = *reinterpret_cast<const short8*>(FB + (mt1*16 + ks)*512 + lane*8);
        short8 B0 = *reinterpret_cast<const short8*>(&Bf[((ks)*64 + lane)*8]);
        short8 B1 = *reinterpret_cast<const short8*>(&Bf[((16 + ks)*64 + lane)*8]);
        acc[0][0] = __builtin_amdgcn_mfma_f32_32x32x16_bf16(A0, B0, acc[0][0], 0, 0, 0);
        acc[0][1] = __builtin_amdgcn_mfma_f32_32x32x16_bf16(A0, B1, acc[0][1], 0, 0, 0);
        acc[1][0] = __builtin_amdgcn_mfma_f32_32x32x16_bf16(A1, B0, acc[1][0], 0, 0, 0);
        acc[1][1] = __builtin_amdgcn_mfma_f32_32x32x16_bf16(A1, B1, acc[1][1], 0, 0, 0);
    }
    __syncthreads();   // all layer-0 B-reads done before update writes

    // trH layer-1 + Jac update: Jac[m][d] += 0.5*tp0[m]*KJ1[m][d]
    #pragma unroll
    for (int jm = 0; jm < 2; ++jm) {
        int mt = w*2 + jm;
        #pragma unroll
        for (int g = 0; g < 4; ++g) {
            float w1m[4], tm[4];
            #pragma unroll
            for (int q = 0; q < 4; ++q) {
                int m = mt*32 + 8*g + q + 4*lhi;
                w1m[q] = 0.5f * w1s[m];
                tm[q]  = 0.5f * tp0s[m];
            }
            #pragma unroll
            for (int dh = 0; dh < 2; ++dh) {
                int base = ((dh*16 + mt*2 + (g >> 1))*64
                            + ((g & 1)*32 + l31))*8 + 4*lhi;
                ushort4v old = *reinterpret_cast<ushort4v*>(&Bf[base]);
                ushort4v nw;
                #pragma unroll
                for (int q = 0; q < 4; ++q) {
                    float v = acc[jm][dh][4*g + q];
                    wtot += w1m[q] * v * v;
                    nw[q] = f2bfu(bfu2f(old[q]) + tm[q] * v);
                }
                *reinterpret_cast<ushort4v*>(&Bf[base]) = nw;
            }
        }
    }
    __syncthreads();   // updates visible before layer-1 reads

    // ---------------- layer 1: KJ2 = Wd1 @ Jac_new ----------------
    #pragma unroll
    for (int jm = 0; jm < 2; ++jm)
        #pragma unroll
        for (int dh = 0; dh < 2; ++dh)
            #pragma unroll
            for (int r = 0; r < 16; ++r) acc[jm][dh][r] = 0.f;

    const unsigned short* FB1 = FB + 65536;
    for (int ks = 0; ks < 16; ++ks) {
        short8 A0 = *reinterpret_cast<const short8*>(FB1 + (mt0*16 + ks)*512 + lane*8);
        short8 A1 = *reinterpret_cast<const short8*>(FB1 + (mt1*16 + ks)*512 + lane*8);
        short8 B0 = *reinterpret_cast<const short8*>(&Bf[((ks)*64 + lane)*8]);
        short8 B1 = *reinterpret_cast<const short8*>(&Bf[((16 + ks)*64 + lane)*8]);
        acc[0][0] = __builtin_amdgcn_mfma_f32_32x32x16_bf16(A0, B0, acc[0][0], 0, 0, 0);
        acc[0][1] = __builtin_amdgcn_mfma_f32_32x32x16_bf16(A0, B1, acc[0][1], 0, 0, 0);
        acc[1][0] = __builtin_amdgcn_mfma_f32_32x32x16_bf16(A1, B0, acc[1][0], 0, 0, 0);
        acc[1][1] = __builtin_amdgcn_mfma_f32_32x32x16_bf16(A1, B1, acc[1][1], 0, 0, 0);
    }

    // trH layer-2 term
    #pragma unroll
    for (int jm = 0; jm < 2; ++jm)
        #pragma unroll
        for (int g = 0; g < 4; ++g)
            #pragma unroll
            for (int q = 0; q < 4; ++q) {
                int m = (w*2 + jm)*32 + 8*g + q + 4*lhi;
                float w2m = 0.5f * w2s[m];
                float v0 = acc[jm][0][4*g + q], v1 = acc[jm][1][4*g + q];
                wtot += w2m * (v0*v0 + v1*v1);
            }

    tot += wtot;

    // reduce 256 -> 1
    for (int off = 32; off; off >>= 1) tot += __shfl_down(tot, off, 64);
    if (lane == 0) red[w] = tot;
    __syncthreads();
    if (t == 0) outTrH[n] = red[0] + red[1] + red[2] + red[3] + trace[0];
}

// ---------------- launcher ----------------

extern "C" void kernel_launch(void* const* d_in, const int* in_sizes, int n_in,
                              void* d_out, int out_size, void* d_ws, size_t ws_size,
                              hipStream_t stream) {
    const float* x   = (const float*)d_in[0];   // 4096*64
    const float* W0  = (const float*)d_in[1];   // 256*64
    const float* b0  = (const float*)d_in[2];   // 256
    const float* Wd  = (const float*)d_in[3];   // 2*256*256
    const float* bd  = (const float*)d_in[4];   // 2*256
    const float* wv  = (const float*)d_in[5];   // 256
    const float* A   = (const float*)d_in[6];   // 10*64
    const float* cw  = (const float*)d_in[7];   // 64
    float* out = (float*)d_out;
    float* ws  = (float*)d_ws;

    float* tanhopen = ws;               // NM
    float* tp0  = tanhopen + NM;        // NM
    float* tp1  = tp0 + NM;             // NM
    float* z2T  = tp1 + NM;             // NM
    float* z1T  = z2T + NM;             // NM
    float* FA   = z1T + NM;             // 16384
    float* ksq  = FA + 16384;           // 256
    float* trace= ksq + 256;            // 4 (padded for alignment)
    unsigned short* FBh  = (unsigned short*)(trace + 4);  // 131072
    unsigned short* FBl  = FBh + 131072;
    unsigned short* FBTh = FBl + 131072;
    unsigned short* FBTl = FBTh + 131072;
    unsigned short* FW0h = FBTl + 131072;                 // 16384
    unsigned short* FW0l = FW0h + 16384;
    unsigned short* FWTh = FW0l + 16384;                  // 16384
    unsigned short* FWTl = FWTh + 16384;
    unsigned short* FSAh = FWTl + 16384;                  // 4096
    unsigned short* FSAl = FSAh + 4096;

    k_prep<<<155, 256, 0, stream>>>(Wd, W0, A, FBh, FBl, FBTh, FBTl,
                                    FW0h, FW0l, FWTh, FWTl, FSAh, FSAl,
                                    FA, ksq, trace);
    k_fb<<<NEX/32, 512, 0, stream>>>(x, b0, bd, wv, cw,
                                     FW0h, FW0l, FBh, FBl, FBTh, FBTl,
                                     FWTh, FWTl, FSAh, FSAl,
                                     tanhopen, tp0, tp1, z2T, z1T, out);
    k_heavy_mfma<<<NEX, 256, 0, stream>>>(tanhopen, tp0, tp1, z2T, z1T, wv,
                                          FA, FBh, ksq, trace, out + NEX*64);
}

// Round 14
// 121.080 us; speedup vs baseline: 3.5610x; 1.2215x over previous
//
#include <hip/hip_runtime.h>
#include <hip/hip_bf16.h>

#define NEX 4096
#define M   256
#define NM  (NEX*M)

typedef __attribute__((ext_vector_type(8))) short short8;
typedef __attribute__((ext_vector_type(16))) float floatx16;
typedef __attribute__((ext_vector_type(4))) unsigned short ushort4v;

__device__ inline unsigned short f2bfu(float x) {
    __hip_bfloat16 h = __float2bfloat16(x);
    union { __hip_bfloat16 b; unsigned short u; } cv; cv.b = h;
    return cv.u;
}
__device__ inline float bfu2f(unsigned short u) {
    union { unsigned short u; __hip_bfloat16 b; } cv; cv.u = u;
    return __bfloat162float(cv.b);
}

// ---------------- fused prep kernel ----------------
// Fragment convention (32x32x16 MFMA, verified rounds 8-13):
//   A-frag slot: lane&31 = C-row, k = ks*16 + (lane>>5)*8 + e
//   B-frag slot: lane&31 = C-col, k = ks*16 + (lane>>5)*8 + e
//   C/D: col = lane&31, row = (r&3) + 8*(r>>2) + 4*(lane>>5)
// Weights are single-bf16 (hi only); x/activations carry hi+lo at use sites.
__global__ void k_prep(const float* __restrict__ Wd, const float* __restrict__ W0,
                       const float* __restrict__ A,
                       unsigned short* __restrict__ FB,
                       unsigned short* __restrict__ FBT,
                       unsigned short* __restrict__ FW0,
                       unsigned short* __restrict__ FWT,
                       unsigned short* __restrict__ FSA,
                       float* __restrict__ FA,
                       float* __restrict__ ksq, float* __restrict__ trace) {
    int b = blockIdx.x, t = threadIdx.x;
    int lane = t & 63, l31 = lane & 31, lhi = lane >> 5;
    if (b < 64) {
        // FB: 256 combos (l, mtile, kstep)
        int combo = b*4 + (t >> 6);
        int l = combo >> 7, rest = combo & 127;
        int mtile = rest >> 4, kstep = rest & 15;
        const float* src = Wd + l*65536 + (mtile*32 + l31)*256 + kstep*16 + lhi*8;
        int off = l*65536 + (mtile*16 + kstep)*512 + lane*8;
        #pragma unroll
        for (int e = 0; e < 8; ++e) FB[off+e] = f2bfu(src[e]);
    } else if (b < 128) {
        // FBT: 256 combos (l, ktile, ms)
        int combo = (b-64)*4 + (t >> 6);
        int l = combo >> 7, rest = combo & 127;
        int kt = rest >> 4, ms = rest & 15;
        const float* src = Wd + l*65536 + (ms*16 + lhi*8)*256 + kt*32 + l31;
        int off = l*65536 + (kt*16 + ms)*512 + lane*8;
        #pragma unroll
        for (int e = 0; e < 8; ++e) FBT[off+e] = f2bfu(src[e*256]);
    } else if (b < 136) {
        // FW0: 32 combos (mt, ks)
        int combo = (b-128)*4 + (t >> 6);
        int mt = combo >> 2, ks = combo & 3;
        const float* src = W0 + (mt*32 + l31)*64 + ks*16 + lhi*8;
        int off = combo*512 + lane*8;
        #pragma unroll
        for (int e = 0; e < 8; ++e) FW0[off+e] = f2bfu(src[e]);
    } else if (b < 144) {
        // FWT: 32 combos (ct, ms)
        int combo = (b-136)*4 + (t >> 6);
        int ct = combo >> 4, ms = combo & 15;
        const float* src = W0 + (ms*16 + lhi*8)*64 + ct*32 + l31;
        int off = combo*512 + lane*8;
        #pragma unroll
        for (int e = 0; e < 8; ++e) FWT[off+e] = f2bfu(src[e*64]);
    } else if (b < 146) {
        // FSA: 8 combos (ct, ks); symA computed inline from A
        int combo = (b-144)*4 + (t >> 6);
        int ct = combo >> 2, ks = combo & 3;
        int c = ct*32 + l31;
        int off = combo*512 + lane*8;
        #pragma unroll
        for (int e = 0; e < 8; ++e) {
            int j = ks*16 + lhi*8 + e;
            float s = 0.f;
            #pragma unroll
            for (int r = 0; r < 10; ++r) s += A[r*64+c] * A[r*64+j];
            FSA[off+e] = f2bfu(s);
        }
    } else if (b == 146) {
        float s = 0.f;
        for (int dd = 0; dd < 63; dd++) { float v = W0[t*64+dd]; s += v*v; }
        ksq[t] = s;
        float p = 0.f;
        for (int idx = t; idx < 630; idx += 256) {
            int r = idx / 63, i = idx % 63;
            float v = A[r*64+i]; p += v*v;
        }
        for (int off = 32; off; off >>= 1) p += __shfl_down(p, off, 64);
        __shared__ float red[4];
        if ((t & 63) == 0) red[t >> 6] = p;
        __syncthreads();
        if (t == 0) trace[0] = red[0]+red[1]+red[2]+red[3];
    } else {
        // FA build: 2048 lane-slots, 256 per block
        int q = (b-147)*256 + t;            // [0,2048)
        int tl = q & 63, frag = q >> 6;     // frag = dh*16+ks in [0,32)
        int d  = (frag >> 4)*32 + (tl & 31);
        int m0 = (frag & 15)*16 + (tl >> 5)*8;
        float* dst = FA + q*8;
        #pragma unroll
        for (int e = 0; e < 8; ++e)
            dst[e] = (d == 63) ? 0.f : W0[(m0 + e)*64 + d];
    }
}

// ---------------- fused fwd+bwd MFMA kernel: 32 examples/block ----------------
// 512 threads (8 waves), 128 blocks. Wave w owns m-tile w. Weights bf16 (A);
// activations hi/lo (B) -> 2 MFMA per ks. Fast exp/log transcendentals.
// Per phase: {sync; write bounce+Bu; sync; global store; GEMM} (2 syncs).
__global__ __launch_bounds__(512, 2) void k_fb(
        const float* __restrict__ x, const float* __restrict__ b0,
        const float* __restrict__ bd, const float* __restrict__ wv,
        const float* __restrict__ cw,
        const unsigned short* __restrict__ FW0,
        const unsigned short* __restrict__ FB,
        const unsigned short* __restrict__ FBT,
        const unsigned short* __restrict__ FWT,
        const unsigned short* __restrict__ FSA,
        float* __restrict__ tanhopen, float* __restrict__ tp0g,
        float* __restrict__ tp1g, float* __restrict__ z2T, float* __restrict__ z1T,
        float* __restrict__ out) {
    __shared__ __align__(16) unsigned short Buh[8192], Bul[8192];   // 16ks x 512, 32 KB
    __shared__ __align__(16) unsigned short Bxh[2048], Bxl[2048];   // 4ks x 512, 8 KB
    __shared__ __align__(16) float bounce[8224];                    // 32*257 / gpart 8*32*32
    __shared__ float b0s[256], bd0s[256], bd1s[256], wvs[256], cws[64];
    int n0 = blockIdx.x * 32, t = threadIdx.x;
    int lane = t & 63, w = t >> 6, l31 = lane & 31, lhi = lane >> 5;

    if (t < 256) { b0s[t]=b0[t]; bd0s[t]=bd[t]; bd1s[t]=bd[256+t]; wvs[t]=wv[t]; }
    if (t < 64) cws[t] = cw[t];
    if (t < 256) {
        // Bx build: t = ks*64 + tl
        int tl = t & 63;
        int ex = tl & 31, k0 = (t >> 6)*16 + (tl >> 5)*8;
        const float* xp = x + (n0+ex)*64 + k0;
        short8 h8, l8;
        #pragma unroll
        for (int e = 0; e < 8; ++e) {
            float v = xp[e];
            unsigned short h = f2bfu(v);
            h8[e] = (short)h; l8[e] = (short)f2bfu(v - bfu2f(h));
        }
        *reinterpret_cast<short8*>(&Bxh[t*8]) = h8;
        *reinterpret_cast<short8*>(&Bxl[t*8]) = l8;
    }
    __syncthreads();

#define MROW(r) (w*32 + ((r)&3) + 8*((r)>>2) + 4*lhi)

#define MFMA2(AH, BH, BL) do { \
    acc = __builtin_amdgcn_mfma_f32_32x32x16_bf16(AH, BH, acc, 0, 0, 0); \
    acc = __builtin_amdgcn_mfma_f32_32x32x16_bf16(AH, BL, acc, 0, 0, 0); \
} while (0)

#define GEMM256(PH) do { \
    for (int ks = 0; ks < 16; ++ks) { \
        short8 Ah = *reinterpret_cast<const short8*>(PH + (w*16+ks)*512 + lane*8); \
        short8 Bh = *reinterpret_cast<const short8*>(&Buh[(ks*64+lane)*8]); \
        short8 Bl = *reinterpret_cast<const short8*>(&Bul[(ks*64+lane)*8]); \
        MFMA2(Ah, Bh, Bl); \
    } \
} while (0)

// merged epilogue: sync; write bounce(SVAL)+Bu(BVAL); sync; global store from bounce
#define EPILOGUE(SVAL, DST, BVAL) do { \
    __syncthreads(); \
    _Pragma("unroll") \
    for (int r = 0; r < 16; ++r) bounce[l31*257 + MROW(r)] = SVAL[r]; \
    _Pragma("unroll") \
    for (int g = 0; g < 4; ++g) { \
        int ks_ = w*2 + (g>>1); \
        int lp_ = (g&1)*32 + l31; \
        int base_ = (ks_*64 + lp_)*8 + 4*lhi; \
        ushort4v h4, l4; \
        _Pragma("unroll") \
        for (int q = 0; q < 4; ++q) { \
            float v_ = BVAL[g*4+q]; \
            unsigned short h_ = f2bfu(v_); \
            h4[q] = h_; l4[q] = f2bfu(v_ - bfu2f(h_)); \
        } \
        *reinterpret_cast<ushort4v*>(&Buh[base_]) = h4; \
        *reinterpret_cast<ushort4v*>(&Bul[base_]) = l4; \
    } \
    __syncthreads(); \
    _Pragma("unroll") \
    for (int i = 0; i < 16; ++i) { \
        int f = t + i*512; int ex_ = f >> 8, m_ = f & 255; \
        DST[(n0+ex_)*256 + m_] = bounce[ex_*257 + m_]; \
    } \
} while (0)

    floatx16 acc;
    float sv[16], u0v[16], tp0v[16], z2v[16], cf[16];

    // ---- opening (K=64, A=FW0, B=Bx) ----
    #pragma unroll
    for (int r = 0; r < 16; ++r) acc[r] = 0.f;
    #pragma unroll
    for (int ks = 0; ks < 4; ++ks) {
        short8 Ah = *reinterpret_cast<const short8*>(FW0 + (w*4+ks)*512 + lane*8);
        short8 Bh = *reinterpret_cast<const short8*>(&Bxh[(ks*64+lane)*8]);
        short8 Bl = *reinterpret_cast<const short8*>(&Bxl[(ks*64+lane)*8]);
        MFMA2(Ah, Bh, Bl);
    }
    #pragma unroll
    for (int r = 0; r < 16; ++r) {
        float p = acc[r] + b0s[MROW(r)];
        float a = fabsf(p);
        float e = __expf(-2.f*a);
        float th = (1.f - e) * __builtin_amdgcn_rcpf(1.f + e);
        sv[r] = __builtin_copysignf(th, p);
        u0v[r] = a + __logf(1.f + e);
    }
    EPILOGUE(sv, tanhopen, u0v);

    // ---- pre0 (A=FB layer0, B=u0) ----
    #pragma unroll
    for (int r = 0; r < 16; ++r) acc[r] = 0.f;
    GEMM256(FB);
    #pragma unroll
    for (int r = 0; r < 16; ++r) {
        float p = acc[r] + bd0s[MROW(r)];
        float a = fabsf(p);
        float e = __expf(-2.f*a);
        float th = (1.f - e) * __builtin_amdgcn_rcpf(1.f + e);
        tp0v[r] = __builtin_copysignf(th, p);
        u0v[r] += 0.5f*(a + __logf(1.f + e));   // now u1
    }
    EPILOGUE(tp0v, tp0g, u0v);

    // ---- pre1 (A=FB layer1, B=u1) ----
    #pragma unroll
    for (int r = 0; r < 16; ++r) acc[r] = 0.f;
    GEMM256(FB + 65536);
    #pragma unroll
    for (int r = 0; r < 16; ++r) {
        float p = acc[r] + bd1s[MROW(r)];
        float a = fabsf(p);
        float e = __expf(-2.f*a);
        float th = (1.f - e) * __builtin_amdgcn_rcpf(1.f + e);
        cf[r] = __builtin_copysignf(th, p);
        z2v[r] = cf[r] * wvs[MROW(r)];           // coef2 = tp1*wv (reuse z2v slot)
    }
    EPILOGUE(cf, tp1g, z2v);

    // ---- z2 (A=FBT layer1, B=coef2) ----
    #pragma unroll
    for (int r = 0; r < 16; ++r) acc[r] = 0.f;
    GEMM256(FBT + 65536);
    #pragma unroll
    for (int r = 0; r < 16; ++r) {
        z2v[r] = wvs[MROW(r)] + 0.5f*acc[r];
        cf[r] = tp0v[r] * z2v[r];                // coef1
    }
    EPILOGUE(z2v, z2T, cf);

    // ---- z1 (A=FBT layer0, B=coef1) ----
    #pragma unroll
    for (int r = 0; r < 16; ++r) acc[r] = 0.f;
    GEMM256(FBT);
    #pragma unroll
    for (int r = 0; r < 16; ++r) {
        z2v[r] += 0.5f*acc[r];                   // now z1
        cf[r] = sv[r] * z2v[r];                  // coef0
    }
    EPILOGUE(z2v, z1T, cf);

    // ---- grad (A=FWT over coef0, + FSA over x), K-split across waves ----
    {
        int ct = w >> 2, seg = w & 3;
        #pragma unroll
        for (int r = 0; r < 16; ++r) acc[r] = 0.f;
        #pragma unroll
        for (int k2 = 0; k2 < 4; ++k2) {
            int ms = seg*4 + k2;
            short8 Ah = *reinterpret_cast<const short8*>(FWT + (ct*16+ms)*512 + lane*8);
            short8 Bh = *reinterpret_cast<const short8*>(&Buh[(ms*64+lane)*8]);
            short8 Bl = *reinterpret_cast<const short8*>(&Bul[(ms*64+lane)*8]);
            MFMA2(Ah, Bh, Bl);
        }
        if (seg == 0) {
            #pragma unroll
            for (int ks = 0; ks < 4; ++ks) {
                short8 Ah = *reinterpret_cast<const short8*>(FSA + (ct*4+ks)*512 + lane*8);
                short8 Bh = *reinterpret_cast<const short8*>(&Bxh[(ks*64+lane)*8]);
                short8 Bl = *reinterpret_cast<const short8*>(&Bxl[(ks*64+lane)*8]);
                MFMA2(Ah, Bh, Bl);
            }
        }
        __syncthreads();   // protect bounce (last z1 store reads done)
        float* gpart = bounce;   // [8][32][32]
        #pragma unroll
        for (int r = 0; r < 16; ++r) gpart[w*1024 + (2*r+lhi)*32 + l31] = acc[r];
        __syncthreads();
        int o0 = t*4, ex = o0 >> 6, c0 = o0 & 63;
        float4 gv;
        #pragma unroll
        for (int jj = 0; jj < 4; ++jj) {
            int c = c0 + jj;
            int ctx = c >> 5, cr = c & 31;
            int lh = (cr >> 2) & 1;
            int rr = (cr & 3) | ((cr >> 3) << 2);
            float s = cws[c];
            #pragma unroll
            for (int sg = 0; sg < 4; ++sg)
                s += gpart[(ctx*4+sg)*1024 + (2*rr+lh)*32 + ex];
            gv[jj] = s;
        }
        *reinterpret_cast<float4*>(&out[(n0+ex)*64 + c0]) = gv;
    }
#undef MROW
#undef MFMA2
#undef GEMM256
#undef EPILOGUE
}

// ---------------- heavy Jacobian kernel: 256 thr, 1 example/block (round-13 proven) ----------------
__global__ __launch_bounds__(256, 3) void k_heavy_mfma(
        const float* __restrict__ tanhopen, const float* __restrict__ tp0,
        const float* __restrict__ tp1, const float* __restrict__ z2T,
        const float* __restrict__ z1T, const float* __restrict__ wv,
        const float* __restrict__ FA, const unsigned short* __restrict__ FB,
        const float* __restrict__ ksq, const float* __restrict__ trace,
        float* __restrict__ outTrH) {
    __shared__ __align__(16) unsigned short Bf[16384];   // 32 KB: 32 frags x 512
    __shared__ float ss[256], tp0s[256], w1s[256], w2s[256];
    __shared__ float red[4];
    int n = blockIdx.x, t = threadIdx.x;           // t in [0,256)
    int lane = t & 63, w = t >> 6, l31 = lane & 31, lhi = lane >> 5;

    float sv = tanhopen[n*256 + t];
    float a0 = tp0[n*256 + t];
    float a1 = tp1[n*256 + t];
    ss[t] = sv;
    tp0s[t] = a0;
    w1s[t] = (1.f - a0*a0) * z2T[n*256 + t];
    w2s[t] = (1.f - a1*a1) * wv[t];
    float tot = (1.f - sv*sv) * z1T[n*256 + t] * ksq[t];   // trH layer-0 partial (m=t)
    __syncthreads();

    // build Bf[frag= dh*16+ks][tl][e] = bf16( W0T[d][k] * ss[k] )
    #pragma unroll
    for (int i = 0; i < 8; ++i) {
        int q = t + i*256;                  // [0,2048) lane-chunks of short8
        int frag = q >> 6, tl = q & 63;
        int k0 = (frag & 15)*16 + (tl >> 5)*8;
        const float* fp = FA + q*8;         // FA layout matches frag*64+tl
        short8 v8;
        #pragma unroll
        for (int e = 0; e < 8; ++e)
            v8[e] = (short)f2bfu(fp[e] * ss[k0 + e]);
        *reinterpret_cast<short8*>(&Bf[q*8]) = v8;
    }
    __syncthreads();

    floatx16 acc[2][2];   // [m-tile jm][d-half dh]
    int mt0 = w*2, mt1 = w*2 + 1;
    float wtot = 0.f;

    // ---------------- layer 0: KJ1 = Wd0 @ Jac ----------------
    #pragma unroll
    for (int jm = 0; jm < 2; ++jm)
        #pragma unroll
        for (int dh = 0; dh < 2; ++dh)
            #pragma unroll
            for (int r = 0; r < 16; ++r) acc[jm][dh][r] = 0.f;

    for (int ks = 0; ks < 16; ++ks) {
        short8 A0 = *reinterpret_cast<const short8*>(FB + (mt0*16 + ks)*512 + lane*8);
        short8 A1 = *reinterpret_cast<const short8*>(FB + (mt1*16 + ks)*512 + lane*8);
        short8 B0 = *reinterpret_cast<const short8*>(&Bf[((ks)*64 + lane)*8]);
        short8 B1 = *reinterpret_cast<const short8*>(&Bf[((16 + ks)*64 + lane)*8]);
        acc[0][0] = __builtin_amdgcn_mfma_f32_32x32x16_bf16(A0, B0, acc[0][0], 0, 0, 0);
        acc[0][1] = __builtin_amdgcn_mfma_f32_32x32x16_bf16(A0, B1, acc[0][1], 0, 0, 0);
        acc[1][0] = __builtin_amdgcn_mfma_f32_32x32x16_bf16(A1, B0, acc[1][0], 0, 0, 0);
        acc[1][1] = __builtin_amdgcn_mfma_f32_32x32x16_bf16(A1, B1, acc[1][1], 0, 0, 0);
    }
    __syncthreads();   // all layer-0 B-reads done before update writes

    // trH layer-1 + Jac update: Jac[m][d] += 0.5*tp0[m]*KJ1[m][d]
    #pragma unroll
    for (int jm = 0; jm < 2; ++jm) {
        int mt = w*2 + jm;
        #pragma unroll
        for (int g = 0; g < 4; ++g) {
            float w1m[4], tm[4];
            #pragma unroll
            for (int q = 0; q < 4; ++q) {
                int m = mt*32 + 8*g + q + 4*lhi;
                w1m[q] = 0.5f * w1s[m];
                tm[q]  = 0.5f * tp0s[m];
            }
            #pragma unroll
            for (int dh = 0; dh < 2; ++dh) {
                int base = ((dh*16 + mt*2 + (g >> 1))*64
                            + ((g & 1)*32 + l31))*8 + 4*lhi;
                ushort4v old = *reinterpret_cast<ushort4v*>(&Bf[base]);
                ushort4v nw;
                #pragma unroll
                for (int q = 0; q < 4; ++q) {
                    float v = acc[jm][dh][4*g + q];
                    wtot += w1m[q] * v * v;
                    nw[q] = f2bfu(bfu2f(old[q]) + tm[q] * v);
                }
                *reinterpret_cast<ushort4v*>(&Bf[base]) = nw;
            }
        }
    }
    __syncthreads();   // updates visible before layer-1 reads

    // ---------------- layer 1: KJ2 = Wd1 @ Jac_new ----------------
    #pragma unroll
    for (int jm = 0; jm < 2; ++jm)
        #pragma unroll
        for (int dh = 0; dh < 2; ++dh)
            #pragma unroll
            for (int r = 0; r < 16; ++r) acc[jm][dh][r] = 0.f;

    const unsigned short* FB1 = FB + 65536;
    for (int ks = 0; ks < 16; ++ks) {
        short8 A0 = *reinterpret_cast<const short8*>(FB1 + (mt0*16 + ks)*512 + lane*8);
        short8 A1 = *reinterpret_cast<const short8*>(FB1 + (mt1*16 + ks)*512 + lane*8);
        short8 B0 = *reinterpret_cast<const short8*>(&Bf[((ks)*64 + lane)*8]);
        short8 B1 = *reinterpret_cast<const short8*>(&Bf[((16 + ks)*64 + lane)*8]);
        acc[0][0] = __builtin_amdgcn_mfma_f32_32x32x16_bf16(A0, B0, acc[0][0], 0, 0, 0);
        acc[0][1] = __builtin_amdgcn_mfma_f32_32x32x16_bf16(A0, B1, acc[0][1], 0, 0, 0);
        acc[1][0] = __builtin_amdgcn_mfma_f32_32x32x16_bf16(A1, B0, acc[1][0], 0, 0, 0);
        acc[1][1] = __builtin_amdgcn_mfma_f32_32x32x16_bf16(A1, B1, acc[1][1], 0, 0, 0);
    }

    // trH layer-2 term
    #pragma unroll
    for (int jm = 0; jm < 2; ++jm)
        #pragma unroll
        for (int g = 0; g < 4; ++g)
            #pragma unroll
            for (int q = 0; q < 4; ++q) {
                int m = (w*2 + jm)*32 + 8*g + q + 4*lhi;
                float w2m = 0.5f * w2s[m];
                float v0 = acc[jm][0][4*g + q], v1 = acc[jm][1][4*g + q];
                wtot += w2m * (v0*v0 + v1*v1);
            }

    tot += wtot;

    // reduce 256 -> 1
    for (int off = 32; off; off >>= 1) tot += __shfl_down(tot, off, 64);
    if (lane == 0) red[w] = tot;
    __syncthreads();
    if (t == 0) outTrH[n] = red[0] + red[1] + red[2] + red[3] + trace[0];
}

// ---------------- launcher ----------------

extern "C" void kernel_launch(void* const* d_in, const int* in_sizes, int n_in,
                              void* d_out, int out_size, void* d_ws, size_t ws_size,
                              hipStream_t stream) {
    const float* x   = (const float*)d_in[0];   // 4096*64
    const float* W0  = (const float*)d_in[1];   // 256*64
    const float* b0  = (const float*)d_in[2];   // 256
    const float* Wd  = (const float*)d_in[3];   // 2*256*256
    const float* bd  = (const float*)d_in[4];   // 2*256
    const float* wv  = (const float*)d_in[5];   // 256
    const float* A   = (const float*)d_in[6];   // 10*64
    const float* cw  = (const float*)d_in[7];   // 64
    float* out = (float*)d_out;
    float* ws  = (float*)d_ws;

    float* tanhopen = ws;               // NM
    float* tp0  = tanhopen + NM;        // NM
    float* tp1  = tp0 + NM;             // NM
    float* z2T  = tp1 + NM;             // NM
    float* z1T  = z2T + NM;             // NM
    float* FA   = z1T + NM;             // 16384
    float* ksq  = FA + 16384;           // 256
    float* trace= ksq + 256;            // 4 (padded for alignment)
    unsigned short* FB  = (unsigned short*)(trace + 4);   // 131072
    unsigned short* FBT = FB + 131072;                    // 131072
    unsigned short* FW0 = FBT + 131072;                   // 16384
    unsigned short* FWT = FW0 + 16384;                    // 16384
    unsigned short* FSA = FWT + 16384;                    // 4096

    k_prep<<<155, 256, 0, stream>>>(Wd, W0, A, FB, FBT, FW0, FWT, FSA,
                                    FA, ksq, trace);
    k_fb<<<NEX/32, 512, 0, stream>>>(x, b0, bd, wv, cw,
                                     FW0, FB, FBT, FWT, FSA,
                                     tanhopen, tp0, tp1, z2T, z1T, out);
    k_heavy_mfma<<<NEX, 256, 0, stream>>>(tanhopen, tp0, tp1, z2T, z1T, wv,
                                          FA, FB, ksq, trace, out + NEX*64);
}

// Round 15
// 117.992 us; speedup vs baseline: 3.6542x; 1.0262x over previous
//
#include <hip/hip_runtime.h>
#include <hip/hip_bf16.h>

#define NEX 4096
#define M   256
#define NM  (NEX*M)

typedef __attribute__((ext_vector_type(8))) short short8;
typedef __attribute__((ext_vector_type(16))) float floatx16;
typedef __attribute__((ext_vector_type(4))) unsigned short ushort4v;

__device__ inline unsigned short f2bfu(float x) {
    __hip_bfloat16 h = __float2bfloat16(x);
    union { __hip_bfloat16 b; unsigned short u; } cv; cv.b = h;
    return cv.u;
}
__device__ inline float bfu2f(unsigned short u) {
    union { unsigned short u; __hip_bfloat16 b; } cv; cv.u = u;
    return __bfloat162float(cv.b);
}

// ---------------- fused prep kernel ----------------
// Fragment convention (32x32x16 MFMA, verified rounds 8-14):
//   A-frag slot: lane&31 = C-row, k = ks*16 + (lane>>5)*8 + e
//   B-frag slot: lane&31 = C-col, k = ks*16 + (lane>>5)*8 + e
//   C/D: col = lane&31, row = (r&3) + 8*(r>>2) + 4*(lane>>5)
// Weights are single-bf16 (hi only); x/activations carry hi+lo at use sites.
__global__ void k_prep(const float* __restrict__ Wd, const float* __restrict__ W0,
                       const float* __restrict__ A,
                       unsigned short* __restrict__ FB,
                       unsigned short* __restrict__ FBT,
                       unsigned short* __restrict__ FW0,
                       unsigned short* __restrict__ FWT,
                       unsigned short* __restrict__ FSA,
                       float* __restrict__ FA,
                       float* __restrict__ ksq, float* __restrict__ trace) {
    int b = blockIdx.x, t = threadIdx.x;
    int lane = t & 63, l31 = lane & 31, lhi = lane >> 5;
    if (b < 64) {
        // FB: 256 combos (l, mtile, kstep)
        int combo = b*4 + (t >> 6);
        int l = combo >> 7, rest = combo & 127;
        int mtile = rest >> 4, kstep = rest & 15;
        const float* src = Wd + l*65536 + (mtile*32 + l31)*256 + kstep*16 + lhi*8;
        int off = l*65536 + (mtile*16 + kstep)*512 + lane*8;
        #pragma unroll
        for (int e = 0; e < 8; ++e) FB[off+e] = f2bfu(src[e]);
    } else if (b < 128) {
        // FBT: 256 combos (l, ktile, ms)
        int combo = (b-64)*4 + (t >> 6);
        int l = combo >> 7, rest = combo & 127;
        int kt = rest >> 4, ms = rest & 15;
        const float* src = Wd + l*65536 + (ms*16 + lhi*8)*256 + kt*32 + l31;
        int off = l*65536 + (kt*16 + ms)*512 + lane*8;
        #pragma unroll
        for (int e = 0; e < 8; ++e) FBT[off+e] = f2bfu(src[e*256]);
    } else if (b < 136) {
        // FW0: 32 combos (mt, ks)
        int combo = (b-128)*4 + (t >> 6);
        int mt = combo >> 2, ks = combo & 3;
        const float* src = W0 + (mt*32 + l31)*64 + ks*16 + lhi*8;
        int off = combo*512 + lane*8;
        #pragma unroll
        for (int e = 0; e < 8; ++e) FW0[off+e] = f2bfu(src[e]);
    } else if (b < 144) {
        // FWT: 32 combos (ct, ms)
        int combo = (b-136)*4 + (t >> 6);
        int ct = combo >> 4, ms = combo & 15;
        const float* src = W0 + (ms*16 + lhi*8)*64 + ct*32 + l31;
        int off = combo*512 + lane*8;
        #pragma unroll
        for (int e = 0; e < 8; ++e) FWT[off+e] = f2bfu(src[e*64]);
    } else if (b < 146) {
        // FSA: 8 combos (ct, ks); symA computed inline from A
        int combo = (b-144)*4 + (t >> 6);
        int ct = combo >> 2, ks = combo & 3;
        int c = ct*32 + l31;
        int off = combo*512 + lane*8;
        #pragma unroll
        for (int e = 0; e < 8; ++e) {
            int j = ks*16 + lhi*8 + e;
            float s = 0.f;
            #pragma unroll
            for (int r = 0; r < 10; ++r) s += A[r*64+c] * A[r*64+j];
            FSA[off+e] = f2bfu(s);
        }
    } else if (b == 146) {
        float s = 0.f;
        for (int dd = 0; dd < 63; dd++) { float v = W0[t*64+dd]; s += v*v; }
        ksq[t] = s;
        float p = 0.f;
        for (int idx = t; idx < 630; idx += 256) {
            int r = idx / 63, i = idx % 63;
            float v = A[r*64+i]; p += v*v;
        }
        for (int off = 32; off; off >>= 1) p += __shfl_down(p, off, 64);
        __shared__ float red[4];
        if ((t & 63) == 0) red[t >> 6] = p;
        __syncthreads();
        if (t == 0) trace[0] = red[0]+red[1]+red[2]+red[3];
    } else {
        // FA build: 2048 lane-slots, 256 per block
        int q = (b-147)*256 + t;            // [0,2048)
        int tl = q & 63, frag = q >> 6;     // frag = dh*16+ks in [0,32)
        int d  = (frag >> 4)*32 + (tl & 31);
        int m0 = (frag & 15)*16 + (tl >> 5)*8;
        float* dst = FA + q*8;
        #pragma unroll
        for (int e = 0; e < 8; ++e)
            dst[e] = (d == 63) ? 0.f : W0[(m0 + e)*64 + d];
    }
}

// ---------------- fused fwd+bwd MFMA kernel: 32 examples/block ----------------
__global__ __launch_bounds__(512, 2) void k_fb(
        const float* __restrict__ x, const float* __restrict__ b0,
        const float* __restrict__ bd, const float* __restrict__ wv,
        const float* __restrict__ cw,
        const unsigned short* __restrict__ FW0,
        const unsigned short* __restrict__ FB,
        const unsigned short* __restrict__ FBT,
        const unsigned short* __restrict__ FWT,
        const unsigned short* __restrict__ FSA,
        float* __restrict__ tanhopen, float* __restrict__ tp0g,
        float* __restrict__ tp1g, float* __restrict__ z2T, float* __restrict__ z1T,
        float* __restrict__ out) {
    __shared__ __align__(16) unsigned short Buh[8192], Bul[8192];   // 16ks x 512, 32 KB
    __shared__ __align__(16) unsigned short Bxh[2048], Bxl[2048];   // 4ks x 512, 8 KB
    __shared__ __align__(16) float bounce[8224];                    // 32*257 / gpart 8*32*32
    __shared__ float b0s[256], bd0s[256], bd1s[256], wvs[256], cws[64];
    int n0 = blockIdx.x * 32, t = threadIdx.x;
    int lane = t & 63, w = t >> 6, l31 = lane & 31, lhi = lane >> 5;

    if (t < 256) { b0s[t]=b0[t]; bd0s[t]=bd[t]; bd1s[t]=bd[256+t]; wvs[t]=wv[t]; }
    if (t < 64) cws[t] = cw[t];
    if (t < 256) {
        // Bx build: t = ks*64 + tl
        int tl = t & 63;
        int ex = tl & 31, k0 = (t >> 6)*16 + (tl >> 5)*8;
        const float* xp = x + (n0+ex)*64 + k0;
        short8 h8, l8;
        #pragma unroll
        for (int e = 0; e < 8; ++e) {
            float v = xp[e];
            unsigned short h = f2bfu(v);
            h8[e] = (short)h; l8[e] = (short)f2bfu(v - bfu2f(h));
        }
        *reinterpret_cast<short8*>(&Bxh[t*8]) = h8;
        *reinterpret_cast<short8*>(&Bxl[t*8]) = l8;
    }
    __syncthreads();

#define MROW(r) (w*32 + ((r)&3) + 8*((r)>>2) + 4*lhi)

#define MFMA2(AH, BH, BL) do { \
    acc = __builtin_amdgcn_mfma_f32_32x32x16_bf16(AH, BH, acc, 0, 0, 0); \
    acc = __builtin_amdgcn_mfma_f32_32x32x16_bf16(AH, BL, acc, 0, 0, 0); \
} while (0)

#define GEMM256(PH) do { \
    for (int ks = 0; ks < 16; ++ks) { \
        short8 Ah = *reinterpret_cast<const short8*>(PH + (w*16+ks)*512 + lane*8); \
        short8 Bh = *reinterpret_cast<const short8*>(&Buh[(ks*64+lane)*8]); \
        short8 Bl = *reinterpret_cast<const short8*>(&Bul[(ks*64+lane)*8]); \
        MFMA2(Ah, Bh, Bl); \
    } \
} while (0)

// merged epilogue: sync; write bounce(SVAL)+Bu(BVAL); sync; global store from bounce
#define EPILOGUE(SVAL, DST, BVAL) do { \
    __syncthreads(); \
    _Pragma("unroll") \
    for (int r = 0; r < 16; ++r) bounce[l31*257 + MROW(r)] = SVAL[r]; \
    _Pragma("unroll") \
    for (int g = 0; g < 4; ++g) { \
        int ks_ = w*2 + (g>>1); \
        int lp_ = (g&1)*32 + l31; \
        int base_ = (ks_*64 + lp_)*8 + 4*lhi; \
        ushort4v h4, l4; \
        _Pragma("unroll") \
        for (int q = 0; q < 4; ++q) { \
            float v_ = BVAL[g*4+q]; \
            unsigned short h_ = f2bfu(v_); \
            h4[q] = h_; l4[q] = f2bfu(v_ - bfu2f(h_)); \
        } \
        *reinterpret_cast<ushort4v*>(&Buh[base_]) = h4; \
        *reinterpret_cast<ushort4v*>(&Bul[base_]) = l4; \
    } \
    __syncthreads(); \
    _Pragma("unroll") \
    for (int i = 0; i < 16; ++i) { \
        int f = t + i*512; int ex_ = f >> 8, m_ = f & 255; \
        DST[(n0+ex_)*256 + m_] = bounce[ex_*257 + m_]; \
    } \
} while (0)

    floatx16 acc;
    float sv[16], u0v[16], tp0v[16], z2v[16], cf[16];

    // ---- opening (K=64, A=FW0, B=Bx) ----
    #pragma unroll
    for (int r = 0; r < 16; ++r) acc[r] = 0.f;
    #pragma unroll
    for (int ks = 0; ks < 4; ++ks) {
        short8 Ah = *reinterpret_cast<const short8*>(FW0 + (w*4+ks)*512 + lane*8);
        short8 Bh = *reinterpret_cast<const short8*>(&Bxh[(ks*64+lane)*8]);
        short8 Bl = *reinterpret_cast<const short8*>(&Bxl[(ks*64+lane)*8]);
        MFMA2(Ah, Bh, Bl);
    }
    #pragma unroll
    for (int r = 0; r < 16; ++r) {
        float p = acc[r] + b0s[MROW(r)];
        float a = fabsf(p);
        float e = __expf(-2.f*a);
        float th = (1.f - e) * __builtin_amdgcn_rcpf(1.f + e);
        sv[r] = __builtin_copysignf(th, p);
        u0v[r] = a + __logf(1.f + e);
    }
    EPILOGUE(sv, tanhopen, u0v);

    // ---- pre0 (A=FB layer0, B=u0) ----
    #pragma unroll
    for (int r = 0; r < 16; ++r) acc[r] = 0.f;
    GEMM256(FB);
    #pragma unroll
    for (int r = 0; r < 16; ++r) {
        float p = acc[r] + bd0s[MROW(r)];
        float a = fabsf(p);
        float e = __expf(-2.f*a);
        float th = (1.f - e) * __builtin_amdgcn_rcpf(1.f + e);
        tp0v[r] = __builtin_copysignf(th, p);
        u0v[r] += 0.5f*(a + __logf(1.f + e));   // now u1
    }
    EPILOGUE(tp0v, tp0g, u0v);

    // ---- pre1 (A=FB layer1, B=u1) ----
    #pragma unroll
    for (int r = 0; r < 16; ++r) acc[r] = 0.f;
    GEMM256(FB + 65536);
    #pragma unroll
    for (int r = 0; r < 16; ++r) {
        float p = acc[r] + bd1s[MROW(r)];
        float a = fabsf(p);
        float e = __expf(-2.f*a);
        float th = (1.f - e) * __builtin_amdgcn_rcpf(1.f + e);
        cf[r] = __builtin_copysignf(th, p);
        z2v[r] = cf[r] * wvs[MROW(r)];           // coef2 = tp1*wv (reuse z2v slot)
    }
    EPILOGUE(cf, tp1g, z2v);

    // ---- z2 (A=FBT layer1, B=coef2) ----
    #pragma unroll
    for (int r = 0; r < 16; ++r) acc[r] = 0.f;
    GEMM256(FBT + 65536);
    #pragma unroll
    for (int r = 0; r < 16; ++r) {
        z2v[r] = wvs[MROW(r)] + 0.5f*acc[r];
        cf[r] = tp0v[r] * z2v[r];                // coef1
    }
    EPILOGUE(z2v, z2T, cf);

    // ---- z1 (A=FBT layer0, B=coef1) ----
    #pragma unroll
    for (int r = 0; r < 16; ++r) acc[r] = 0.f;
    GEMM256(FBT);
    #pragma unroll
    for (int r = 0; r < 16; ++r) {
        z2v[r] += 0.5f*acc[r];                   // now z1
        cf[r] = sv[r] * z2v[r];                  // coef0
    }
    EPILOGUE(z2v, z1T, cf);

    // ---- grad (A=FWT over coef0, + FSA over x), K-split across waves ----
    {
        int ct = w >> 2, seg = w & 3;
        #pragma unroll
        for (int r = 0; r < 16; ++r) acc[r] = 0.f;
        #pragma unroll
        for (int k2 = 0; k2 < 4; ++k2) {
            int ms = seg*4 + k2;
            short8 Ah = *reinterpret_cast<const short8*>(FWT + (ct*16+ms)*512 + lane*8);
            short8 Bh = *reinterpret_cast<const short8*>(&Buh[(ms*64+lane)*8]);
            short8 Bl = *reinterpret_cast<const short8*>(&Bul[(ms*64+lane)*8]);
            MFMA2(Ah, Bh, Bl);
        }
        if (seg == 0) {
            #pragma unroll
            for (int ks = 0; ks < 4; ++ks) {
                short8 Ah = *reinterpret_cast<const short8*>(FSA + (ct*4+ks)*512 + lane*8);
                short8 Bh = *reinterpret_cast<const short8*>(&Bxh[(ks*64+lane)*8]);
                short8 Bl = *reinterpret_cast<const short8*>(&Bxl[(ks*64+lane)*8]);
                MFMA2(Ah, Bh, Bl);
            }
        }
        __syncthreads();   // protect bounce (last z1 store reads done)
        float* gpart = bounce;   // [8][32][32]
        #pragma unroll
        for (int r = 0; r < 16; ++r) gpart[w*1024 + (2*r+lhi)*32 + l31] = acc[r];
        __syncthreads();
        int o0 = t*4, ex = o0 >> 6, c0 = o0 & 63;
        float4 gv;
        #pragma unroll
        for (int jj = 0; jj < 4; ++jj) {
            int c = c0 + jj;
            int ctx = c >> 5, cr = c & 31;
            int lh = (cr >> 2) & 1;
            int rr = (cr & 3) | ((cr >> 3) << 2);
            float s = cws[c];
            #pragma unroll
            for (int sg = 0; sg < 4; ++sg)
                s += gpart[(ctx*4+sg)*1024 + (2*rr+lh)*32 + ex];
            gv[jj] = s;
        }
        *reinterpret_cast<float4*>(&out[(n0+ex)*64 + c0]) = gv;
    }
#undef MROW
#undef MFMA2
#undef GEMM256
#undef EPILOGUE
}

// ---------------- heavy Jacobian kernel: 256 thr, 1 ex/block, pipelined ks-loop ----------------
// Round-13 structure + explicit 2-stage register pipeline (a/b sets) in both layer
// GEMM loops; layer-1 A prologue prefetched before the RMW barrier.
// 3 blocks/CU target: ~92 arch + 64 acc = 156/thread, 3 waves/SIMD = 468 <= 512.
__global__ __launch_bounds__(256, 3) void k_heavy_mfma(
        const float* __restrict__ tanhopen, const float* __restrict__ tp0,
        const float* __restrict__ tp1, const float* __restrict__ z2T,
        const float* __restrict__ z1T, const float* __restrict__ wv,
        const float* __restrict__ FA, const unsigned short* __restrict__ FB,
        const float* __restrict__ ksq, const float* __restrict__ trace,
        float* __restrict__ outTrH) {
    __shared__ __align__(16) unsigned short Bf[16384];   // 32 KB: 32 frags x 512
    __shared__ float ss[256], tp0s[256], w1s[256], w2s[256];
    __shared__ float red[4];
    int n = blockIdx.x, t = threadIdx.x;           // t in [0,256)
    int lane = t & 63, w = t >> 6, l31 = lane & 31, lhi = lane >> 5;

    float sv = tanhopen[n*256 + t];
    float a0 = tp0[n*256 + t];
    float a1 = tp1[n*256 + t];
    ss[t] = sv;
    tp0s[t] = a0;
    w1s[t] = (1.f - a0*a0) * z2T[n*256 + t];
    w2s[t] = (1.f - a1*a1) * wv[t];
    float tot = (1.f - sv*sv) * z1T[n*256 + t] * ksq[t];   // trH layer-0 partial (m=t)
    __syncthreads();

    // build Bf[frag= dh*16+ks][tl][e] = bf16( W0T[d][k] * ss[k] )
    #pragma unroll
    for (int i = 0; i < 8; ++i) {
        int q = t + i*256;                  // [0,2048) lane-chunks of short8
        int frag = q >> 6, tl = q & 63;
        int k0 = (frag & 15)*16 + (tl >> 5)*8;
        const float* fp = FA + q*8;         // FA layout matches frag*64+tl
        short8 v8;
        #pragma unroll
        for (int e = 0; e < 8; ++e)
            v8[e] = (short)f2bfu(fp[e] * ss[k0 + e]);
        *reinterpret_cast<short8*>(&Bf[q*8]) = v8;
    }
    __syncthreads();

    floatx16 acc[2][2];   // [m-tile jm][d-half dh]
    int mt0 = w*2, mt1 = w*2 + 1;
    float wtot = 0.f;

    const unsigned short* pA0 = FB + mt0*16*512 + lane*8;   // layer 0, mt0, ks stride 512
    const unsigned short* pA1 = FB + mt1*16*512 + lane*8;
    const unsigned short* qB0 = &Bf[lane*8];                // dh=0, ks stride 512
    const unsigned short* qB1 = &Bf[(16*64 + lane)*8];      // dh=1

#define MFMA4(A0_, A1_, B0_, B1_) do { \
    acc[0][0] = __builtin_amdgcn_mfma_f32_32x32x16_bf16(A0_, B0_, acc[0][0], 0, 0, 0); \
    acc[0][1] = __builtin_amdgcn_mfma_f32_32x32x16_bf16(A0_, B1_, acc[0][1], 0, 0, 0); \
    acc[1][0] = __builtin_amdgcn_mfma_f32_32x32x16_bf16(A1_, B0_, acc[1][0], 0, 0, 0); \
    acc[1][1] = __builtin_amdgcn_mfma_f32_32x32x16_bf16(A1_, B1_, acc[1][1], 0, 0, 0); \
} while (0)

    // ---------------- layer 0: KJ1 = Wd0 @ Jac (2-stage pipelined) ----------------
    #pragma unroll
    for (int jm = 0; jm < 2; ++jm)
        #pragma unroll
        for (int dh = 0; dh < 2; ++dh)
            #pragma unroll
            for (int r = 0; r < 16; ++r) acc[jm][dh][r] = 0.f;

    {
        short8 A0a = *reinterpret_cast<const short8*>(pA0);
        short8 A1a = *reinterpret_cast<const short8*>(pA1);
        short8 B0a = *reinterpret_cast<const short8*>(qB0);
        short8 B1a = *reinterpret_cast<const short8*>(qB1);
        short8 A0b, A1b, B0b, B1b;
        #pragma unroll
        for (int k2 = 0; k2 < 8; ++k2) {
            int ksn = 2*k2 + 1;
            A0b = *reinterpret_cast<const short8*>(pA0 + ksn*512);
            A1b = *reinterpret_cast<const short8*>(pA1 + ksn*512);
            B0b = *reinterpret_cast<const short8*>(qB0 + ksn*512);
            B1b = *reinterpret_cast<const short8*>(qB1 + ksn*512);
            MFMA4(A0a, A1a, B0a, B1a);
            if (k2 < 7) {
                int ksm = 2*k2 + 2;
                A0a = *reinterpret_cast<const short8*>(pA0 + ksm*512);
                A1a = *reinterpret_cast<const short8*>(pA1 + ksm*512);
                B0a = *reinterpret_cast<const short8*>(qB0 + ksm*512);
                B1a = *reinterpret_cast<const short8*>(qB1 + ksm*512);
            }
            MFMA4(A0b, A1b, B0b, B1b);
        }
    }

    // prefetch layer-1 first A fragments (global; independent of the RMW below)
    const unsigned short* pC0 = FB + 65536 + mt0*16*512 + lane*8;
    const unsigned short* pC1 = FB + 65536 + mt1*16*512 + lane*8;
    short8 nA0 = *reinterpret_cast<const short8*>(pC0);
    short8 nA1 = *reinterpret_cast<const short8*>(pC1);

    __syncthreads();   // all layer-0 B-reads done before update writes

    // trH layer-1 + Jac update: Jac[m][d] += 0.5*tp0[m]*KJ1[m][d]
    #pragma unroll
    for (int jm = 0; jm < 2; ++jm) {
        int mt = w*2 + jm;
        #pragma unroll
        for (int g = 0; g < 4; ++g) {
            float w1m[4], tm[4];
            #pragma unroll
            for (int q = 0; q < 4; ++q) {
                int m = mt*32 + 8*g + q + 4*lhi;
                w1m[q] = 0.5f * w1s[m];
                tm[q]  = 0.5f * tp0s[m];
            }
            #pragma unroll
            for (int dh = 0; dh < 2; ++dh) {
                int base = ((dh*16 + mt*2 + (g >> 1))*64
                            + ((g & 1)*32 + l31))*8 + 4*lhi;
                ushort4v old = *reinterpret_cast<ushort4v*>(&Bf[base]);
                ushort4v nw;
                #pragma unroll
                for (int q = 0; q < 4; ++q) {
                    float v = acc[jm][dh][4*g + q];
                    wtot += w1m[q] * v * v;
                    nw[q] = f2bfu(bfu2f(old[q]) + tm[q] * v);
                }
                *reinterpret_cast<ushort4v*>(&Bf[base]) = nw;
            }
        }
    }
    __syncthreads();   // updates visible before layer-1 reads

    // ---------------- layer 1: KJ2 = Wd1 @ Jac_new (2-stage pipelined) ----------------
    #pragma unroll
    for (int jm = 0; jm < 2; ++jm)
        #pragma unroll
        for (int dh = 0; dh < 2; ++dh)
            #pragma unroll
            for (int r = 0; r < 16; ++r) acc[jm][dh][r] = 0.f;

    {
        short8 A0a = nA0;
        short8 A1a = nA1;
        short8 B0a = *reinterpret_cast<const short8*>(qB0);
        short8 B1a = *reinterpret_cast<const short8*>(qB1);
        short8 A0b, A1b, B0b, B1b;
        #pragma unroll
        for (int k2 = 0; k2 < 8; ++k2) {
            int ksn = 2*k2 + 1;
            A0b = *reinterpret_cast<const short8*>(pC0 + ksn*512);
            A1b = *reinterpret_cast<const short8*>(pC1 + ksn*512);
            B0b = *reinterpret_cast<const short8*>(qB0 + ksn*512);
            B1b = *reinterpret_cast<const short8*>(qB1 + ksn*512);
            MFMA4(A0a, A1a, B0a, B1a);
            if (k2 < 7) {
                int ksm = 2*k2 + 2;
                A0a = *reinterpret_cast<const short8*>(pC0 + ksm*512);
                A1a = *reinterpret_cast<const short8*>(pC1 + ksm*512);
                B0a = *reinterpret_cast<const short8*>(qB0 + ksm*512);
                B1a = *reinterpret_cast<const short8*>(qB1 + ksm*512);
            }
            MFMA4(A0b, A1b, B0b, B1b);
        }
    }
#undef MFMA4

    // trH layer-2 term
    #pragma unroll
    for (int jm = 0; jm < 2; ++jm)
        #pragma unroll
        for (int g = 0; g < 4; ++g)
            #pragma unroll
            for (int q = 0; q < 4; ++q) {
                int m = (w*2 + jm)*32 + 8*g + q + 4*lhi;
                float w2m = 0.5f * w2s[m];
                float v0 = acc[jm][0][4*g + q], v1 = acc[jm][1][4*g + q];
                wtot += w2m * (v0*v0 + v1*v1);
            }

    tot += wtot;

    // reduce 256 -> 1
    for (int off = 32; off; off >>= 1) tot += __shfl_down(tot, off, 64);
    if (lane == 0) red[w] = tot;
    __syncthreads();
    if (t == 0) outTrH[n] = red[0] + red[1] + red[2] + red[3] + trace[0];
}

// ---------------- launcher ----------------

extern "C" void kernel_launch(void* const* d_in, const int* in_sizes, int n_in,
                              void* d_out, int out_size, void* d_ws, size_t ws_size,
                              hipStream_t stream) {
    const float* x   = (const float*)d_in[0];   // 4096*64
    const float* W0  = (const float*)d_in[1];   // 256*64
    const float* b0  = (const float*)d_in[2];   // 256
    const float* Wd  = (const float*)d_in[3];   // 2*256*256
    const float* bd  = (const float*)d_in[4];   // 2*256
    const float* wv  = (const float*)d_in[5];   // 256
    const float* A   = (const float*)d_in[6];   // 10*64
    const float* cw  = (const float*)d_in[7];   // 64
    float* out = (float*)d_out;
    float* ws  = (float*)d_ws;

    float* tanhopen = ws;               // NM
    float* tp0  = tanhopen + NM;        // NM
    float* tp1  = tp0 + NM;             // NM
    float* z2T  = tp1 + NM;             // NM
    float* z1T  = z2T + NM;             // NM
    float* FA   = z1T + NM;             // 16384
    float* ksq  = FA + 16384;           // 256
    float* trace= ksq + 256;            // 4 (padded for alignment)
    unsigned short* FB  = (unsigned short*)(trace + 4);   // 131072
    unsigned short* FBT = FB + 131072;                    // 131072
    unsigned short* FW0 = FBT + 131072;                   // 16384
    unsigned short* FWT = FW0 + 16384;                    // 16384
    unsigned short* FSA = FWT + 16384;                    // 4096

    k_prep<<<155, 256, 0, stream>>>(Wd, W0, A, FB, FBT, FW0, FWT, FSA,
                                    FA, ksq, trace);
    k_fb<<<NEX/32, 512, 0, stream>>>(x, b0, bd, wv, cw,
                                     FW0, FB, FBT, FWT, FSA,
                                     tanhopen, tp0, tp1, z2T, z1T, out);
    k_heavy_mfma<<<NEX, 256, 0, stream>>>(tanhopen, tp0, tp1, z2T, z1T, wv,
                                          FA, FB, ksq, trace, out + NEX*64);
}

// Round 16
// 117.773 us; speedup vs baseline: 3.6610x; 1.0019x over previous
//
#include <hip/hip_runtime.h>
#include <hip/hip_bf16.h>

#define NEX 4096
#define M   256
#define NM  (NEX*M)

typedef __attribute__((ext_vector_type(8))) short short8;
typedef __attribute__((ext_vector_type(16))) float floatx16;
typedef __attribute__((ext_vector_type(4))) unsigned short ushort4v;

__device__ inline unsigned short f2bfu(float x) {
    __hip_bfloat16 h = __float2bfloat16(x);
    union { __hip_bfloat16 b; unsigned short u; } cv; cv.b = h;
    return cv.u;
}
__device__ inline float bfu2f(unsigned short u) {
    union { unsigned short u; __hip_bfloat16 b; } cv; cv.u = u;
    return __bfloat162float(cv.b);
}

// ---------------- fused prep kernel ----------------
// Fragment convention (32x32x16 MFMA, verified rounds 8-15):
//   A-frag slot: lane&31 = C-row, k = ks*16 + (lane>>5)*8 + e
//   B-frag slot: lane&31 = C-col, k = ks*16 + (lane>>5)*8 + e
//   C/D: col = lane&31, row = (r&3) + 8*(r>>2) + 4*(lane>>5)
// Weights are single-bf16 (hi only); x/activations carry hi+lo at use sites.
__global__ void k_prep(const float* __restrict__ Wd, const float* __restrict__ W0,
                       const float* __restrict__ A,
                       unsigned short* __restrict__ FB,
                       unsigned short* __restrict__ FBT,
                       unsigned short* __restrict__ FW0,
                       unsigned short* __restrict__ FWT,
                       unsigned short* __restrict__ FSA,
                       float* __restrict__ FA,
                       float* __restrict__ ksq, float* __restrict__ trace) {
    int b = blockIdx.x, t = threadIdx.x;
    int lane = t & 63, l31 = lane & 31, lhi = lane >> 5;
    if (b < 64) {
        // FB: 256 combos (l, mtile, kstep)
        int combo = b*4 + (t >> 6);
        int l = combo >> 7, rest = combo & 127;
        int mtile = rest >> 4, kstep = rest & 15;
        const float* src = Wd + l*65536 + (mtile*32 + l31)*256 + kstep*16 + lhi*8;
        int off = l*65536 + (mtile*16 + kstep)*512 + lane*8;
        #pragma unroll
        for (int e = 0; e < 8; ++e) FB[off+e] = f2bfu(src[e]);
    } else if (b < 128) {
        // FBT: 256 combos (l, ktile, ms)
        int combo = (b-64)*4 + (t >> 6);
        int l = combo >> 7, rest = combo & 127;
        int kt = rest >> 4, ms = rest & 15;
        const float* src = Wd + l*65536 + (ms*16 + lhi*8)*256 + kt*32 + l31;
        int off = l*65536 + (kt*16 + ms)*512 + lane*8;
        #pragma unroll
        for (int e = 0; e < 8; ++e) FBT[off+e] = f2bfu(src[e*256]);
    } else if (b < 136) {
        // FW0: 32 combos (mt, ks)
        int combo = (b-128)*4 + (t >> 6);
        int mt = combo >> 2, ks = combo & 3;
        const float* src = W0 + (mt*32 + l31)*64 + ks*16 + lhi*8;
        int off = combo*512 + lane*8;
        #pragma unroll
        for (int e = 0; e < 8; ++e) FW0[off+e] = f2bfu(src[e]);
    } else if (b < 144) {
        // FWT: 32 combos (ct, ms)
        int combo = (b-136)*4 + (t >> 6);
        int ct = combo >> 4, ms = combo & 15;
        const float* src = W0 + (ms*16 + lhi*8)*64 + ct*32 + l31;
        int off = combo*512 + lane*8;
        #pragma unroll
        for (int e = 0; e < 8; ++e) FWT[off+e] = f2bfu(src[e*64]);
    } else if (b < 146) {
        // FSA: 8 combos (ct, ks); symA computed inline from A
        int combo = (b-144)*4 + (t >> 6);
        int ct = combo >> 2, ks = combo & 3;
        int c = ct*32 + l31;
        int off = combo*512 + lane*8;
        #pragma unroll
        for (int e = 0; e < 8; ++e) {
            int j = ks*16 + lhi*8 + e;
            float s = 0.f;
            #pragma unroll
            for (int r = 0; r < 10; ++r) s += A[r*64+c] * A[r*64+j];
            FSA[off+e] = f2bfu(s);
        }
    } else if (b == 146) {
        float s = 0.f;
        for (int dd = 0; dd < 63; dd++) { float v = W0[t*64+dd]; s += v*v; }
        ksq[t] = s;
        float p = 0.f;
        for (int idx = t; idx < 630; idx += 256) {
            int r = idx / 63, i = idx % 63;
            float v = A[r*64+i]; p += v*v;
        }
        for (int off = 32; off; off >>= 1) p += __shfl_down(p, off, 64);
        __shared__ float red[4];
        if ((t & 63) == 0) red[t >> 6] = p;
        __syncthreads();
        if (t == 0) trace[0] = red[0]+red[1]+red[2]+red[3];
    } else {
        // FA build: 2048 lane-slots, 256 per block
        int q = (b-147)*256 + t;            // [0,2048)
        int tl = q & 63, frag = q >> 6;     // frag = dh*16+ks in [0,32)
        int d  = (frag >> 4)*32 + (tl & 31);
        int m0 = (frag & 15)*16 + (tl >> 5)*8;
        float* dst = FA + q*8;
        #pragma unroll
        for (int e = 0; e < 8; ++e)
            dst[e] = (d == 63) ? 0.f : W0[(m0 + e)*64 + d];
    }
}

// ---------------- fused fwd+bwd MFMA kernel: 32 examples/block ----------------
__global__ __launch_bounds__(512, 2) void k_fb(
        const float* __restrict__ x, const float* __restrict__ b0,
        const float* __restrict__ bd, const float* __restrict__ wv,
        const float* __restrict__ cw,
        const unsigned short* __restrict__ FW0,
        const unsigned short* __restrict__ FB,
        const unsigned short* __restrict__ FBT,
        const unsigned short* __restrict__ FWT,
        const unsigned short* __restrict__ FSA,
        float* __restrict__ tanhopen, float* __restrict__ tp0g,
        float* __restrict__ tp1g, float* __restrict__ z2T, float* __restrict__ z1T,
        float* __restrict__ out) {
    __shared__ __align__(16) unsigned short Buh[8192], Bul[8192];   // 16ks x 512, 32 KB
    __shared__ __align__(16) unsigned short Bxh[2048], Bxl[2048];   // 4ks x 512, 8 KB
    __shared__ __align__(16) float bounce[8224];                    // 32*257 / gpart 8*32*32
    __shared__ float b0s[256], bd0s[256], bd1s[256], wvs[256], cws[64];
    int n0 = blockIdx.x * 32, t = threadIdx.x;
    int lane = t & 63, w = t >> 6, l31 = lane & 31, lhi = lane >> 5;

    if (t < 256) { b0s[t]=b0[t]; bd0s[t]=bd[t]; bd1s[t]=bd[256+t]; wvs[t]=wv[t]; }
    if (t < 64) cws[t] = cw[t];
    if (t < 256) {
        // Bx build: t = ks*64 + tl
        int tl = t & 63;
        int ex = tl & 31, k0 = (t >> 6)*16 + (tl >> 5)*8;
        const float* xp = x + (n0+ex)*64 + k0;
        short8 h8, l8;
        #pragma unroll
        for (int e = 0; e < 8; ++e) {
            float v = xp[e];
            unsigned short h = f2bfu(v);
            h8[e] = (short)h; l8[e] = (short)f2bfu(v - bfu2f(h));
        }
        *reinterpret_cast<short8*>(&Bxh[t*8]) = h8;
        *reinterpret_cast<short8*>(&Bxl[t*8]) = l8;
    }
    __syncthreads();

#define MROW(r) (w*32 + ((r)&3) + 8*((r)>>2) + 4*lhi)

#define MFMA2(AH, BH, BL) do { \
    acc = __builtin_amdgcn_mfma_f32_32x32x16_bf16(AH, BH, acc, 0, 0, 0); \
    acc = __builtin_amdgcn_mfma_f32_32x32x16_bf16(AH, BL, acc, 0, 0, 0); \
} while (0)

#define GEMM256(PH) do { \
    for (int ks = 0; ks < 16; ++ks) { \
        short8 Ah = *reinterpret_cast<const short8*>(PH + (w*16+ks)*512 + lane*8); \
        short8 Bh = *reinterpret_cast<const short8*>(&Buh[(ks*64+lane)*8]); \
        short8 Bl = *reinterpret_cast<const short8*>(&Bul[(ks*64+lane)*8]); \
        MFMA2(Ah, Bh, Bl); \
    } \
} while (0)

// merged epilogue: sync; write bounce(SVAL)+Bu(BVAL); sync; global store from bounce
#define EPILOGUE(SVAL, DST, BVAL) do { \
    __syncthreads(); \
    _Pragma("unroll") \
    for (int r = 0; r < 16; ++r) bounce[l31*257 + MROW(r)] = SVAL[r]; \
    _Pragma("unroll") \
    for (int g = 0; g < 4; ++g) { \
        int ks_ = w*2 + (g>>1); \
        int lp_ = (g&1)*32 + l31; \
        int base_ = (ks_*64 + lp_)*8 + 4*lhi; \
        ushort4v h4, l4; \
        _Pragma("unroll") \
        for (int q = 0; q < 4; ++q) { \
            float v_ = BVAL[g*4+q]; \
            unsigned short h_ = f2bfu(v_); \
            h4[q] = h_; l4[q] = f2bfu(v_ - bfu2f(h_)); \
        } \
        *reinterpret_cast<ushort4v*>(&Buh[base_]) = h4; \
        *reinterpret_cast<ushort4v*>(&Bul[base_]) = l4; \
    } \
    __syncthreads(); \
    _Pragma("unroll") \
    for (int i = 0; i < 16; ++i) { \
        int f = t + i*512; int ex_ = f >> 8, m_ = f & 255; \
        DST[(n0+ex_)*256 + m_] = bounce[ex_*257 + m_]; \
    } \
} while (0)

    floatx16 acc;
    float sv[16], u0v[16], tp0v[16], z2v[16], cf[16];

    // ---- opening (K=64, A=FW0, B=Bx) ----
    #pragma unroll
    for (int r = 0; r < 16; ++r) acc[r] = 0.f;
    #pragma unroll
    for (int ks = 0; ks < 4; ++ks) {
        short8 Ah = *reinterpret_cast<const short8*>(FW0 + (w*4+ks)*512 + lane*8);
        short8 Bh = *reinterpret_cast<const short8*>(&Bxh[(ks*64+lane)*8]);
        short8 Bl = *reinterpret_cast<const short8*>(&Bxl[(ks*64+lane)*8]);
        MFMA2(Ah, Bh, Bl);
    }
    #pragma unroll
    for (int r = 0; r < 16; ++r) {
        float p = acc[r] + b0s[MROW(r)];
        float a = fabsf(p);
        float e = __expf(-2.f*a);
        float th = (1.f - e) * __builtin_amdgcn_rcpf(1.f + e);
        sv[r] = __builtin_copysignf(th, p);
        u0v[r] = a + __logf(1.f + e);
    }
    EPILOGUE(sv, tanhopen, u0v);

    // ---- pre0 (A=FB layer0, B=u0) ----
    #pragma unroll
    for (int r = 0; r < 16; ++r) acc[r] = 0.f;
    GEMM256(FB);
    #pragma unroll
    for (int r = 0; r < 16; ++r) {
        float p = acc[r] + bd0s[MROW(r)];
        float a = fabsf(p);
        float e = __expf(-2.f*a);
        float th = (1.f - e) * __builtin_amdgcn_rcpf(1.f + e);
        tp0v[r] = __builtin_copysignf(th, p);
        u0v[r] += 0.5f*(a + __logf(1.f + e));   // now u1
    }
    EPILOGUE(tp0v, tp0g, u0v);

    // ---- pre1 (A=FB layer1, B=u1) ----
    #pragma unroll
    for (int r = 0; r < 16; ++r) acc[r] = 0.f;
    GEMM256(FB + 65536);
    #pragma unroll
    for (int r = 0; r < 16; ++r) {
        float p = acc[r] + bd1s[MROW(r)];
        float a = fabsf(p);
        float e = __expf(-2.f*a);
        float th = (1.f - e) * __builtin_amdgcn_rcpf(1.f + e);
        cf[r] = __builtin_copysignf(th, p);
        z2v[r] = cf[r] * wvs[MROW(r)];           // coef2 = tp1*wv (reuse z2v slot)
    }
    EPILOGUE(cf, tp1g, z2v);

    // ---- z2 (A=FBT layer1, B=coef2) ----
    #pragma unroll
    for (int r = 0; r < 16; ++r) acc[r] = 0.f;
    GEMM256(FBT + 65536);
    #pragma unroll
    for (int r = 0; r < 16; ++r) {
        z2v[r] = wvs[MROW(r)] + 0.5f*acc[r];
        cf[r] = tp0v[r] * z2v[r];                // coef1
    }
    EPILOGUE(z2v, z2T, cf);

    // ---- z1 (A=FBT layer0, B=coef1) ----
    #pragma unroll
    for (int r = 0; r < 16; ++r) acc[r] = 0.f;
    GEMM256(FBT);
    #pragma unroll
    for (int r = 0; r < 16; ++r) {
        z2v[r] += 0.5f*acc[r];                   // now z1
        cf[r] = sv[r] * z2v[r];                  // coef0
    }
    EPILOGUE(z2v, z1T, cf);

    // ---- grad (A=FWT over coef0, + FSA over x), K-split across waves ----
    {
        int ct = w >> 2, seg = w & 3;
        #pragma unroll
        for (int r = 0; r < 16; ++r) acc[r] = 0.f;
        #pragma unroll
        for (int k2 = 0; k2 < 4; ++k2) {
            int ms = seg*4 + k2;
            short8 Ah = *reinterpret_cast<const short8*>(FWT + (ct*16+ms)*512 + lane*8);
            short8 Bh = *reinterpret_cast<const short8*>(&Buh[(ms*64+lane)*8]);
            short8 Bl = *reinterpret_cast<const short8*>(&Bul[(ms*64+lane)*8]);
            MFMA2(Ah, Bh, Bl);
        }
        if (seg == 0) {
            #pragma unroll
            for (int ks = 0; ks < 4; ++ks) {
                short8 Ah = *reinterpret_cast<const short8*>(FSA + (ct*4+ks)*512 + lane*8);
                short8 Bh = *reinterpret_cast<const short8*>(&Bxh[(ks*64+lane)*8]);
                short8 Bl = *reinterpret_cast<const short8*>(&Bxl[(ks*64+lane)*8]);
                MFMA2(Ah, Bh, Bl);
            }
        }
        __syncthreads();   // protect bounce (last z1 store reads done)
        float* gpart = bounce;   // [8][32][32]
        #pragma unroll
        for (int r = 0; r < 16; ++r) gpart[w*1024 + (2*r+lhi)*32 + l31] = acc[r];
        __syncthreads();
        int o0 = t*4, ex = o0 >> 6, c0 = o0 & 63;
        float4 gv;
        #pragma unroll
        for (int jj = 0; jj < 4; ++jj) {
            int c = c0 + jj;
            int ctx = c >> 5, cr = c & 31;
            int lh = (cr >> 2) & 1;
            int rr = (cr & 3) | ((cr >> 3) << 2);
            float s = cws[c];
            #pragma unroll
            for (int sg = 0; sg < 4; ++sg)
                s += gpart[(ctx*4+sg)*1024 + (2*rr+lh)*32 + ex];
            gv[jj] = s;
        }
        *reinterpret_cast<float4*>(&out[(n0+ex)*64 + c0]) = gv;
    }
#undef MROW
#undef MFMA2
#undef GEMM256
#undef EPILOGUE
}

// ---------------- heavy Jacobian kernel: 256 thr, 1 ex/block, 4-deep A pipeline ----------------
// Round-15 structure with A (global/L2, ~250 cyc) prefetched 4 stages ahead; B (LDS)
// stays 2-deep. Fully-unrolled ks loops keep stage indices static (rule #20).
// Layer-1's first 3 A-stages prefetch before/through the RMW barrier phase.
__global__ __launch_bounds__(256, 3) void k_heavy_mfma(
        const float* __restrict__ tanhopen, const float* __restrict__ tp0,
        const float* __restrict__ tp1, const float* __restrict__ z2T,
        const float* __restrict__ z1T, const float* __restrict__ wv,
        const float* __restrict__ FA, const unsigned short* __restrict__ FB,
        const float* __restrict__ ksq, const float* __restrict__ trace,
        float* __restrict__ outTrH) {
    __shared__ __align__(16) unsigned short Bf[16384];   // 32 KB: 32 frags x 512
    __shared__ float ss[256], tp0s[256], w1s[256], w2s[256];
    __shared__ float red[4];
    int n = blockIdx.x, t = threadIdx.x;           // t in [0,256)
    int lane = t & 63, w = t >> 6, l31 = lane & 31, lhi = lane >> 5;

    float sv = tanhopen[n*256 + t];
    float a0 = tp0[n*256 + t];
    float a1 = tp1[n*256 + t];
    ss[t] = sv;
    tp0s[t] = a0;
    w1s[t] = (1.f - a0*a0) * z2T[n*256 + t];
    w2s[t] = (1.f - a1*a1) * wv[t];
    float tot = (1.f - sv*sv) * z1T[n*256 + t] * ksq[t];   // trH layer-0 partial (m=t)
    __syncthreads();

    // build Bf[frag= dh*16+ks][tl][e] = bf16( W0T[d][k] * ss[k] )
    #pragma unroll
    for (int i = 0; i < 8; ++i) {
        int q = t + i*256;                  // [0,2048) lane-chunks of short8
        int frag = q >> 6, tl = q & 63;
        int k0 = (frag & 15)*16 + (tl >> 5)*8;
        const float* fp = FA + q*8;         // FA layout matches frag*64+tl
        short8 v8;
        #pragma unroll
        for (int e = 0; e < 8; ++e)
            v8[e] = (short)f2bfu(fp[e] * ss[k0 + e]);
        *reinterpret_cast<short8*>(&Bf[q*8]) = v8;
    }
    __syncthreads();

    floatx16 acc[2][2];   // [m-tile jm][d-half dh]
    int mt0 = w*2, mt1 = w*2 + 1;
    float wtot = 0.f;

    const unsigned short* pA0 = FB + mt0*16*512 + lane*8;   // layer 0, mt0, ks stride 512
    const unsigned short* pA1 = FB + mt1*16*512 + lane*8;
    const unsigned short* qB0 = &Bf[lane*8];                // dh=0, ks stride 512
    const unsigned short* qB1 = &Bf[(16*64 + lane)*8];      // dh=1

#define LD8(P, KS) (*reinterpret_cast<const short8*>((P) + (KS)*512))
#define MFMA4(A0_, A1_, B0_, B1_) do { \
    acc[0][0] = __builtin_amdgcn_mfma_f32_32x32x16_bf16(A0_, B0_, acc[0][0], 0, 0, 0); \
    acc[0][1] = __builtin_amdgcn_mfma_f32_32x32x16_bf16(A0_, B1_, acc[0][1], 0, 0, 0); \
    acc[1][0] = __builtin_amdgcn_mfma_f32_32x32x16_bf16(A1_, B0_, acc[1][0], 0, 0, 0); \
    acc[1][1] = __builtin_amdgcn_mfma_f32_32x32x16_bf16(A1_, B1_, acc[1][1], 0, 0, 0); \
} while (0)

    // ---------------- layer 0: KJ1 = Wd0 @ Jac (4-deep A, 2-deep B) ----------------
    #pragma unroll
    for (int jm = 0; jm < 2; ++jm)
        #pragma unroll
        for (int dh = 0; dh < 2; ++dh)
            #pragma unroll
            for (int r = 0; r < 16; ++r) acc[jm][dh][r] = 0.f;

    {
        short8 A0s[4], A1s[4], B0s[2], B1s[2];
        A0s[0] = LD8(pA0, 0); A1s[0] = LD8(pA1, 0);
        A0s[1] = LD8(pA0, 1); A1s[1] = LD8(pA1, 1);
        A0s[2] = LD8(pA0, 2); A1s[2] = LD8(pA1, 2);
        B0s[0] = LD8(qB0, 0); B1s[0] = LD8(qB1, 0);
        #pragma unroll
        for (int ks = 0; ks < 16; ++ks) {
            if (ks + 3 < 16) {
                A0s[(ks+3)&3] = LD8(pA0, ks+3);
                A1s[(ks+3)&3] = LD8(pA1, ks+3);
            }
            if (ks + 1 < 16) {
                B0s[(ks+1)&1] = LD8(qB0, ks+1);
                B1s[(ks+1)&1] = LD8(qB1, ks+1);
            }
            MFMA4(A0s[ks&3], A1s[ks&3], B0s[ks&1], B1s[ks&1]);
        }
    }

    // prefetch layer-1 first A stages (global; independent of the RMW below)
    const unsigned short* pC0 = FB + 65536 + mt0*16*512 + lane*8;
    const unsigned short* pC1 = FB + 65536 + mt1*16*512 + lane*8;
    short8 nA00 = LD8(pC0, 0), nA10 = LD8(pC1, 0);
    short8 nA01 = LD8(pC0, 1), nA11 = LD8(pC1, 1);
    short8 nA02 = LD8(pC0, 2), nA12 = LD8(pC1, 2);

    __syncthreads();   // all layer-0 B-reads done before update writes

    // trH layer-1 + Jac update: Jac[m][d] += 0.5*tp0[m]*KJ1[m][d]
    #pragma unroll
    for (int jm = 0; jm < 2; ++jm) {
        int mt = w*2 + jm;
        #pragma unroll
        for (int g = 0; g < 4; ++g) {
            float w1m[4], tm[4];
            #pragma unroll
            for (int q = 0; q < 4; ++q) {
                int m = mt*32 + 8*g + q + 4*lhi;
                w1m[q] = 0.5f * w1s[m];
                tm[q]  = 0.5f * tp0s[m];
            }
            #pragma unroll
            for (int dh = 0; dh < 2; ++dh) {
                int base = ((dh*16 + mt*2 + (g >> 1))*64
                            + ((g & 1)*32 + l31))*8 + 4*lhi;
                ushort4v old = *reinterpret_cast<ushort4v*>(&Bf[base]);
                ushort4v nw;
                #pragma unroll
                for (int q = 0; q < 4; ++q) {
                    float v = acc[jm][dh][4*g + q];
                    wtot += w1m[q] * v * v;
                    nw[q] = f2bfu(bfu2f(old[q]) + tm[q] * v);
                }
                *reinterpret_cast<ushort4v*>(&Bf[base]) = nw;
            }
        }
    }
    __syncthreads();   // updates visible before layer-1 reads

    // ---------------- layer 1: KJ2 = Wd1 @ Jac_new (4-deep A, 2-deep B) ----------------
    #pragma unroll
    for (int jm = 0; jm < 2; ++jm)
        #pragma unroll
        for (int dh = 0; dh < 2; ++dh)
            #pragma unroll
            for (int r = 0; r < 16; ++r) acc[jm][dh][r] = 0.f;

    {
        short8 A0s[4], A1s[4], B0s[2], B1s[2];
        A0s[0] = nA00; A1s[0] = nA10;
        A0s[1] = nA01; A1s[1] = nA11;
        A0s[2] = nA02; A1s[2] = nA12;
        B0s[0] = LD8(qB0, 0); B1s[0] = LD8(qB1, 0);
        #pragma unroll
        for (int ks = 0; ks < 16; ++ks) {
            if (ks + 3 < 16) {
                A0s[(ks+3)&3] = LD8(pC0, ks+3);
                A1s[(ks+3)&3] = LD8(pC1, ks+3);
            }
            if (ks + 1 < 16) {
                B0s[(ks+1)&1] = LD8(qB0, ks+1);
                B1s[(ks+1)&1] = LD8(qB1, ks+1);
            }
            MFMA4(A0s[ks&3], A1s[ks&3], B0s[ks&1], B1s[ks&1]);
        }
    }
#undef MFMA4
#undef LD8

    // trH layer-2 term
    #pragma unroll
    for (int jm = 0; jm < 2; ++jm)
        #pragma unroll
        for (int g = 0; g < 4; ++g)
            #pragma unroll
            for (int q = 0; q < 4; ++q) {
                int m = (w*2 + jm)*32 + 8*g + q + 4*lhi;
                float w2m = 0.5f * w2s[m];
                float v0 = acc[jm][0][4*g + q], v1 = acc[jm][1][4*g + q];
                wtot += w2m * (v0*v0 + v1*v1);
            }

    tot += wtot;

    // reduce 256 -> 1
    for (int off = 32; off; off >>= 1) tot += __shfl_down(tot, off, 64);
    if (lane == 0) red[w] = tot;
    __syncthreads();
    if (t == 0) outTrH[n] = red[0] + red[1] + red[2] + red[3] + trace[0];
}

// ---------------- launcher ----------------

extern "C" void kernel_launch(void* const* d_in, const int* in_sizes, int n_in,
                              void* d_out, int out_size, void* d_ws, size_t ws_size,
                              hipStream_t stream) {
    const float* x   = (const float*)d_in[0];   // 4096*64
    const float* W0  = (const float*)d_in[1];   // 256*64
    const float* b0  = (const float*)d_in[2];   // 256
    const float* Wd  = (const float*)d_in[3];   // 2*256*256
    const float* bd  = (const float*)d_in[4];   // 2*256
    const float* wv  = (const float*)d_in[5];   // 256
    const float* A   = (const float*)d_in[6];   // 10*64
    const float* cw  = (const float*)d_in[7];   // 64
    float* out = (float*)d_out;
    float* ws  = (float*)d_ws;

    float* tanhopen = ws;               // NM
    float* tp0  = tanhopen + NM;        // NM
    float* tp1  = tp0 + NM;             // NM
    float* z2T  = tp1 + NM;             // NM
    float* z1T  = z2T + NM;             // NM
    float* FA   = z1T + NM;             // 16384
    float* ksq  = FA + 16384;           // 256
    float* trace= ksq + 256;            // 4 (padded for alignment)
    unsigned short* FB  = (unsigned short*)(trace + 4);   // 131072
    unsigned short* FBT = FB + 131072;                    // 131072
    unsigned short* FW0 = FBT + 131072;                   // 16384
    unsigned short* FWT = FW0 + 16384;                    // 16384
    unsigned short* FSA = FWT + 16384;                    // 4096

    k_prep<<<155, 256, 0, stream>>>(Wd, W0, A, FB, FBT, FW0, FWT, FSA,
                                    FA, ksq, trace);
    k_fb<<<NEX/32, 512, 0, stream>>>(x, b0, bd, wv, cw,
                                     FW0, FB, FBT, FWT, FSA,
                                     tanhopen, tp0, tp1, z2T, z1T, out);
    k_heavy_mfma<<<NEX, 256, 0, stream>>>(tanhopen, tp0, tp1, z2T, z1T, wv,
                                          FA, FB, ksq, trace, out + NEX*64);
}